// Round 2
// baseline (706.331 us; speedup 1.0000x reference)
//
#include <hip/hip_runtime.h>
#include <math.h>

// UrbanModelV2: encoder MLPs -> 4x GCNConv (2 graphs) -> gated combine -> LN-MLP head.
// N=100000, CTX=128, TGT=32, H=64, FUS=96, E1=1.6M, E2=0.8M. fp32 in/out.
//
// R11: degcount was capped at a flat 24.5G atomics/s (device-scope atomics execute
//   at the shared memory-side cache; replication was a no-op). -> atomic-free CSR:
//   13 node-ranges x 64 edge-slices; each block histograms its range in 64KB LDS
//   (LDS atomics), writes u16 per-slice counts; scan3 turns them into per-node
//   exclusive prefixes over slices; fill2 re-counts in LDS and scatters srcs
//   directly. No global atomics, no rank array, no memset.
//   Assumes max node degree < 65536 (actual ~60 for this random graph).

#define LN_EPS 1e-5f
#define RNG 13          // node-range groups (16000 nodes each covers 2N=200000)
#define NRANGE 16000    // nodes per range -> 64000B LDS, 2 blocks/CU
#define NSLICE 64       // edge slices

typedef __attribute__((ext_vector_type(8))) short short8;            // 8 bf16
typedef __attribute__((ext_vector_type(4))) float float4v;           // MFMA acc
typedef __attribute__((ext_vector_type(4))) unsigned short ushort4v; // 4 bf16

__device__ __forceinline__ float gelu_exact(float x) {
    return 0.5f * x * (1.0f + erff(x * 0.70710678118654752440f));
}

// reduce across the 16-lane quad-group (lane masks 1..8 stay within group)
__device__ __forceinline__ float qsum16(float v) {
#pragma unroll
    for (int m = 1; m < 16; m <<= 1)
        v += __shfl_xor(v, m, 64);
    return v;
}

__device__ __forceinline__ int load_edge(const void* ei, int is32, long idx) {
    return is32 ? ((const int*)ei)[idx] : (int)((const long long*)ei)[idx];
}

__device__ __forceinline__ unsigned short f32_to_bf16(float f) {
    unsigned int x = __float_as_uint(f);
    x += 0x7fffu + ((x >> 16) & 1u);   // RNE, finite values
    return (unsigned short)(x >> 16);
}
__device__ __forceinline__ float bf16_to_f32(unsigned short u) {
    return __uint_as_float((unsigned int)u << 16);
}

// load dst-nodes (transit offset by n) for edges base..base+3; nv = #valid
__device__ __forceinline__ void load_dst4(const void* ei1, int e1, const void* ei2, int e2,
                                          int n, int is32, int base, int nv, int nd[4]) {
    if (is32 && nv == 4) {
        if (base + 3 < e1 && (((e1 + base) & 3) == 0)) {
            int4 v = *(const int4*)((const int*)ei1 + (size_t)e1 + base);
            nd[0] = v.x; nd[1] = v.y; nd[2] = v.z; nd[3] = v.w;
            return;
        }
        if (base >= e1 && (((e2 + base - e1) & 3) == 0)) {
            int4 v = *(const int4*)((const int*)ei2 + (size_t)e2 + (base - e1));
            nd[0] = v.x + n; nd[1] = v.y + n; nd[2] = v.z + n; nd[3] = v.w + n;
            return;
        }
    }
#pragma unroll
    for (int u = 0; u < 4; ++u) {
        int i = base + u;
        if (u >= nv) { nd[u] = -1; continue; }
        if (i < e1) nd[u] = load_edge(ei1, is32, (long)e1 + i);
        else        nd[u] = load_edge(ei2, is32, (long)e2 + (i - e1)) + n;
    }
}

// ---------------- dtype detection ----------------
__global__ __launch_bounds__(256) void detect_kernel(const unsigned char* __restrict__ mask_bytes,
                                                     const int* __restrict__ ei_words,
                                                     int* __restrict__ flags) {
    __shared__ int f0, f1;
    if (threadIdx.x == 0) { f0 = 0; f1 = 0; }
    __syncthreads();
    int i = threadIdx.x;
    if ((i & 3) != 0 && mask_bytes[i] != 0) f0 = 1;
    if (i < 64 && ei_words[2 * i + 1] != 0) f1 = 1;
    __syncthreads();
    if (threadIdx.x == 0) { flags[0] = f0; flags[1] = f1; }
}

// ---------------- CSR build: LDS-histogram count (no global atomics) ----------------
// block (r,s): node range [r*NRANGE, ...), edge slice [s*SL, ...).
__global__ __launch_bounds__(256) void count_kernel(
    const void* __restrict__ ei1, int e1, const void* __restrict__ ei2, int e2,
    int n, const int* __restrict__ flags, unsigned short* __restrict__ deg16, int SL)
{
    __shared__ int cnt[NRANGE];
    for (int k = threadIdx.x; k < NRANGE; k += 256) cnt[k] = 0;
    __syncthreads();

    const int r = blockIdx.x % RNG;
    const int s = blockIdx.x / RNG;
    const int n2 = 2 * n;
    const int lo = r * NRANGE;
    const int hi = lo + NRANGE;
    const int is32 = flags[1];
    const int E = e1 + e2;
    const int s0 = s * SL;
    const int send = (s0 + SL < E) ? s0 + SL : E;

    for (int base = s0 + (int)threadIdx.x * 4; base < send; base += 2048) {
        int nd[4];
        int nv = send - base; if (nv > 4) nv = 4;
        load_dst4(ei1, e1, ei2, e2, n, is32, base, nv, nd);
        int b1 = base + 1024;
        int nd2[4];
        int nv2 = send - b1; if (nv2 > 4) nv2 = 4;
        if (nv2 > 0) load_dst4(ei1, e1, ei2, e2, n, is32, b1, nv2, nd2);
        else { nd2[0] = nd2[1] = nd2[2] = nd2[3] = -1; }
#pragma unroll
        for (int u = 0; u < 4; ++u)
            if (nd[u] >= lo && nd[u] < hi) atomicAdd(&cnt[nd[u] - lo], 1);
#pragma unroll
        for (int u = 0; u < 4; ++u)
            if (nd2[u] >= lo && nd2[u] < hi) atomicAdd(&cnt[nd2[u] - lo], 1);
    }
    __syncthreads();
    for (int k = threadIdx.x; k < NRANGE; k += 256) {
        int node = lo + k;
        if (node < n2) deg16[(size_t)s * n2 + node] = (unsigned short)cnt[k];
    }
}

__global__ __launch_bounds__(256) void scan1_kernel(const unsigned short* __restrict__ deg16,
                                                    int n2, int* __restrict__ bsum) {
    __shared__ int red[4];
    int i = blockIdx.x * 256 + threadIdx.x;
    int v = 0;
    if (i < n2) {
        for (int r = 0; r < NSLICE; ++r)
            v += deg16[(size_t)r * n2 + i];
    }
#pragma unroll
    for (int off = 32; off > 0; off >>= 1)
        v += __shfl_xor(v, off, 64);
    if ((threadIdx.x & 63) == 0) red[threadIdx.x >> 6] = v;
    __syncthreads();
    if (threadIdx.x == 0) bsum[blockIdx.x] = red[0] + red[1] + red[2] + red[3];
}

__global__ __launch_bounds__(1024) void scan2_kernel(int* __restrict__ bsum, int nb) {
    __shared__ int s[1024];
    int t = threadIdx.x;
    s[t] = (t < nb) ? bsum[t] : 0;
    __syncthreads();
    for (int off = 1; off < 1024; off <<= 1) {
        int v = (t >= off) ? s[t - off] : 0;
        __syncthreads();
        if (t >= off) s[t] += v;
        __syncthreads();
    }
    if (t < nb) bsum[t] = (t == 0) ? 0 : s[t - 1];
}

// rowptr/dinv from per-node totals; rewrites deg16 in place as the exclusive
// prefix over slices (so fill2 gets each slice's base offset without atomics).
__global__ __launch_bounds__(256) void scan3_kernel(unsigned short* __restrict__ deg16, int n2,
                                                    const int* __restrict__ boff,
                                                    int* __restrict__ rowptr,
                                                    float* __restrict__ dinv) {
    __shared__ int sm[256];
    int t = threadIdx.x;
    int i = blockIdx.x * 256 + t;
    int v = 0;
    if (i < n2) {
        for (int r = 0; r < NSLICE; ++r) {
            size_t idx = (size_t)r * n2 + i;
            int c = deg16[idx];
            deg16[idx] = (unsigned short)v;   // exclusive prefix over slices
            v += c;
        }
    }
    sm[t] = v;
    __syncthreads();
    for (int off = 1; off < 256; off <<= 1) {
        int u = (t >= off) ? sm[t - off] : 0;
        __syncthreads();
        if (t >= off) sm[t] += u;
        __syncthreads();
    }
    int base = boff[blockIdx.x];
    if (i < n2) {
        rowptr[i] = base + sm[t] - v;
        dinv[i] = rsqrtf((float)v + 1.0f);
        if (i == n2 - 1) rowptr[n2] = base + sm[t];
    }
}

// re-count in LDS; slot = rowptr[dst] + pre16[s][dst] + lds_rank; scatter srcs.
__global__ __launch_bounds__(256) void fill2_kernel(
    const void* __restrict__ ei1, int e1, const void* __restrict__ ei2, int e2,
    int n, const int* __restrict__ flags, const int* __restrict__ rowptr,
    const unsigned short* __restrict__ pre16, int* __restrict__ srcs, int SL)
{
    __shared__ int cnt[NRANGE];
    for (int k = threadIdx.x; k < NRANGE; k += 256) cnt[k] = 0;
    __syncthreads();

    const int r = blockIdx.x % RNG;
    const int s = blockIdx.x / RNG;
    const int n2 = 2 * n;
    const int lo = r * NRANGE;
    const int hi = lo + NRANGE;
    const int is32 = flags[1];
    const int E = e1 + e2;
    const int s0 = s * SL;
    const int send = (s0 + SL < E) ? s0 + SL : E;
    const unsigned short* pre = pre16 + (size_t)s * n2;

    for (int base = s0 + (int)threadIdx.x * 4; base < send; base += 2048) {
#pragma unroll
        for (int half = 0; half < 2; ++half) {
            int b = base + half * 1024;
            int nv = send - b; if (nv > 4) nv = 4;
            if (nv <= 0) continue;
            int nd[4];
            load_dst4(ei1, e1, ei2, e2, n, is32, b, nv, nd);
#pragma unroll
            for (int u = 0; u < 4; ++u) {
                if (nd[u] >= lo && nd[u] < hi) {
                    int i = b + u;
                    int sv = (i < e1) ? load_edge(ei1, is32, i)
                                      : load_edge(ei2, is32, i - e1);
                    int rk = atomicAdd(&cnt[nd[u] - lo], 1);
                    srcs[rowptr[nd[u]] + (int)pre[nd[u]] + rk] = sv;
                }
            }
        }
    }
}

// ---------------- prep: ctx->bf16 + masked-target encoder -> fused[:,64:96] ----------------
__global__ __launch_bounds__(256) void prep_kernel(
    const float* __restrict__ context, const float* __restrict__ target,
    const void* __restrict__ mask, const int* __restrict__ flags,
    const float* __restrict__ mask_token,
    const float* __restrict__ te_W, const float* __restrict__ te_b,
    unsigned short* __restrict__ ctxb, unsigned short* __restrict__ fused, int n)
{
    __shared__ float tbuf[32][32];
    int w = threadIdx.x >> 6;
    int j = threadIdx.x & 63;
    int r0 = __builtin_amdgcn_readfirstlane(blockIdx.x * 32 + w * 8);
    if (r0 >= n) return;  // N % 32 == 0

    const float4* src = (const float4*)(context + (size_t)r0 * 128);
    ushort4v* dst = (ushort4v*)(ctxb + (size_t)r0 * 128);
#pragma unroll
    for (int p = 0; p < 4; ++p) {
        float4 v = src[p * 64 + j];
        ushort4v o;
        o.x = f32_to_bf16(v.x); o.y = f32_to_bf16(v.y);
        o.z = f32_to_bf16(v.z); o.w = f32_to_bf16(v.w);
        dst[p * 64 + j] = o;
    }

    int tr = j >> 5;
    int tj = j & 31;
#pragma unroll
    for (int rr = 0; rr < 4; ++rr) {
        int r = tr + rr * 2;
        long mi = (long)(r0 + r) * 32 + tj;
        int mraw = flags[0] ? (int)((const unsigned char*)mask)[mi]
                            : ((const int*)mask)[mi];
        float m = mraw ? 1.0f : 0.0f;
        tbuf[w * 8 + r][tj] = target[mi] * (1.0f - m) + mask_token[tj] * m;
    }

#pragma unroll
    for (int rr = 0; rr < 4; ++rr) {
        int r = tr + rr * 2;
        float y3 = te_b[tj];
#pragma unroll
        for (int k = 0; k < 32; ++k)
            y3 = fmaf(tbuf[w * 8 + r][k], te_W[k * 32 + tj], y3);
        fused[(long)(r0 + r) * 96 + 64 + tj] = f32_to_bf16(gelu_exact(y3));
    }
}

// ---------------- MFMA encoder layer 1: LN+GELU epilogue ----------------
__global__ __launch_bounds__(256) void mfma_ln_kernel(
    const unsigned short* __restrict__ x, const float* __restrict__ W,
    const float* __restrict__ bias, const float* __restrict__ g,
    const float* __restrict__ beta, unsigned short* __restrict__ y, int n)
{
    constexpr int K = 128, KS = K / 32, STRIDE = K + 8;
    __shared__ __align__(16) unsigned short wt[64 * STRIDE];
    int n0 = threadIdx.x & 63;
    int kk = threadIdx.x >> 6;
    for (int k = kk; k < K; k += 4)
        wt[n0 * STRIDE + k] = f32_to_bf16(W[k * 64 + n0]);
    __syncthreads();

    int w = threadIdx.x >> 6;
    int lane = threadIdx.x & 63;
    int c = lane & 15;
    int q = lane >> 4;

    short8 bfrag[KS][4];
#pragma unroll
    for (int s = 0; s < KS; ++s)
#pragma unroll
        for (int nt = 0; nt < 4; ++nt)
            bfrag[s][nt] = *(const short8*)&wt[(nt * 16 + c) * STRIDE + s * 32 + q * 8];

    float bs[4], gs[4], be[4];
#pragma unroll
    for (int nt = 0; nt < 4; ++nt) {
        bs[nt] = bias[nt * 16 + c];
        gs[nt] = g[nt * 16 + c];
        be[nt] = beta[nt * 16 + c];
    }

    int T = n >> 4;
    int stride = gridDim.x * 4;
    for (int t = __builtin_amdgcn_readfirstlane(blockIdx.x * 4 + w); t < T; t += stride) {
        int r0 = t << 4;
        const unsigned short* xa = x + (size_t)(r0 + c) * K + q * 8;
        float4v acc[4] = {{0,0,0,0},{0,0,0,0},{0,0,0,0},{0,0,0,0}};
#pragma unroll
        for (int s = 0; s < KS; ++s) {
            short8 a = *(const short8*)(xa + s * 32);
#pragma unroll
            for (int nt = 0; nt < 4; ++nt)
                acc[nt] = __builtin_amdgcn_mfma_f32_16x16x32_bf16(a, bfrag[s][nt], acc[nt], 0, 0, 0);
        }
#pragma unroll
        for (int reg = 0; reg < 4; ++reg) {
            float v0 = acc[0][reg] + bs[0];
            float v1 = acc[1][reg] + bs[1];
            float v2 = acc[2][reg] + bs[2];
            float v3 = acc[3][reg] + bs[3];
            float mean = qsum16((v0 + v1) + (v2 + v3)) * (1.0f / 64.0f);
            float x0 = v0 - mean, x1 = v1 - mean, x2 = v2 - mean, x3 = v3 - mean;
            float var = qsum16((x0 * x0 + x1 * x1) + (x2 * x2 + x3 * x3)) * (1.0f / 64.0f);
            float rstd = rsqrtf(var + LN_EPS);
            size_t row = (size_t)(r0 + q * 4 + reg) * 64;
            y[row + 0 * 16 + c] = f32_to_bf16(gelu_exact(x0 * rstd * gs[0] + be[0]));
            y[row + 1 * 16 + c] = f32_to_bf16(gelu_exact(x1 * rstd * gs[1] + be[1]));
            y[row + 2 * 16 + c] = f32_to_bf16(gelu_exact(x2 * rstd * gs[2] + be[2]));
            y[row + 3 * 16 + c] = f32_to_bf16(gelu_exact(x3 * rstd * gs[3] + be[3]));
        }
    }
}

// ---------------- MFMA encoder layer 2: GELU epilogue, output stride 96 ----------------
__global__ __launch_bounds__(256) void mfma_gelu_kernel(
    const unsigned short* __restrict__ x, const float* __restrict__ W,
    const float* __restrict__ bias, unsigned short* __restrict__ y, int n)
{
    constexpr int K = 64, KS = K / 32, STRIDE = K + 8;
    __shared__ __align__(16) unsigned short wt[64 * STRIDE];
    int n0 = threadIdx.x & 63;
    int kk = threadIdx.x >> 6;
    for (int k = kk; k < K; k += 4)
        wt[n0 * STRIDE + k] = f32_to_bf16(W[k * 64 + n0]);
    __syncthreads();

    int w = threadIdx.x >> 6;
    int lane = threadIdx.x & 63;
    int c = lane & 15;
    int q = lane >> 4;

    short8 bfrag[KS][4];
#pragma unroll
    for (int s = 0; s < KS; ++s)
#pragma unroll
        for (int nt = 0; nt < 4; ++nt)
            bfrag[s][nt] = *(const short8*)&wt[(nt * 16 + c) * STRIDE + s * 32 + q * 8];

    float bs[4];
#pragma unroll
    for (int nt = 0; nt < 4; ++nt) bs[nt] = bias[nt * 16 + c];

    int T = n >> 4;
    int stride = gridDim.x * 4;
    for (int t = __builtin_amdgcn_readfirstlane(blockIdx.x * 4 + w); t < T; t += stride) {
        int r0 = t << 4;
        const unsigned short* xa = x + (size_t)(r0 + c) * K + q * 8;
        float4v acc[4] = {{0,0,0,0},{0,0,0,0},{0,0,0,0},{0,0,0,0}};
#pragma unroll
        for (int s = 0; s < KS; ++s) {
            short8 a = *(const short8*)(xa + s * 32);
#pragma unroll
            for (int nt = 0; nt < 4; ++nt)
                acc[nt] = __builtin_amdgcn_mfma_f32_16x16x32_bf16(a, bfrag[s][nt], acc[nt], 0, 0, 0);
        }
#pragma unroll
        for (int nt = 0; nt < 4; ++nt)
#pragma unroll
            for (int reg = 0; reg < 4; ++reg)
                y[(size_t)(r0 + q * 4 + reg) * 96 + nt * 16 + c] =
                    f32_to_bf16(gelu_exact(acc[nt][reg] + bs[nt]));
    }
}

// ---------------- MFMA GCN matmul: y_bf16 = (x @ W) * scale[row] ----------------
template <int K>
__global__ __launch_bounds__(256) void mfma_matmul(const unsigned short* __restrict__ x,
                                                   const float* __restrict__ W,
                                                   const float* __restrict__ scale,
                                                   unsigned short* __restrict__ y, int n) {
    constexpr int KS = K / 32;
    constexpr int STRIDE = K + 8;
    __shared__ __align__(16) unsigned short wt[64 * STRIDE];

    int n0 = threadIdx.x & 63;
    int kk = threadIdx.x >> 6;
    for (int k = kk; k < K; k += 4)
        wt[n0 * STRIDE + k] = f32_to_bf16(W[k * 64 + n0]);
    __syncthreads();

    int w = threadIdx.x >> 6;
    int lane = threadIdx.x & 63;
    int c = lane & 15;
    int q = lane >> 4;

    short8 bfrag[KS][4];
#pragma unroll
    for (int s = 0; s < KS; ++s)
#pragma unroll
        for (int nt = 0; nt < 4; ++nt)
            bfrag[s][nt] = *(const short8*)&wt[(nt * 16 + c) * STRIDE + s * 32 + q * 8];

    int T = n >> 4;
    int stride = gridDim.x * 4;
    for (int t = __builtin_amdgcn_readfirstlane(blockIdx.x * 4 + w); t < T; t += stride) {
        int r0 = t << 4;
        const unsigned short* xa = x + (size_t)(r0 + c) * K + q * 8;
        float4v acc[4] = {{0,0,0,0},{0,0,0,0},{0,0,0,0},{0,0,0,0}};
#pragma unroll
        for (int s = 0; s < KS; ++s) {
            short8 a = *(const short8*)(xa + s * 32);
#pragma unroll
            for (int nt = 0; nt < 4; ++nt)
                acc[nt] = __builtin_amdgcn_mfma_f32_16x16x32_bf16(a, bfrag[s][nt], acc[nt], 0, 0, 0);
        }
        float sc[4];
#pragma unroll
        for (int reg = 0; reg < 4; ++reg)
            sc[reg] = scale[r0 + q * 4 + reg];
#pragma unroll
        for (int nt = 0; nt < 4; ++nt)
#pragma unroll
            for (int reg = 0; reg < 4; ++reg)
                y[(size_t)(r0 + q * 4 + reg) * 64 + nt * 16 + c] = f32_to_bf16(acc[nt][reg] * sc[reg]);
    }
}

// ---------------- gather + fused finalize (wave/node; lin pre-scaled by dinv) ----------------
// mode 0: outb = bf16(gelu(pre))
// mode 1: outf = a*pre                     (fp32 partial)
// mode 2: outb = bf16(outf + (1-a)*pre)    (gated combine -> bf16 for MFMA head)
__global__ __launch_bounds__(256) void gather_kernel(
    const int* __restrict__ rowptr, const int* __restrict__ srcs,
    const float* __restrict__ dinv, const unsigned short* __restrict__ lin,
    const float* __restrict__ b, const float* __restrict__ alpha_ptr, int mode,
    unsigned short* __restrict__ outb, float* __restrict__ outf, int n)
{
    int w = threadIdx.x >> 6;
    int j = threadIdx.x & 63;
    int node = __builtin_amdgcn_readfirstlane(blockIdx.x * 4 + w);
    if (node >= n) return;

    int beg = rowptr[node];
    int end = rowptr[node + 1];
    float acc = 0.0f;
    for (int base = beg; base < end; base += 64) {
        int cnt = end - base;
        if (cnt > 64) cnt = 64;
        int sj = (j < cnt) ? srcs[base + j] : 0;
        int t = 0;
        for (; t + 8 <= cnt; t += 8) {
            float v[8];
#pragma unroll
            for (int u = 0; u < 8; ++u) {
                int s = __shfl(sj, t + u, 64);
                v[u] = bf16_to_f32(lin[(long)s * 64 + j]);
            }
            acc += ((v[0] + v[1]) + (v[2] + v[3])) + ((v[4] + v[5]) + (v[6] + v[7]));
        }
        for (; t < cnt; ++t) {
            int s = __shfl(sj, t, 64);
            acc += bf16_to_f32(lin[(long)s * 64 + j]);
        }
    }
    float dd = dinv[node];
    float pre = fmaf(dd, acc + bf16_to_f32(lin[(long)node * 64 + j]), b[j]);

    long oi = (long)node * 64 + j;
    if (mode == 0) {
        outb[oi] = f32_to_bf16(gelu_exact(pre));
    } else {
        float a = 1.0f / (1.0f + expf(-alpha_ptr[0]));
        if (mode == 1) outf[oi] = a * pre;
        else           outb[oi] = f32_to_bf16(outf[oi] + (1.0f - a) * pre);
    }
}

// ---------------- MFMA head: [hb|fused] @ W1 -> LN -> gelu -> @ W2 + b2 ----------------
__global__ __launch_bounds__(256) void head_mfma_kernel(
    const unsigned short* __restrict__ hb, const unsigned short* __restrict__ fused,
    const float* __restrict__ h_W1, const float* __restrict__ h_b1,
    const float* __restrict__ h_g, const float* __restrict__ h_beta,
    const float* __restrict__ h_W2, const float* __restrict__ h_b2,
    float* __restrict__ out, int n)
{
    constexpr int ST1 = 168;  // 160 + 8
    constexpr int ST2 = 72;   // 64 + 8
    __shared__ __align__(16) unsigned short wt1[64 * ST1];     // 21504 B
    __shared__ __align__(16) unsigned short wt2[32 * ST2];     // 4608 B
    __shared__ __align__(16) unsigned short zl[4][16 * ST2];   // 9216 B

    int n0 = threadIdx.x & 63;
    int kk = threadIdx.x >> 6;
    for (int k = kk; k < 160; k += 4)
        wt1[n0 * ST1 + k] = f32_to_bf16(h_W1[k * 64 + n0]);
    if (n0 < 32)
        for (int k = kk; k < 64; k += 4)
            wt2[n0 * ST2 + k] = f32_to_bf16(h_W2[k * 32 + n0]);
    __syncthreads();

    int w = threadIdx.x >> 6;
    int lane = threadIdx.x & 63;
    int c = lane & 15;
    int q = lane >> 4;

    short8 b1f[5][4];
#pragma unroll
    for (int s = 0; s < 5; ++s)
#pragma unroll
        for (int nt = 0; nt < 4; ++nt)
            b1f[s][nt] = *(const short8*)&wt1[(nt * 16 + c) * ST1 + s * 32 + q * 8];
    short8 b2f[2][2];
#pragma unroll
    for (int s = 0; s < 2; ++s)
#pragma unroll
        for (int nt = 0; nt < 2; ++nt)
            b2f[s][nt] = *(const short8*)&wt2[(nt * 16 + c) * ST2 + s * 32 + q * 8];

    float bs[4], gs[4], be[4];
#pragma unroll
    for (int nt = 0; nt < 4; ++nt) {
        bs[nt] = h_b1[nt * 16 + c];
        gs[nt] = h_g[nt * 16 + c];
        be[nt] = h_beta[nt * 16 + c];
    }
    float b2s[2];
#pragma unroll
    for (int nt = 0; nt < 2; ++nt) b2s[nt] = h_b2[nt * 16 + c];

    unsigned short* zw = zl[w];
    int T = n >> 4;
    int stride = gridDim.x * 4;
    for (int t = __builtin_amdgcn_readfirstlane(blockIdx.x * 4 + w); t < T; t += stride) {
        int r0 = t << 4;
        // stage 1: K=160 (hb: k 0..63, fused: k 64..159)
        const unsigned short* xh = hb + (size_t)(r0 + c) * 64 + q * 8;
        const unsigned short* xf = fused + (size_t)(r0 + c) * 96 + q * 8;
        float4v acc[4] = {{0,0,0,0},{0,0,0,0},{0,0,0,0},{0,0,0,0}};
#pragma unroll
        for (int s = 0; s < 2; ++s) {
            short8 a = *(const short8*)(xh + s * 32);
#pragma unroll
            for (int nt = 0; nt < 4; ++nt)
                acc[nt] = __builtin_amdgcn_mfma_f32_16x16x32_bf16(a, b1f[s][nt], acc[nt], 0, 0, 0);
        }
#pragma unroll
        for (int s = 0; s < 3; ++s) {
            short8 a = *(const short8*)(xf + s * 32);
#pragma unroll
            for (int nt = 0; nt < 4; ++nt)
                acc[nt] = __builtin_amdgcn_mfma_f32_16x16x32_bf16(a, b1f[2 + s][nt], acc[nt], 0, 0, 0);
        }
        // epilogue: +b1, LN per row (q*4+reg), gelu -> zl (wave-private)
#pragma unroll
        for (int reg = 0; reg < 4; ++reg) {
            float v0 = acc[0][reg] + bs[0];
            float v1 = acc[1][reg] + bs[1];
            float v2 = acc[2][reg] + bs[2];
            float v3 = acc[3][reg] + bs[3];
            float mean = qsum16((v0 + v1) + (v2 + v3)) * (1.0f / 64.0f);
            float x0 = v0 - mean, x1 = v1 - mean, x2 = v2 - mean, x3 = v3 - mean;
            float var = qsum16((x0 * x0 + x1 * x1) + (x2 * x2 + x3 * x3)) * (1.0f / 64.0f);
            float rstd = rsqrtf(var + LN_EPS);
            int row = q * 4 + reg;
            zw[row * ST2 + 0 * 16 + c] = f32_to_bf16(gelu_exact(x0 * rstd * gs[0] + be[0]));
            zw[row * ST2 + 1 * 16 + c] = f32_to_bf16(gelu_exact(x1 * rstd * gs[1] + be[1]));
            zw[row * ST2 + 2 * 16 + c] = f32_to_bf16(gelu_exact(x2 * rstd * gs[2] + be[2]));
            zw[row * ST2 + 3 * 16 + c] = f32_to_bf16(gelu_exact(x3 * rstd * gs[3] + be[3]));
        }
        // stage 2: z (16x64) @ W2 (64x32); same-wave LDS write->read, no barrier
        float4v acc2[2] = {{0,0,0,0},{0,0,0,0}};
#pragma unroll
        for (int s = 0; s < 2; ++s) {
            short8 a2 = *(const short8*)&zw[c * ST2 + s * 32 + q * 8];
#pragma unroll
            for (int nt = 0; nt < 2; ++nt)
                acc2[nt] = __builtin_amdgcn_mfma_f32_16x16x32_bf16(a2, b2f[s][nt], acc2[nt], 0, 0, 0);
        }
#pragma unroll
        for (int nt = 0; nt < 2; ++nt)
#pragma unroll
            for (int reg = 0; reg < 4; ++reg)
                out[(size_t)(r0 + q * 4 + reg) * 32 + nt * 16 + c] = acc2[nt][reg] + b2s[nt];
    }
}

extern "C" void kernel_launch(void* const* d_in, const int* in_sizes, int n_in,
                              void* d_out, int out_size, void* d_ws, size_t ws_size,
                              hipStream_t stream) {
    const float* context    = (const float*)d_in[0];
    const float* target     = (const float*)d_in[1];
    const void*  mask       = d_in[2];
    const void*  adj_ei     = d_in[3];
    const void*  tr_ei      = d_in[4];
    const float* mask_token = (const float*)d_in[5];
    const float* ce_W1 = (const float*)d_in[6];
    const float* ce_b1 = (const float*)d_in[7];
    const float* ce_g  = (const float*)d_in[8];
    const float* ce_be = (const float*)d_in[9];
    const float* ce_W2 = (const float*)d_in[10];
    const float* ce_b2 = (const float*)d_in[11];
    const float* te_W  = (const float*)d_in[12];
    const float* te_b  = (const float*)d_in[13];
    const float* g1_W  = (const float*)d_in[14];
    const float* g1_b  = (const float*)d_in[15];
    const float* g2_W  = (const float*)d_in[16];
    const float* g2_b  = (const float*)d_in[17];
    const float* t1_W  = (const float*)d_in[18];
    const float* t1_b  = (const float*)d_in[19];
    const float* t2_W  = (const float*)d_in[20];
    const float* t2_b  = (const float*)d_in[21];
    const float* alpha = (const float*)d_in[22];
    const float* h_W1  = (const float*)d_in[23];
    const float* h_b1  = (const float*)d_in[24];
    const float* h_g   = (const float*)d_in[25];
    const float* h_be  = (const float*)d_in[26];
    const float* h_W2  = (const float*)d_in[27];
    const float* h_b2  = (const float*)d_in[28];

    const int N  = in_sizes[0] / 128;
    const int E1 = in_sizes[3] / 2;
    const int E2 = in_sizes[4] / 2;
    const int E  = E1 + E2;
    const int N2 = 2 * N;
    const int nb = (N2 + 255) / 256;

    // ---- workspace layout ----
    char* p = (char*)d_ws;
    int*   flags  = (int*)p;                    p += 256;
    unsigned short* ctxb  = (unsigned short*)p; p += (size_t)N * 128 * 2;
    unsigned short* fused = (unsigned short*)p; p += (size_t)N * 96 * 2;
    unsigned short* cb    = (unsigned short*)p; p += (size_t)N * 64 * 2;
    unsigned short* lin   = (unsigned short*)p; p += (size_t)N * 64 * 2;
    unsigned short* h1    = (unsigned short*)p; p += (size_t)N * 64 * 2;
    unsigned short* hb    = (unsigned short*)p; p += (size_t)N * 64 * 2;
    float* hacc   = (float*)p;                  p += (size_t)N * 64 * 4;
    float* dinv   = (float*)p;                  p += (size_t)N2 * 4;
    int*   rowptr = (int*)p;                    p += (size_t)(N2 + 64) * 4;
    int*   bsum   = (int*)p;                    p += 1024 * 4;
    int*   srcs   = (int*)p;                    p += (size_t)E * 4;
    // per-slice degree counts / prefixes (NSLICE * N2 u16 = 25.6 MB) alias hacc:
    // deg16 is dead after fill2; hacc is first written by gather mode 1 (later).
    unsigned short* deg16 = (unsigned short*)hacc;
    float* out    = (float*)d_out;

    const unsigned rowBlocks32 = (unsigned)((N + 31) / 32);
    const unsigned nodeBlocks  = (unsigned)((N + 3) / 4);
    const unsigned csrBlocks   = (unsigned)(RNG * NSLICE);
    const unsigned mmBlocks    = 391;
    const int SL = (((E + NSLICE - 1) / NSLICE) + 3) & ~3;  // slice size, mult of 4

    detect_kernel<<<1, 256, 0, stream>>>((const unsigned char*)mask, (const int*)adj_ei, flags);

    // ---- CSR build (both graphs; atomic-free) ----
    count_kernel<<<csrBlocks, 256, 0, stream>>>(adj_ei, E1, tr_ei, E2, N, flags, deg16, SL);
    scan1_kernel<<<nb, 256, 0, stream>>>(deg16, N2, bsum);
    scan2_kernel<<<1, 1024, 0, stream>>>(bsum, nb);
    scan3_kernel<<<nb, 256, 0, stream>>>(deg16, N2, bsum, rowptr, dinv);
    fill2_kernel<<<csrBlocks, 256, 0, stream>>>(adj_ei, E1, tr_ei, E2, N, flags, rowptr,
                                                deg16, srcs, SL);

    // ---- encoder ----
    prep_kernel<<<rowBlocks32, 256, 0, stream>>>(context, target, mask, flags, mask_token,
                                                 te_W, te_b, ctxb, fused, N);
    mfma_ln_kernel<<<mmBlocks, 256, 0, stream>>>(ctxb, ce_W1, ce_b1, ce_g, ce_be, cb, N);
    mfma_gelu_kernel<<<mmBlocks, 256, 0, stream>>>(cb, ce_W2, ce_b2, fused, N);

    const float* dinv_a = dinv;
    const float* dinv_t = dinv + N;
    const int*   row_a  = rowptr;
    const int*   row_t  = rowptr + N;

    // ---- spatial branch ----
    mfma_matmul<96><<<mmBlocks, 256, 0, stream>>>(fused, g1_W, dinv_a, lin, N);
    gather_kernel<<<nodeBlocks, 256, 0, stream>>>(row_a, srcs, dinv_a, lin, g1_b, alpha, 0, h1, hacc, N);
    mfma_matmul<64><<<mmBlocks, 256, 0, stream>>>(h1, g2_W, dinv_a, lin, N);
    gather_kernel<<<nodeBlocks, 256, 0, stream>>>(row_a, srcs, dinv_a, lin, g2_b, alpha, 1, hb, hacc, N);

    // ---- transit branch ----
    mfma_matmul<96><<<mmBlocks, 256, 0, stream>>>(fused, t1_W, dinv_t, lin, N);
    gather_kernel<<<nodeBlocks, 256, 0, stream>>>(row_t, srcs, dinv_t, lin, t1_b, alpha, 0, h1, hacc, N);
    mfma_matmul<64><<<mmBlocks, 256, 0, stream>>>(h1, t2_W, dinv_t, lin, N);
    gather_kernel<<<nodeBlocks, 256, 0, stream>>>(row_t, srcs, dinv_t, lin, t2_b, alpha, 2, hb, hacc, N);

    // ---- head (MFMA) ----
    head_mfma_kernel<<<mmBlocks, 256, 0, stream>>>(hb, fused, h_W1, h_b1, h_g, h_be,
                                                   h_W2, h_b2, out, N);
}

// Round 3
// 572.930 us; speedup vs baseline: 1.2328x; 1.2328x over previous
//
#include <hip/hip_runtime.h>
#include <math.h>

// UrbanModelV2: encoder MLPs -> 4x GCNConv (2 graphs) -> gated combine -> LN-MLP head.
// N=100000, CTX=128, TGT=32, H=64, FUS=96, E1=1.6M, E2=0.8M. fp32 in/out.
//
// R12: CSR build rewritten as two-level partition (R11's range x slice matrix paid
//   13x redundancy twice at 17% occupancy; R9's degcount hit the flat ~24.5G/s
//   device-atomic cap). passp: block-local LDS histogram over 512-node ranges,
//   ONE global atomic per (block,range) (~229K atomics vs 2.4M), scatter edges
//   into per-range buckets (coalesced-ish runs). rscan: 391-entry prefix. passq:
//   one block per range builds exact per-node CSR in LDS and scatters srcs into
//   its own contiguous region (single-writer, cache-local). Order within a node's
//   neighbor list is arbitrary (fp-sum reorder only).

#define LN_EPS 1e-5f
#define RANGE_BITS 9
#define RANGE_SZ 512
#define MAXR 512            // max ranges supported (N2 <= 262144)
#define PASSP_EDGES 4096

typedef __attribute__((ext_vector_type(8))) short short8;            // 8 bf16
typedef __attribute__((ext_vector_type(4))) float float4v;           // MFMA acc
typedef __attribute__((ext_vector_type(4))) unsigned short ushort4v; // 4 bf16

__device__ __forceinline__ float gelu_exact(float x) {
    return 0.5f * x * (1.0f + erff(x * 0.70710678118654752440f));
}

// reduce across the 16-lane quad-group (lane masks 1..8 stay within group)
__device__ __forceinline__ float qsum16(float v) {
#pragma unroll
    for (int m = 1; m < 16; m <<= 1)
        v += __shfl_xor(v, m, 64);
    return v;
}

__device__ __forceinline__ int load_edge(const void* ei, int is32, long idx) {
    return is32 ? ((const int*)ei)[idx] : (int)((const long long*)ei)[idx];
}

__device__ __forceinline__ unsigned short f32_to_bf16(float f) {
    unsigned int x = __float_as_uint(f);
    x += 0x7fffu + ((x >> 16) & 1u);   // RNE, finite values
    return (unsigned short)(x >> 16);
}
__device__ __forceinline__ float bf16_to_f32(unsigned short u) {
    return __uint_as_float((unsigned int)u << 16);
}

// load dst-nodes (transit offset by n) for edges base..base+3; nv = #valid
__device__ __forceinline__ void load_dst4(const void* ei1, int e1, const void* ei2, int e2,
                                          int n, int is32, int base, int nv, int nd[4]) {
    if (is32 && nv == 4) {
        if (base + 3 < e1 && (((e1 + base) & 3) == 0)) {
            int4 v = *(const int4*)((const int*)ei1 + (size_t)e1 + base);
            nd[0] = v.x; nd[1] = v.y; nd[2] = v.z; nd[3] = v.w;
            return;
        }
        if (base >= e1 && (((e2 + base - e1) & 3) == 0)) {
            int4 v = *(const int4*)((const int*)ei2 + (size_t)e2 + (base - e1));
            nd[0] = v.x + n; nd[1] = v.y + n; nd[2] = v.z + n; nd[3] = v.w + n;
            return;
        }
    }
#pragma unroll
    for (int u = 0; u < 4; ++u) {
        int i = base + u;
        if (u >= nv) { nd[u] = -1; continue; }
        if (i < e1) nd[u] = load_edge(ei1, is32, (long)e1 + i);
        else        nd[u] = load_edge(ei2, is32, (long)e2 + (i - e1)) + n;
    }
}

// load src-nodes for edges base..base+3; nv = #valid
__device__ __forceinline__ void load_src4(const void* ei1, int e1, const void* ei2, int e2,
                                          int is32, int base, int nv, int ns[4]) {
    if (is32 && nv == 4) {
        if (base + 3 < e1 && ((base & 3) == 0)) {
            int4 v = *(const int4*)((const int*)ei1 + base);
            ns[0] = v.x; ns[1] = v.y; ns[2] = v.z; ns[3] = v.w;
            return;
        }
        if (base >= e1 && (((base - e1) & 3) == 0)) {
            int4 v = *(const int4*)((const int*)ei2 + (base - e1));
            ns[0] = v.x; ns[1] = v.y; ns[2] = v.z; ns[3] = v.w;
            return;
        }
    }
#pragma unroll
    for (int u = 0; u < 4; ++u) {
        int i = base + u;
        if (u >= nv) { ns[u] = 0; continue; }
        if (i < e1) ns[u] = load_edge(ei1, is32, i);
        else        ns[u] = load_edge(ei2, is32, (long)(i - e1));
    }
}

// ---------------- dtype detection ----------------
__global__ __launch_bounds__(256) void detect_kernel(const unsigned char* __restrict__ mask_bytes,
                                                     const int* __restrict__ ei_words,
                                                     int* __restrict__ flags) {
    __shared__ int f0, f1;
    if (threadIdx.x == 0) { f0 = 0; f1 = 0; }
    __syncthreads();
    int i = threadIdx.x;
    if ((i & 3) != 0 && mask_bytes[i] != 0) f0 = 1;
    if (i < 64 && ei_words[2 * i + 1] != 0) f1 = 1;
    __syncthreads();
    if (threadIdx.x == 0) { flags[0] = f0; flags[1] = f1; }
}

// ---------------- CSR stage 0: init per-range cursors ----------------
__global__ __launch_bounds__(256) void initcur_kernel(int* __restrict__ gcur, int cap) {
    int r = blockIdx.x * 256 + threadIdx.x;
    if (r < MAXR) gcur[r] = r * cap;
}

// ---------------- CSR stage 1: partition edges into 512-node range buckets ----------------
// per block: LDS histogram over ranges -> 1 global atomic per (block,range) -> scatter.
__global__ __launch_bounds__(256) void passp_kernel(
    const void* __restrict__ ei1, int e1, const void* __restrict__ ei2, int e2,
    int n, const int* __restrict__ flags, int* __restrict__ gcur, int cap,
    int* __restrict__ ebuf_src, unsigned short* __restrict__ ebuf_ld)
{
    __shared__ int hist[MAXR];
    __shared__ int base[MAXR];
    const int E = e1 + e2;
    const int is32 = flags[1];
    const int b0 = blockIdx.x * PASSP_EDGES;
    const int bend = (b0 + PASSP_EDGES < E) ? b0 + PASSP_EDGES : E;

    for (int k = threadIdx.x; k < MAXR; k += 256) hist[k] = 0;
    __syncthreads();

    // pass 1: histogram dst ranges (keep dsts in registers for pass 2)
    int nd[16];
#pragma unroll
    for (int j = 0; j < 4; ++j) {
        int bi = b0 + j * 1024 + (int)threadIdx.x * 4;
        int nv = bend - bi; nv = (nv < 0) ? 0 : (nv > 4 ? 4 : nv);
        load_dst4(ei1, e1, ei2, e2, n, is32, bi, nv, &nd[j * 4]);
#pragma unroll
        for (int u = 0; u < 4; ++u)
            if (u < nv) atomicAdd(&hist[nd[j * 4 + u] >> RANGE_BITS], 1);
    }
    __syncthreads();

    // allocate: one device atomic per nonempty (block,range)
    for (int r = threadIdx.x; r < MAXR; r += 256) {
        int c = hist[r];
        base[r] = c ? atomicAdd(&gcur[r], c) : 0;
        hist[r] = 0;   // reuse as local cursor
    }
    __syncthreads();

    // pass 2: scatter (src, local-dst) into range buckets
#pragma unroll
    for (int j = 0; j < 4; ++j) {
        int bi = b0 + j * 1024 + (int)threadIdx.x * 4;
        int nv = bend - bi; nv = (nv < 0) ? 0 : (nv > 4 ? 4 : nv);
        int sv[4];
        load_src4(ei1, e1, ei2, e2, is32, bi, nv, sv);
#pragma unroll
        for (int u = 0; u < 4; ++u) {
            if (u < nv) {
                int d = nd[j * 4 + u];
                int r = d >> RANGE_BITS;
                int pos = base[r] + atomicAdd(&hist[r], 1);
                if (pos < (r + 1) * cap) {   // capacity guard
                    ebuf_src[pos] = sv[u];
                    ebuf_ld[pos] = (unsigned short)(d & (RANGE_SZ - 1));
                }
            }
        }
    }
}

// ---------------- CSR stage 2: prefix over range totals ----------------
__global__ __launch_bounds__(512) void rscan_kernel(const int* __restrict__ gcur,
                                                    int nranges, int cap, int E,
                                                    int* __restrict__ rstart,
                                                    int* __restrict__ rowptr, int n2) {
    __shared__ int s[512];
    int t = threadIdx.x;
    int tot = (t < nranges) ? (gcur[t] - t * cap) : 0;
    s[t] = tot;
    __syncthreads();
    for (int off = 1; off < 512; off <<= 1) {
        int v = (t >= off) ? s[t - off] : 0;
        __syncthreads();
        if (t >= off) s[t] += v;
        __syncthreads();
    }
    if (t < nranges) rstart[t] = s[t] - tot;
    if (t == 0) { rstart[nranges] = E; rowptr[n2] = E; }
}

// ---------------- CSR stage 3: per-range CSR build (one block per range) ----------------
__global__ __launch_bounds__(256) void passq_kernel(
    const int* __restrict__ rstart, const int* __restrict__ ebuf_src,
    const unsigned short* __restrict__ ebuf_ld, int cap, int n2,
    int* __restrict__ rowptr, float* __restrict__ dinv, int* __restrict__ srcs)
{
    __shared__ int deg[RANGE_SZ];
    __shared__ int cur[RANGE_SZ];
    __shared__ int ws[256];
    const int g = blockIdx.x;
    const int t = threadIdx.x;
    const int lo = g << RANGE_BITS;
    const int gbase = rstart[g];
    const int total = rstart[g + 1] - gbase;
    const int* es = ebuf_src + (size_t)g * cap;
    const unsigned short* el = ebuf_ld + (size_t)g * cap;

    deg[2 * t] = 0; deg[2 * t + 1] = 0;
    __syncthreads();
    for (int i = t; i < total; i += 256)
        atomicAdd(&deg[el[i]], 1);
    __syncthreads();

    // block scan over 512 (2 elems per thread)
    int a0 = deg[2 * t], a1 = deg[2 * t + 1];
    ws[t] = a0 + a1;
    __syncthreads();
    for (int off = 1; off < 256; off <<= 1) {
        int v = (t >= off) ? ws[t - off] : 0;
        __syncthreads();
        if (t >= off) ws[t] += v;
        __syncthreads();
    }
    int ex = t ? ws[t - 1] : 0;  // exclusive over pairs
    cur[2 * t] = ex;
    cur[2 * t + 1] = ex + a0;
    int n0 = lo + 2 * t, n1 = lo + 2 * t + 1;
    if (n0 < n2) { rowptr[n0] = gbase + ex;      dinv[n0] = rsqrtf((float)a0 + 1.0f); }
    if (n1 < n2) { rowptr[n1] = gbase + ex + a0; dinv[n1] = rsqrtf((float)a1 + 1.0f); }
    __syncthreads();

    // scatter into this range's contiguous CSR region (single writer)
    for (int i = t; i < total; i += 256) {
        int ld = el[i];
        int rk = atomicAdd(&cur[ld], 1);
        srcs[gbase + rk] = es[i];
    }
}

// ---------------- prep: ctx->bf16 + masked-target encoder -> fused[:,64:96] ----------------
__global__ __launch_bounds__(256) void prep_kernel(
    const float* __restrict__ context, const float* __restrict__ target,
    const void* __restrict__ mask, const int* __restrict__ flags,
    const float* __restrict__ mask_token,
    const float* __restrict__ te_W, const float* __restrict__ te_b,
    unsigned short* __restrict__ ctxb, unsigned short* __restrict__ fused, int n)
{
    __shared__ float tbuf[32][32];
    int w = threadIdx.x >> 6;
    int j = threadIdx.x & 63;
    int r0 = __builtin_amdgcn_readfirstlane(blockIdx.x * 32 + w * 8);
    if (r0 >= n) return;  // N % 32 == 0

    const float4* src = (const float4*)(context + (size_t)r0 * 128);
    ushort4v* dst = (ushort4v*)(ctxb + (size_t)r0 * 128);
#pragma unroll
    for (int p = 0; p < 4; ++p) {
        float4 v = src[p * 64 + j];
        ushort4v o;
        o.x = f32_to_bf16(v.x); o.y = f32_to_bf16(v.y);
        o.z = f32_to_bf16(v.z); o.w = f32_to_bf16(v.w);
        dst[p * 64 + j] = o;
    }

    int tr = j >> 5;
    int tj = j & 31;
#pragma unroll
    for (int rr = 0; rr < 4; ++rr) {
        int r = tr + rr * 2;
        long mi = (long)(r0 + r) * 32 + tj;
        int mraw = flags[0] ? (int)((const unsigned char*)mask)[mi]
                            : ((const int*)mask)[mi];
        float m = mraw ? 1.0f : 0.0f;
        tbuf[w * 8 + r][tj] = target[mi] * (1.0f - m) + mask_token[tj] * m;
    }

#pragma unroll
    for (int rr = 0; rr < 4; ++rr) {
        int r = tr + rr * 2;
        float y3 = te_b[tj];
#pragma unroll
        for (int k = 0; k < 32; ++k)
            y3 = fmaf(tbuf[w * 8 + r][k], te_W[k * 32 + tj], y3);
        fused[(long)(r0 + r) * 96 + 64 + tj] = f32_to_bf16(gelu_exact(y3));
    }
}

// ---------------- MFMA encoder layer 1: LN+GELU epilogue ----------------
__global__ __launch_bounds__(256) void mfma_ln_kernel(
    const unsigned short* __restrict__ x, const float* __restrict__ W,
    const float* __restrict__ bias, const float* __restrict__ g,
    const float* __restrict__ beta, unsigned short* __restrict__ y, int n)
{
    constexpr int K = 128, KS = K / 32, STRIDE = K + 8;
    __shared__ __align__(16) unsigned short wt[64 * STRIDE];
    int n0 = threadIdx.x & 63;
    int kk = threadIdx.x >> 6;
    for (int k = kk; k < K; k += 4)
        wt[n0 * STRIDE + k] = f32_to_bf16(W[k * 64 + n0]);
    __syncthreads();

    int w = threadIdx.x >> 6;
    int lane = threadIdx.x & 63;
    int c = lane & 15;
    int q = lane >> 4;

    short8 bfrag[KS][4];
#pragma unroll
    for (int s = 0; s < KS; ++s)
#pragma unroll
        for (int nt = 0; nt < 4; ++nt)
            bfrag[s][nt] = *(const short8*)&wt[(nt * 16 + c) * STRIDE + s * 32 + q * 8];

    float bs[4], gs[4], be[4];
#pragma unroll
    for (int nt = 0; nt < 4; ++nt) {
        bs[nt] = bias[nt * 16 + c];
        gs[nt] = g[nt * 16 + c];
        be[nt] = beta[nt * 16 + c];
    }

    int T = n >> 4;
    int stride = gridDim.x * 4;
    for (int t = __builtin_amdgcn_readfirstlane(blockIdx.x * 4 + w); t < T; t += stride) {
        int r0 = t << 4;
        const unsigned short* xa = x + (size_t)(r0 + c) * K + q * 8;
        float4v acc[4] = {{0,0,0,0},{0,0,0,0},{0,0,0,0},{0,0,0,0}};
#pragma unroll
        for (int s = 0; s < KS; ++s) {
            short8 a = *(const short8*)(xa + s * 32);
#pragma unroll
            for (int nt = 0; nt < 4; ++nt)
                acc[nt] = __builtin_amdgcn_mfma_f32_16x16x32_bf16(a, bfrag[s][nt], acc[nt], 0, 0, 0);
        }
#pragma unroll
        for (int reg = 0; reg < 4; ++reg) {
            float v0 = acc[0][reg] + bs[0];
            float v1 = acc[1][reg] + bs[1];
            float v2 = acc[2][reg] + bs[2];
            float v3 = acc[3][reg] + bs[3];
            float mean = qsum16((v0 + v1) + (v2 + v3)) * (1.0f / 64.0f);
            float x0 = v0 - mean, x1 = v1 - mean, x2 = v2 - mean, x3 = v3 - mean;
            float var = qsum16((x0 * x0 + x1 * x1) + (x2 * x2 + x3 * x3)) * (1.0f / 64.0f);
            float rstd = rsqrtf(var + LN_EPS);
            size_t row = (size_t)(r0 + q * 4 + reg) * 64;
            y[row + 0 * 16 + c] = f32_to_bf16(gelu_exact(x0 * rstd * gs[0] + be[0]));
            y[row + 1 * 16 + c] = f32_to_bf16(gelu_exact(x1 * rstd * gs[1] + be[1]));
            y[row + 2 * 16 + c] = f32_to_bf16(gelu_exact(x2 * rstd * gs[2] + be[2]));
            y[row + 3 * 16 + c] = f32_to_bf16(gelu_exact(x3 * rstd * gs[3] + be[3]));
        }
    }
}

// ---------------- MFMA encoder layer 2: GELU epilogue, output stride 96 ----------------
__global__ __launch_bounds__(256) void mfma_gelu_kernel(
    const unsigned short* __restrict__ x, const float* __restrict__ W,
    const float* __restrict__ bias, unsigned short* __restrict__ y, int n)
{
    constexpr int K = 64, KS = K / 32, STRIDE = K + 8;
    __shared__ __align__(16) unsigned short wt[64 * STRIDE];
    int n0 = threadIdx.x & 63;
    int kk = threadIdx.x >> 6;
    for (int k = kk; k < K; k += 4)
        wt[n0 * STRIDE + k] = f32_to_bf16(W[k * 64 + n0]);
    __syncthreads();

    int w = threadIdx.x >> 6;
    int lane = threadIdx.x & 63;
    int c = lane & 15;
    int q = lane >> 4;

    short8 bfrag[KS][4];
#pragma unroll
    for (int s = 0; s < KS; ++s)
#pragma unroll
        for (int nt = 0; nt < 4; ++nt)
            bfrag[s][nt] = *(const short8*)&wt[(nt * 16 + c) * STRIDE + s * 32 + q * 8];

    float bs[4];
#pragma unroll
    for (int nt = 0; nt < 4; ++nt) bs[nt] = bias[nt * 16 + c];

    int T = n >> 4;
    int stride = gridDim.x * 4;
    for (int t = __builtin_amdgcn_readfirstlane(blockIdx.x * 4 + w); t < T; t += stride) {
        int r0 = t << 4;
        const unsigned short* xa = x + (size_t)(r0 + c) * K + q * 8;
        float4v acc[4] = {{0,0,0,0},{0,0,0,0},{0,0,0,0},{0,0,0,0}};
#pragma unroll
        for (int s = 0; s < KS; ++s) {
            short8 a = *(const short8*)(xa + s * 32);
#pragma unroll
            for (int nt = 0; nt < 4; ++nt)
                acc[nt] = __builtin_amdgcn_mfma_f32_16x16x32_bf16(a, bfrag[s][nt], acc[nt], 0, 0, 0);
        }
#pragma unroll
        for (int nt = 0; nt < 4; ++nt)
#pragma unroll
            for (int reg = 0; reg < 4; ++reg)
                y[(size_t)(r0 + q * 4 + reg) * 96 + nt * 16 + c] =
                    f32_to_bf16(gelu_exact(acc[nt][reg] + bs[nt]));
    }
}

// ---------------- MFMA GCN matmul: y_bf16 = (x @ W) * scale[row] ----------------
template <int K>
__global__ __launch_bounds__(256) void mfma_matmul(const unsigned short* __restrict__ x,
                                                   const float* __restrict__ W,
                                                   const float* __restrict__ scale,
                                                   unsigned short* __restrict__ y, int n) {
    constexpr int KS = K / 32;
    constexpr int STRIDE = K + 8;
    __shared__ __align__(16) unsigned short wt[64 * STRIDE];

    int n0 = threadIdx.x & 63;
    int kk = threadIdx.x >> 6;
    for (int k = kk; k < K; k += 4)
        wt[n0 * STRIDE + k] = f32_to_bf16(W[k * 64 + n0]);
    __syncthreads();

    int w = threadIdx.x >> 6;
    int lane = threadIdx.x & 63;
    int c = lane & 15;
    int q = lane >> 4;

    short8 bfrag[KS][4];
#pragma unroll
    for (int s = 0; s < KS; ++s)
#pragma unroll
        for (int nt = 0; nt < 4; ++nt)
            bfrag[s][nt] = *(const short8*)&wt[(nt * 16 + c) * STRIDE + s * 32 + q * 8];

    int T = n >> 4;
    int stride = gridDim.x * 4;
    for (int t = __builtin_amdgcn_readfirstlane(blockIdx.x * 4 + w); t < T; t += stride) {
        int r0 = t << 4;
        const unsigned short* xa = x + (size_t)(r0 + c) * K + q * 8;
        float4v acc[4] = {{0,0,0,0},{0,0,0,0},{0,0,0,0},{0,0,0,0}};
#pragma unroll
        for (int s = 0; s < KS; ++s) {
            short8 a = *(const short8*)(xa + s * 32);
#pragma unroll
            for (int nt = 0; nt < 4; ++nt)
                acc[nt] = __builtin_amdgcn_mfma_f32_16x16x32_bf16(a, bfrag[s][nt], acc[nt], 0, 0, 0);
        }
        float sc[4];
#pragma unroll
        for (int reg = 0; reg < 4; ++reg)
            sc[reg] = scale[r0 + q * 4 + reg];
#pragma unroll
        for (int nt = 0; nt < 4; ++nt)
#pragma unroll
            for (int reg = 0; reg < 4; ++reg)
                y[(size_t)(r0 + q * 4 + reg) * 64 + nt * 16 + c] = f32_to_bf16(acc[nt][reg] * sc[reg]);
    }
}

// ---------------- gather + fused finalize (wave/node; lin pre-scaled by dinv) ----------------
// mode 0: outb = bf16(gelu(pre))
// mode 1: outf = a*pre                     (fp32 partial)
// mode 2: outb = bf16(outf + (1-a)*pre)    (gated combine -> bf16 for MFMA head)
__global__ __launch_bounds__(256) void gather_kernel(
    const int* __restrict__ rowptr, const int* __restrict__ srcs,
    const float* __restrict__ dinv, const unsigned short* __restrict__ lin,
    const float* __restrict__ b, const float* __restrict__ alpha_ptr, int mode,
    unsigned short* __restrict__ outb, float* __restrict__ outf, int n)
{
    int w = threadIdx.x >> 6;
    int j = threadIdx.x & 63;
    int node = __builtin_amdgcn_readfirstlane(blockIdx.x * 4 + w);
    if (node >= n) return;

    int beg = rowptr[node];
    int end = rowptr[node + 1];
    float acc = 0.0f;
    for (int base = beg; base < end; base += 64) {
        int cnt = end - base;
        if (cnt > 64) cnt = 64;
        int sj = (j < cnt) ? srcs[base + j] : 0;
        int t = 0;
        for (; t + 8 <= cnt; t += 8) {
            float v[8];
#pragma unroll
            for (int u = 0; u < 8; ++u) {
                int s = __shfl(sj, t + u, 64);
                v[u] = bf16_to_f32(lin[(long)s * 64 + j]);
            }
            acc += ((v[0] + v[1]) + (v[2] + v[3])) + ((v[4] + v[5]) + (v[6] + v[7]));
        }
        for (; t < cnt; ++t) {
            int s = __shfl(sj, t, 64);
            acc += bf16_to_f32(lin[(long)s * 64 + j]);
        }
    }
    float dd = dinv[node];
    float pre = fmaf(dd, acc + bf16_to_f32(lin[(long)node * 64 + j]), b[j]);

    long oi = (long)node * 64 + j;
    if (mode == 0) {
        outb[oi] = f32_to_bf16(gelu_exact(pre));
    } else {
        float a = 1.0f / (1.0f + expf(-alpha_ptr[0]));
        if (mode == 1) outf[oi] = a * pre;
        else           outb[oi] = f32_to_bf16(outf[oi] + (1.0f - a) * pre);
    }
}

// ---------------- MFMA head: [hb|fused] @ W1 -> LN -> gelu -> @ W2 + b2 ----------------
__global__ __launch_bounds__(256) void head_mfma_kernel(
    const unsigned short* __restrict__ hb, const unsigned short* __restrict__ fused,
    const float* __restrict__ h_W1, const float* __restrict__ h_b1,
    const float* __restrict__ h_g, const float* __restrict__ h_beta,
    const float* __restrict__ h_W2, const float* __restrict__ h_b2,
    float* __restrict__ out, int n)
{
    constexpr int ST1 = 168;  // 160 + 8
    constexpr int ST2 = 72;   // 64 + 8
    __shared__ __align__(16) unsigned short wt1[64 * ST1];     // 21504 B
    __shared__ __align__(16) unsigned short wt2[32 * ST2];     // 4608 B
    __shared__ __align__(16) unsigned short zl[4][16 * ST2];   // 9216 B

    int n0 = threadIdx.x & 63;
    int kk = threadIdx.x >> 6;
    for (int k = kk; k < 160; k += 4)
        wt1[n0 * ST1 + k] = f32_to_bf16(h_W1[k * 64 + n0]);
    if (n0 < 32)
        for (int k = kk; k < 64; k += 4)
            wt2[n0 * ST2 + k] = f32_to_bf16(h_W2[k * 32 + n0]);
    __syncthreads();

    int w = threadIdx.x >> 6;
    int lane = threadIdx.x & 63;
    int c = lane & 15;
    int q = lane >> 4;

    short8 b1f[5][4];
#pragma unroll
    for (int s = 0; s < 5; ++s)
#pragma unroll
        for (int nt = 0; nt < 4; ++nt)
            b1f[s][nt] = *(const short8*)&wt1[(nt * 16 + c) * ST1 + s * 32 + q * 8];
    short8 b2f[2][2];
#pragma unroll
    for (int s = 0; s < 2; ++s)
#pragma unroll
        for (int nt = 0; nt < 2; ++nt)
            b2f[s][nt] = *(const short8*)&wt2[(nt * 16 + c) * ST2 + s * 32 + q * 8];

    float bs[4], gs[4], be[4];
#pragma unroll
    for (int nt = 0; nt < 4; ++nt) {
        bs[nt] = h_b1[nt * 16 + c];
        gs[nt] = h_g[nt * 16 + c];
        be[nt] = h_beta[nt * 16 + c];
    }
    float b2s[2];
#pragma unroll
    for (int nt = 0; nt < 2; ++nt) b2s[nt] = h_b2[nt * 16 + c];

    unsigned short* zw = zl[w];
    int T = n >> 4;
    int stride = gridDim.x * 4;
    for (int t = __builtin_amdgcn_readfirstlane(blockIdx.x * 4 + w); t < T; t += stride) {
        int r0 = t << 4;
        // stage 1: K=160 (hb: k 0..63, fused: k 64..159)
        const unsigned short* xh = hb + (size_t)(r0 + c) * 64 + q * 8;
        const unsigned short* xf = fused + (size_t)(r0 + c) * 96 + q * 8;
        float4v acc[4] = {{0,0,0,0},{0,0,0,0},{0,0,0,0},{0,0,0,0}};
#pragma unroll
        for (int s = 0; s < 2; ++s) {
            short8 a = *(const short8*)(xh + s * 32);
#pragma unroll
            for (int nt = 0; nt < 4; ++nt)
                acc[nt] = __builtin_amdgcn_mfma_f32_16x16x32_bf16(a, b1f[s][nt], acc[nt], 0, 0, 0);
        }
#pragma unroll
        for (int s = 0; s < 3; ++s) {
            short8 a = *(const short8*)(xf + s * 32);
#pragma unroll
            for (int nt = 0; nt < 4; ++nt)
                acc[nt] = __builtin_amdgcn_mfma_f32_16x16x32_bf16(a, b1f[2 + s][nt], acc[nt], 0, 0, 0);
        }
        // epilogue: +b1, LN per row (q*4+reg), gelu -> zl (wave-private)
#pragma unroll
        for (int reg = 0; reg < 4; ++reg) {
            float v0 = acc[0][reg] + bs[0];
            float v1 = acc[1][reg] + bs[1];
            float v2 = acc[2][reg] + bs[2];
            float v3 = acc[3][reg] + bs[3];
            float mean = qsum16((v0 + v1) + (v2 + v3)) * (1.0f / 64.0f);
            float x0 = v0 - mean, x1 = v1 - mean, x2 = v2 - mean, x3 = v3 - mean;
            float var = qsum16((x0 * x0 + x1 * x1) + (x2 * x2 + x3 * x3)) * (1.0f / 64.0f);
            float rstd = rsqrtf(var + LN_EPS);
            int row = q * 4 + reg;
            zw[row * ST2 + 0 * 16 + c] = f32_to_bf16(gelu_exact(x0 * rstd * gs[0] + be[0]));
            zw[row * ST2 + 1 * 16 + c] = f32_to_bf16(gelu_exact(x1 * rstd * gs[1] + be[1]));
            zw[row * ST2 + 2 * 16 + c] = f32_to_bf16(gelu_exact(x2 * rstd * gs[2] + be[2]));
            zw[row * ST2 + 3 * 16 + c] = f32_to_bf16(gelu_exact(x3 * rstd * gs[3] + be[3]));
        }
        // stage 2: z (16x64) @ W2 (64x32); same-wave LDS write->read, no barrier
        float4v acc2[2] = {{0,0,0,0},{0,0,0,0}};
#pragma unroll
        for (int s = 0; s < 2; ++s) {
            short8 a2 = *(const short8*)&zw[c * ST2 + s * 32 + q * 8];
#pragma unroll
            for (int nt = 0; nt < 2; ++nt)
                acc2[nt] = __builtin_amdgcn_mfma_f32_16x16x32_bf16(a2, b2f[s][nt], acc2[nt], 0, 0, 0);
        }
#pragma unroll
        for (int nt = 0; nt < 2; ++nt)
#pragma unroll
            for (int reg = 0; reg < 4; ++reg)
                out[(size_t)(r0 + q * 4 + reg) * 32 + nt * 16 + c] = acc2[nt][reg] + b2s[nt];
    }
}

extern "C" void kernel_launch(void* const* d_in, const int* in_sizes, int n_in,
                              void* d_out, int out_size, void* d_ws, size_t ws_size,
                              hipStream_t stream) {
    const float* context    = (const float*)d_in[0];
    const float* target     = (const float*)d_in[1];
    const void*  mask       = d_in[2];
    const void*  adj_ei     = d_in[3];
    const void*  tr_ei      = d_in[4];
    const float* mask_token = (const float*)d_in[5];
    const float* ce_W1 = (const float*)d_in[6];
    const float* ce_b1 = (const float*)d_in[7];
    const float* ce_g  = (const float*)d_in[8];
    const float* ce_be = (const float*)d_in[9];
    const float* ce_W2 = (const float*)d_in[10];
    const float* ce_b2 = (const float*)d_in[11];
    const float* te_W  = (const float*)d_in[12];
    const float* te_b  = (const float*)d_in[13];
    const float* g1_W  = (const float*)d_in[14];
    const float* g1_b  = (const float*)d_in[15];
    const float* g2_W  = (const float*)d_in[16];
    const float* g2_b  = (const float*)d_in[17];
    const float* t1_W  = (const float*)d_in[18];
    const float* t1_b  = (const float*)d_in[19];
    const float* t2_W  = (const float*)d_in[20];
    const float* t2_b  = (const float*)d_in[21];
    const float* alpha = (const float*)d_in[22];
    const float* h_W1  = (const float*)d_in[23];
    const float* h_b1  = (const float*)d_in[24];
    const float* h_g   = (const float*)d_in[25];
    const float* h_be  = (const float*)d_in[26];
    const float* h_W2  = (const float*)d_in[27];
    const float* h_b2  = (const float*)d_in[28];

    const int N  = in_sizes[0] / 128;
    const int E1 = in_sizes[3] / 2;
    const int E2 = in_sizes[4] / 2;
    const int E  = E1 + E2;
    const int N2 = 2 * N;
    const int nranges = (N2 + RANGE_SZ - 1) / RANGE_SZ;

    // per-range bucket capacity: ~4/3 x expected, multiple of 256
    long expct = ((long)E * RANGE_SZ) / N2;
    int cap = (int)(((expct * 4 / 3) + 255) & ~255L);
    if (cap < 1024) cap = 1024;
    // keep ebuf (cap*nranges*6B) within the hacc alias region (N*256B)
    long avail = (long)N * 256;
    if ((long)cap * nranges * 6 > avail)
        cap = (int)((avail / ((long)nranges * 6)) & ~255L);

    // ---- workspace layout ----
    char* p = (char*)d_ws;
    int*   flags  = (int*)p;                    p += 256;
    unsigned short* ctxb  = (unsigned short*)p; p += (size_t)N * 128 * 2;
    unsigned short* fused = (unsigned short*)p; p += (size_t)N * 96 * 2;
    unsigned short* cb    = (unsigned short*)p; p += (size_t)N * 64 * 2;
    unsigned short* lin   = (unsigned short*)p; p += (size_t)N * 64 * 2;
    unsigned short* h1    = (unsigned short*)p; p += (size_t)N * 64 * 2;
    unsigned short* hb    = (unsigned short*)p; p += (size_t)N * 64 * 2;
    float* hacc   = (float*)p;                  p += (size_t)N * 64 * 4;
    float* dinv   = (float*)p;                  p += (size_t)N2 * 4;
    int*   rowptr = (int*)p;                    p += (size_t)(N2 + 64) * 4;
    int*   gcur   = (int*)p;                    p += (size_t)MAXR * 4;
    int*   rstart = (int*)p;                    p += (size_t)(MAXR + 8) * 4;
    int*   srcs   = (int*)p;                    p += (size_t)E * 4;
    // edge buckets alias hacc (dead until gather mode 1, which runs after passq)
    int*            ebuf_src = (int*)hacc;
    unsigned short* ebuf_ld  = (unsigned short*)((char*)hacc + (size_t)nranges * cap * 4);
    float* out    = (float*)d_out;

    const unsigned rowBlocks32 = (unsigned)((N + 31) / 32);
    const unsigned nodeBlocks  = (unsigned)((N + 3) / 4);
    const unsigned ppBlocks    = (unsigned)((E + PASSP_EDGES - 1) / PASSP_EDGES);
    const unsigned mmBlocks    = 391;

    detect_kernel<<<1, 256, 0, stream>>>((const unsigned char*)mask, (const int*)adj_ei, flags);

    // ---- CSR build: partition -> prefix -> per-range CSR ----
    initcur_kernel<<<2, 256, 0, stream>>>(gcur, cap);
    passp_kernel<<<ppBlocks, 256, 0, stream>>>(adj_ei, E1, tr_ei, E2, N, flags,
                                               gcur, cap, ebuf_src, ebuf_ld);
    rscan_kernel<<<1, 512, 0, stream>>>(gcur, nranges, cap, E, rstart, rowptr, N2);
    passq_kernel<<<(unsigned)nranges, 256, 0, stream>>>(rstart, ebuf_src, ebuf_ld, cap,
                                                        N2, rowptr, dinv, srcs);

    // ---- encoder ----
    prep_kernel<<<rowBlocks32, 256, 0, stream>>>(context, target, mask, flags, mask_token,
                                                 te_W, te_b, ctxb, fused, N);
    mfma_ln_kernel<<<mmBlocks, 256, 0, stream>>>(ctxb, ce_W1, ce_b1, ce_g, ce_be, cb, N);
    mfma_gelu_kernel<<<mmBlocks, 256, 0, stream>>>(cb, ce_W2, ce_b2, fused, N);

    const float* dinv_a = dinv;
    const float* dinv_t = dinv + N;
    const int*   row_a  = rowptr;
    const int*   row_t  = rowptr + N;

    // ---- spatial branch ----
    mfma_matmul<96><<<mmBlocks, 256, 0, stream>>>(fused, g1_W, dinv_a, lin, N);
    gather_kernel<<<nodeBlocks, 256, 0, stream>>>(row_a, srcs, dinv_a, lin, g1_b, alpha, 0, h1, hacc, N);
    mfma_matmul<64><<<mmBlocks, 256, 0, stream>>>(h1, g2_W, dinv_a, lin, N);
    gather_kernel<<<nodeBlocks, 256, 0, stream>>>(row_a, srcs, dinv_a, lin, g2_b, alpha, 1, hb, hacc, N);

    // ---- transit branch ----
    mfma_matmul<96><<<mmBlocks, 256, 0, stream>>>(fused, t1_W, dinv_t, lin, N);
    gather_kernel<<<nodeBlocks, 256, 0, stream>>>(row_t, srcs, dinv_t, lin, t1_b, alpha, 0, h1, hacc, N);
    mfma_matmul<64><<<mmBlocks, 256, 0, stream>>>(h1, t2_W, dinv_t, lin, N);
    gather_kernel<<<nodeBlocks, 256, 0, stream>>>(row_t, srcs, dinv_t, lin, t2_b, alpha, 2, hb, hacc, N);

    // ---- head (MFMA) ----
    head_mfma_kernel<<<mmBlocks, 256, 0, stream>>>(hb, fused, h_W1, h_b1, h_g, h_be,
                                                   h_W2, h_b2, out, N);
}

// Round 4
// 542.893 us; speedup vs baseline: 1.3010x; 1.0553x over previous
//
#include <hip/hip_runtime.h>
#include <math.h>

// UrbanModelV2: encoder MLPs -> 4x GCNConv (2 graphs) -> gated combine -> LN-MLP head.
// N=100000, CTX=128, TGT=32, H=64, FUS=96, E1=1.6M, E2=0.8M. fp32 in/out.
//
// R13: passp rework + interleaved ranges + grid-level fusion.
//  - passp pass1 keeps the LDS-atomic return as the per-edge rank -> pass2 is pure
//    8B int2 stores (no per-edge LDS round-trip). WRITE amp down (~67->~40MB).
//  - range = node & 511 (not node/512): mixes adj (16/node) and transit (8/node)
//    halves -> uniform ~4.7K edges/range; cap=6144 = 21 sigma margin. (R12's
//    node/512 ranges had adj-range mean == cap -> silent edge drops.) gather now
//    reads degree from rowcnt[] since rowptr is no longer node-contiguous.
//  - grid fusion of independent chains: [passp|prep], [mfma_ln|rscan],
//    [passq|mfma_gelu], initcur inside detect. 12 launches.

#define LN_EPS 1e-5f
#define NRANGES 512
#define RMASK 511
#define LSHIFT 9
#define PASSP_EDGES 4096

typedef __attribute__((ext_vector_type(8))) short short8;            // 8 bf16
typedef __attribute__((ext_vector_type(4))) float float4v;           // MFMA acc
typedef __attribute__((ext_vector_type(4))) unsigned short ushort4v; // 4 bf16

__device__ __forceinline__ float gelu_exact(float x) {
    return 0.5f * x * (1.0f + erff(x * 0.70710678118654752440f));
}

// reduce across the 16-lane quad-group (lane masks 1..8 stay within group)
__device__ __forceinline__ float qsum16(float v) {
#pragma unroll
    for (int m = 1; m < 16; m <<= 1)
        v += __shfl_xor(v, m, 64);
    return v;
}

__device__ __forceinline__ int load_edge(const void* ei, int is32, long idx) {
    return is32 ? ((const int*)ei)[idx] : (int)((const long long*)ei)[idx];
}

__device__ __forceinline__ unsigned short f32_to_bf16(float f) {
    unsigned int x = __float_as_uint(f);
    x += 0x7fffu + ((x >> 16) & 1u);   // RNE, finite values
    return (unsigned short)(x >> 16);
}
__device__ __forceinline__ float bf16_to_f32(unsigned short u) {
    return __uint_as_float((unsigned int)u << 16);
}

// load dst-nodes (transit offset by n) for edges base..base+3; nv = #valid
__device__ __forceinline__ void load_dst4(const void* ei1, int e1, const void* ei2, int e2,
                                          int n, int is32, int base, int nv, int nd[4]) {
    if (is32 && nv == 4) {
        if (base + 3 < e1 && (((e1 + base) & 3) == 0)) {
            int4 v = *(const int4*)((const int*)ei1 + (size_t)e1 + base);
            nd[0] = v.x; nd[1] = v.y; nd[2] = v.z; nd[3] = v.w;
            return;
        }
        if (base >= e1 && (((e2 + base - e1) & 3) == 0)) {
            int4 v = *(const int4*)((const int*)ei2 + (size_t)e2 + (base - e1));
            nd[0] = v.x + n; nd[1] = v.y + n; nd[2] = v.z + n; nd[3] = v.w + n;
            return;
        }
    }
#pragma unroll
    for (int u = 0; u < 4; ++u) {
        int i = base + u;
        if (u >= nv) { nd[u] = -1; continue; }
        if (i < e1) nd[u] = load_edge(ei1, is32, (long)e1 + i);
        else        nd[u] = load_edge(ei2, is32, (long)e2 + (i - e1)) + n;
    }
}

// load src-nodes for edges base..base+3; nv = #valid
__device__ __forceinline__ void load_src4(const void* ei1, int e1, const void* ei2, int e2,
                                          int is32, int base, int nv, int ns[4]) {
    if (is32 && nv == 4) {
        if (base + 3 < e1 && ((base & 3) == 0)) {
            int4 v = *(const int4*)((const int*)ei1 + base);
            ns[0] = v.x; ns[1] = v.y; ns[2] = v.z; ns[3] = v.w;
            return;
        }
        if (base >= e1 && (((base - e1) & 3) == 0)) {
            int4 v = *(const int4*)((const int*)ei2 + (base - e1));
            ns[0] = v.x; ns[1] = v.y; ns[2] = v.z; ns[3] = v.w;
            return;
        }
    }
#pragma unroll
    for (int u = 0; u < 4; ++u) {
        int i = base + u;
        if (u >= nv) { ns[u] = 0; continue; }
        if (i < e1) ns[u] = load_edge(ei1, is32, i);
        else        ns[u] = load_edge(ei2, is32, (long)(i - e1));
    }
}

// ---------------- dtype detection + cursor init ----------------
__global__ __launch_bounds__(256) void detect_kernel(const unsigned char* __restrict__ mask_bytes,
                                                     const int* __restrict__ ei_words,
                                                     int* __restrict__ flags,
                                                     int* __restrict__ gcur, int cap) {
    if (blockIdx.x == 0) {
        __shared__ int f0, f1;
        if (threadIdx.x == 0) { f0 = 0; f1 = 0; }
        __syncthreads();
        int i = threadIdx.x;
        if ((i & 3) != 0 && mask_bytes[i] != 0) f0 = 1;
        if (i < 64 && ei_words[2 * i + 1] != 0) f1 = 1;
        __syncthreads();
        if (threadIdx.x == 0) { flags[0] = f0; flags[1] = f1; }
    } else {
        int r = (blockIdx.x - 1) * 256 + threadIdx.x;
        if (r < NRANGES) gcur[r] = r * cap;
    }
}

// ---------------- CSR stage 1 body: partition edges into range buckets ----------------
__device__ __forceinline__ void passp_body(
    const void* ei1, int e1, const void* ei2, int e2,
    int n, const int* flags, int* gcur, int cap, int2* ebuf, int bid)
{
    __shared__ int hist[NRANGES];
    __shared__ int base[NRANGES];
    const int E = e1 + e2;
    const int is32 = flags[1];
    const int b0 = bid * PASSP_EDGES;
    const int bend = (b0 + PASSP_EDGES < E) ? b0 + PASSP_EDGES : E;

    for (int k = threadIdx.x; k < NRANGES; k += 256) hist[k] = 0;
    __syncthreads();

    // pass 1: histogram; the atomic return IS the local rank (kept in regs)
    int nd[16], rk[16];
#pragma unroll
    for (int j = 0; j < 4; ++j) {
        int bi = b0 + j * 1024 + (int)threadIdx.x * 4;
        int nv = bend - bi; nv = (nv < 0) ? 0 : (nv > 4 ? 4 : nv);
        load_dst4(ei1, e1, ei2, e2, n, is32, bi, nv, &nd[j * 4]);
#pragma unroll
        for (int u = 0; u < 4; ++u)
            if (u < nv) rk[j * 4 + u] = atomicAdd(&hist[nd[j * 4 + u] & RMASK], 1);
    }
    __syncthreads();

    // allocate: one device atomic per nonempty (block,range)
    for (int r = threadIdx.x; r < NRANGES; r += 256) {
        int c = hist[r];
        base[r] = c ? atomicAdd(&gcur[r], c) : 0;
    }
    __syncthreads();

    // pass 2: pure 8B scatter, no LDS ops
#pragma unroll
    for (int j = 0; j < 4; ++j) {
        int bi = b0 + j * 1024 + (int)threadIdx.x * 4;
        int nv = bend - bi; nv = (nv < 0) ? 0 : (nv > 4 ? 4 : nv);
        int sv[4];
        load_src4(ei1, e1, ei2, e2, is32, bi, nv, sv);
#pragma unroll
        for (int u = 0; u < 4; ++u) {
            if (u < nv) {
                int d = nd[j * 4 + u];
                int r = d & RMASK;
                int pos = base[r] + rk[j * 4 + u];
                if (pos < (r + 1) * cap)   // capacity guard (memory safety)
                    ebuf[pos] = make_int2(sv[u], d >> LSHIFT);
            }
        }
    }
}

// ---------------- prep body: ctx->bf16 + masked-target encoder -> fused[:,64:96] ----------------
__device__ __forceinline__ void prep_body(
    const float* context, const float* target, const void* mask, const int* flags,
    const float* mask_token, const float* te_W, const float* te_b,
    unsigned short* ctxb, unsigned short* fused, int n, int bid)
{
    __shared__ float tbuf[32][32];
    int w = threadIdx.x >> 6;
    int j = threadIdx.x & 63;
    int r0 = __builtin_amdgcn_readfirstlane(bid * 32 + w * 8);
    if (r0 >= n) return;  // N % 32 == 0

    const float4* src = (const float4*)(context + (size_t)r0 * 128);
    ushort4v* dst = (ushort4v*)(ctxb + (size_t)r0 * 128);
#pragma unroll
    for (int p = 0; p < 4; ++p) {
        float4 v = src[p * 64 + j];
        ushort4v o;
        o.x = f32_to_bf16(v.x); o.y = f32_to_bf16(v.y);
        o.z = f32_to_bf16(v.z); o.w = f32_to_bf16(v.w);
        dst[p * 64 + j] = o;
    }

    int tr = j >> 5;
    int tj = j & 31;
#pragma unroll
    for (int rr = 0; rr < 4; ++rr) {
        int r = tr + rr * 2;
        long mi = (long)(r0 + r) * 32 + tj;
        int mraw = flags[0] ? (int)((const unsigned char*)mask)[mi]
                            : ((const int*)mask)[mi];
        float m = mraw ? 1.0f : 0.0f;
        tbuf[w * 8 + r][tj] = target[mi] * (1.0f - m) + mask_token[tj] * m;
    }

#pragma unroll
    for (int rr = 0; rr < 4; ++rr) {
        int r = tr + rr * 2;
        float y3 = te_b[tj];
#pragma unroll
        for (int k = 0; k < 32; ++k)
            y3 = fmaf(tbuf[w * 8 + r][k], te_W[k * 32 + tj], y3);
        fused[(long)(r0 + r) * 96 + 64 + tj] = f32_to_bf16(gelu_exact(y3));
    }
}

// ---------------- fused kernel A: passp | prep ----------------
__global__ __launch_bounds__(256) void passp_prep_kernel(
    const void* __restrict__ ei1, int e1, const void* __restrict__ ei2, int e2,
    int n, const int* __restrict__ flags, int* __restrict__ gcur, int cap,
    int2* __restrict__ ebuf, int ppBlocks,
    const float* __restrict__ context, const float* __restrict__ target,
    const void* __restrict__ mask, const float* __restrict__ mask_token,
    const float* __restrict__ te_W, const float* __restrict__ te_b,
    unsigned short* __restrict__ ctxb, unsigned short* __restrict__ fused)
{
    if ((int)blockIdx.x < ppBlocks)
        passp_body(ei1, e1, ei2, e2, n, flags, gcur, cap, ebuf, blockIdx.x);
    else
        prep_body(context, target, mask, flags, mask_token, te_W, te_b,
                  ctxb, fused, n, blockIdx.x - ppBlocks);
}

// ---------------- CSR stage 2 body: prefix over 512 range totals (256 thr) ----------------
__device__ __forceinline__ void rscan_body(const int* gcur, int cap,
                                           int* rstart, int* rowptr, int n2) {
    __shared__ int ws[256];
    int t = threadIdx.x;
    int i0 = 2 * t, i1 = 2 * t + 1;
    int a0 = gcur[i0] - i0 * cap;
    int a1 = gcur[i1] - i1 * cap;
    ws[t] = a0 + a1;
    __syncthreads();
    for (int off = 1; off < 256; off <<= 1) {
        int v = (t >= off) ? ws[t - off] : 0;
        __syncthreads();
        if (t >= off) ws[t] += v;
        __syncthreads();
    }
    int ex = t ? ws[t - 1] : 0;
    rstart[i0] = ex;
    rstart[i1] = ex + a0;
    if (t == 255) { rstart[NRANGES] = ws[255]; rowptr[n2] = ws[255]; }
}

// ---------------- MFMA encoder layer 1 body: LN+GELU epilogue ----------------
__device__ __forceinline__ void mfma_ln_body(
    const unsigned short* x, const float* W, const float* bias, const float* g,
    const float* beta, unsigned short* y, int n, int bid, int nblk)
{
    constexpr int K = 128, KS = K / 32, STRIDE = K + 8;
    __shared__ __align__(16) unsigned short wt[64 * STRIDE];
    int n0 = threadIdx.x & 63;
    int kk = threadIdx.x >> 6;
    for (int k = kk; k < K; k += 4)
        wt[n0 * STRIDE + k] = f32_to_bf16(W[k * 64 + n0]);
    __syncthreads();

    int w = threadIdx.x >> 6;
    int lane = threadIdx.x & 63;
    int c = lane & 15;
    int q = lane >> 4;

    short8 bfrag[KS][4];
#pragma unroll
    for (int s = 0; s < KS; ++s)
#pragma unroll
        for (int nt = 0; nt < 4; ++nt)
            bfrag[s][nt] = *(const short8*)&wt[(nt * 16 + c) * STRIDE + s * 32 + q * 8];

    float bs[4], gs[4], be[4];
#pragma unroll
    for (int nt = 0; nt < 4; ++nt) {
        bs[nt] = bias[nt * 16 + c];
        gs[nt] = g[nt * 16 + c];
        be[nt] = beta[nt * 16 + c];
    }

    int T = n >> 4;
    int stride = nblk * 4;
    for (int t = __builtin_amdgcn_readfirstlane(bid * 4 + w); t < T; t += stride) {
        int r0 = t << 4;
        const unsigned short* xa = x + (size_t)(r0 + c) * K + q * 8;
        float4v acc[4] = {{0,0,0,0},{0,0,0,0},{0,0,0,0},{0,0,0,0}};
#pragma unroll
        for (int s = 0; s < KS; ++s) {
            short8 a = *(const short8*)(xa + s * 32);
#pragma unroll
            for (int nt = 0; nt < 4; ++nt)
                acc[nt] = __builtin_amdgcn_mfma_f32_16x16x32_bf16(a, bfrag[s][nt], acc[nt], 0, 0, 0);
        }
#pragma unroll
        for (int reg = 0; reg < 4; ++reg) {
            float v0 = acc[0][reg] + bs[0];
            float v1 = acc[1][reg] + bs[1];
            float v2 = acc[2][reg] + bs[2];
            float v3 = acc[3][reg] + bs[3];
            float mean = qsum16((v0 + v1) + (v2 + v3)) * (1.0f / 64.0f);
            float x0 = v0 - mean, x1 = v1 - mean, x2 = v2 - mean, x3 = v3 - mean;
            float var = qsum16((x0 * x0 + x1 * x1) + (x2 * x2 + x3 * x3)) * (1.0f / 64.0f);
            float rstd = rsqrtf(var + LN_EPS);
            size_t row = (size_t)(r0 + q * 4 + reg) * 64;
            y[row + 0 * 16 + c] = f32_to_bf16(gelu_exact(x0 * rstd * gs[0] + be[0]));
            y[row + 1 * 16 + c] = f32_to_bf16(gelu_exact(x1 * rstd * gs[1] + be[1]));
            y[row + 2 * 16 + c] = f32_to_bf16(gelu_exact(x2 * rstd * gs[2] + be[2]));
            y[row + 3 * 16 + c] = f32_to_bf16(gelu_exact(x3 * rstd * gs[3] + be[3]));
        }
    }
}

// ---------------- fused kernel B: mfma_ln | rscan ----------------
__global__ __launch_bounds__(256) void ln_rscan_kernel(
    const unsigned short* __restrict__ x, const float* __restrict__ W,
    const float* __restrict__ bias, const float* __restrict__ g,
    const float* __restrict__ beta, unsigned short* __restrict__ y, int n, int nblk,
    const int* __restrict__ gcur, int cap, int* __restrict__ rstart,
    int* __restrict__ rowptr, int n2)
{
    if ((int)blockIdx.x == nblk)
        rscan_body(gcur, cap, rstart, rowptr, n2);
    else
        mfma_ln_body(x, W, bias, g, beta, y, n, blockIdx.x, nblk);
}

// ---------------- CSR stage 3 body: per-range CSR build ----------------
// range g owns nodes {d : (d & 511) == g}, local id l = d >> 9.
__device__ __forceinline__ void passq_body(
    const int* rstart, const int2* ebuf, int cap, int n2,
    int* rowptr, int* rowcnt, float* dinv, int* srcs, int g)
{
    __shared__ int deg[NRANGES];
    __shared__ int cur[NRANGES];
    __shared__ int ws[256];
    const int t = threadIdx.x;
    const int gbase = rstart[g];
    const int total = rstart[g + 1] - gbase;
    const int2* eb = ebuf + (size_t)g * cap;

    deg[2 * t] = 0; deg[2 * t + 1] = 0;
    __syncthreads();
    for (int i = t; i < total; i += 256)
        atomicAdd(&deg[eb[i].y], 1);
    __syncthreads();

    int a0 = deg[2 * t], a1 = deg[2 * t + 1];
    ws[t] = a0 + a1;
    __syncthreads();
    for (int off = 1; off < 256; off <<= 1) {
        int v = (t >= off) ? ws[t - off] : 0;
        __syncthreads();
        if (t >= off) ws[t] += v;
        __syncthreads();
    }
    int ex = t ? ws[t - 1] : 0;
    cur[2 * t] = ex;
    cur[2 * t + 1] = ex + a0;
    int node0 = ((2 * t) << LSHIFT) | g;
    int node1 = ((2 * t + 1) << LSHIFT) | g;
    if (node0 < n2) { rowptr[node0] = gbase + ex;      rowcnt[node0] = a0; dinv[node0] = rsqrtf((float)a0 + 1.0f); }
    if (node1 < n2) { rowptr[node1] = gbase + ex + a0; rowcnt[node1] = a1; dinv[node1] = rsqrtf((float)a1 + 1.0f); }
    __syncthreads();

    for (int i = t; i < total; i += 256) {
        int2 e = eb[i];
        int rk = atomicAdd(&cur[e.y], 1);
        srcs[gbase + rk] = e.x;
    }
}

// ---------------- MFMA encoder layer 2 body: GELU epilogue, out stride 96 ----------------
__device__ __forceinline__ void mfma_gelu_body(
    const unsigned short* x, const float* W, const float* bias,
    unsigned short* y, int n, int bid, int nblk)
{
    constexpr int K = 64, KS = K / 32, STRIDE = K + 8;
    __shared__ __align__(16) unsigned short wt[64 * STRIDE];
    int n0 = threadIdx.x & 63;
    int kk = threadIdx.x >> 6;
    for (int k = kk; k < K; k += 4)
        wt[n0 * STRIDE + k] = f32_to_bf16(W[k * 64 + n0]);
    __syncthreads();

    int w = threadIdx.x >> 6;
    int lane = threadIdx.x & 63;
    int c = lane & 15;
    int q = lane >> 4;

    short8 bfrag[KS][4];
#pragma unroll
    for (int s = 0; s < KS; ++s)
#pragma unroll
        for (int nt = 0; nt < 4; ++nt)
            bfrag[s][nt] = *(const short8*)&wt[(nt * 16 + c) * STRIDE + s * 32 + q * 8];

    float bs[4];
#pragma unroll
    for (int nt = 0; nt < 4; ++nt) bs[nt] = bias[nt * 16 + c];

    int T = n >> 4;
    int stride = nblk * 4;
    for (int t = __builtin_amdgcn_readfirstlane(bid * 4 + w); t < T; t += stride) {
        int r0 = t << 4;
        const unsigned short* xa = x + (size_t)(r0 + c) * K + q * 8;
        float4v acc[4] = {{0,0,0,0},{0,0,0,0},{0,0,0,0},{0,0,0,0}};
#pragma unroll
        for (int s = 0; s < KS; ++s) {
            short8 a = *(const short8*)(xa + s * 32);
#pragma unroll
            for (int nt = 0; nt < 4; ++nt)
                acc[nt] = __builtin_amdgcn_mfma_f32_16x16x32_bf16(a, bfrag[s][nt], acc[nt], 0, 0, 0);
        }
#pragma unroll
        for (int nt = 0; nt < 4; ++nt)
#pragma unroll
            for (int reg = 0; reg < 4; ++reg)
                y[(size_t)(r0 + q * 4 + reg) * 96 + nt * 16 + c] =
                    f32_to_bf16(gelu_exact(acc[nt][reg] + bs[nt]));
    }
}

// ---------------- fused kernel C: passq | mfma_gelu ----------------
__global__ __launch_bounds__(256) void passq_gelu_kernel(
    const int* __restrict__ rstart, const int2* __restrict__ ebuf, int cap, int n2,
    int* __restrict__ rowptr, int* __restrict__ rowcnt, float* __restrict__ dinv,
    int* __restrict__ srcs,
    const unsigned short* __restrict__ x, const float* __restrict__ W,
    const float* __restrict__ bias, unsigned short* __restrict__ y, int n, int nblk)
{
    if ((int)blockIdx.x < NRANGES)
        passq_body(rstart, ebuf, cap, n2, rowptr, rowcnt, dinv, srcs, blockIdx.x);
    else
        mfma_gelu_body(x, W, bias, y, n, blockIdx.x - NRANGES, nblk);
}

// ---------------- MFMA GCN matmul: y_bf16 = (x @ W) * scale[row] ----------------
template <int K>
__global__ __launch_bounds__(256) void mfma_matmul(const unsigned short* __restrict__ x,
                                                   const float* __restrict__ W,
                                                   const float* __restrict__ scale,
                                                   unsigned short* __restrict__ y, int n) {
    constexpr int KS = K / 32;
    constexpr int STRIDE = K + 8;
    __shared__ __align__(16) unsigned short wt[64 * STRIDE];

    int n0 = threadIdx.x & 63;
    int kk = threadIdx.x >> 6;
    for (int k = kk; k < K; k += 4)
        wt[n0 * STRIDE + k] = f32_to_bf16(W[k * 64 + n0]);
    __syncthreads();

    int w = threadIdx.x >> 6;
    int lane = threadIdx.x & 63;
    int c = lane & 15;
    int q = lane >> 4;

    short8 bfrag[KS][4];
#pragma unroll
    for (int s = 0; s < KS; ++s)
#pragma unroll
        for (int nt = 0; nt < 4; ++nt)
            bfrag[s][nt] = *(const short8*)&wt[(nt * 16 + c) * STRIDE + s * 32 + q * 8];

    int T = n >> 4;
    int stride = gridDim.x * 4;
    for (int t = __builtin_amdgcn_readfirstlane(blockIdx.x * 4 + w); t < T; t += stride) {
        int r0 = t << 4;
        const unsigned short* xa = x + (size_t)(r0 + c) * K + q * 8;
        float4v acc[4] = {{0,0,0,0},{0,0,0,0},{0,0,0,0},{0,0,0,0}};
#pragma unroll
        for (int s = 0; s < KS; ++s) {
            short8 a = *(const short8*)(xa + s * 32);
#pragma unroll
            for (int nt = 0; nt < 4; ++nt)
                acc[nt] = __builtin_amdgcn_mfma_f32_16x16x32_bf16(a, bfrag[s][nt], acc[nt], 0, 0, 0);
        }
        float sc[4];
#pragma unroll
        for (int reg = 0; reg < 4; ++reg)
            sc[reg] = scale[r0 + q * 4 + reg];
#pragma unroll
        for (int nt = 0; nt < 4; ++nt)
#pragma unroll
            for (int reg = 0; reg < 4; ++reg)
                y[(size_t)(r0 + q * 4 + reg) * 64 + nt * 16 + c] = f32_to_bf16(acc[nt][reg] * sc[reg]);
    }
}

// ---------------- gather + fused finalize (wave/node; lin pre-scaled by dinv) ----------------
// mode 0: outb = bf16(gelu(pre))
// mode 1: outf = a*pre                     (fp32 partial)
// mode 2: outb = bf16(outf + (1-a)*pre)    (gated combine -> bf16 for MFMA head)
__global__ __launch_bounds__(256) void gather_kernel(
    const int* __restrict__ rowptr, const int* __restrict__ rowcnt,
    const int* __restrict__ srcs,
    const float* __restrict__ dinv, const unsigned short* __restrict__ lin,
    const float* __restrict__ b, const float* __restrict__ alpha_ptr, int mode,
    unsigned short* __restrict__ outb, float* __restrict__ outf, int n)
{
    int w = threadIdx.x >> 6;
    int j = threadIdx.x & 63;
    int node = __builtin_amdgcn_readfirstlane(blockIdx.x * 4 + w);
    if (node >= n) return;

    int beg = rowptr[node];
    int end = beg + rowcnt[node];
    float acc = 0.0f;
    for (int base = beg; base < end; base += 64) {
        int cnt = end - base;
        if (cnt > 64) cnt = 64;
        int sj = (j < cnt) ? srcs[base + j] : 0;
        int t = 0;
        for (; t + 8 <= cnt; t += 8) {
            float v[8];
#pragma unroll
            for (int u = 0; u < 8; ++u) {
                int s = __shfl(sj, t + u, 64);
                v[u] = bf16_to_f32(lin[(long)s * 64 + j]);
            }
            acc += ((v[0] + v[1]) + (v[2] + v[3])) + ((v[4] + v[5]) + (v[6] + v[7]));
        }
        for (; t < cnt; ++t) {
            int s = __shfl(sj, t, 64);
            acc += bf16_to_f32(lin[(long)s * 64 + j]);
        }
    }
    float dd = dinv[node];
    float pre = fmaf(dd, acc + bf16_to_f32(lin[(long)node * 64 + j]), b[j]);

    long oi = (long)node * 64 + j;
    if (mode == 0) {
        outb[oi] = f32_to_bf16(gelu_exact(pre));
    } else {
        float a = 1.0f / (1.0f + expf(-alpha_ptr[0]));
        if (mode == 1) outf[oi] = a * pre;
        else           outb[oi] = f32_to_bf16(outf[oi] + (1.0f - a) * pre);
    }
}

// ---------------- MFMA head: [hb|fused] @ W1 -> LN -> gelu -> @ W2 + b2 ----------------
__global__ __launch_bounds__(256) void head_mfma_kernel(
    const unsigned short* __restrict__ hb, const unsigned short* __restrict__ fused,
    const float* __restrict__ h_W1, const float* __restrict__ h_b1,
    const float* __restrict__ h_g, const float* __restrict__ h_beta,
    const float* __restrict__ h_W2, const float* __restrict__ h_b2,
    float* __restrict__ out, int n)
{
    constexpr int ST1 = 168;  // 160 + 8
    constexpr int ST2 = 72;   // 64 + 8
    __shared__ __align__(16) unsigned short wt1[64 * ST1];     // 21504 B
    __shared__ __align__(16) unsigned short wt2[32 * ST2];     // 4608 B
    __shared__ __align__(16) unsigned short zl[4][16 * ST2];   // 9216 B

    int n0 = threadIdx.x & 63;
    int kk = threadIdx.x >> 6;
    for (int k = kk; k < 160; k += 4)
        wt1[n0 * ST1 + k] = f32_to_bf16(h_W1[k * 64 + n0]);
    if (n0 < 32)
        for (int k = kk; k < 64; k += 4)
            wt2[n0 * ST2 + k] = f32_to_bf16(h_W2[k * 32 + n0]);
    __syncthreads();

    int w = threadIdx.x >> 6;
    int lane = threadIdx.x & 63;
    int c = lane & 15;
    int q = lane >> 4;

    short8 b1f[5][4];
#pragma unroll
    for (int s = 0; s < 5; ++s)
#pragma unroll
        for (int nt = 0; nt < 4; ++nt)
            b1f[s][nt] = *(const short8*)&wt1[(nt * 16 + c) * ST1 + s * 32 + q * 8];
    short8 b2f[2][2];
#pragma unroll
    for (int s = 0; s < 2; ++s)
#pragma unroll
        for (int nt = 0; nt < 2; ++nt)
            b2f[s][nt] = *(const short8*)&wt2[(nt * 16 + c) * ST2 + s * 32 + q * 8];

    float bs[4], gs[4], be[4];
#pragma unroll
    for (int nt = 0; nt < 4; ++nt) {
        bs[nt] = h_b1[nt * 16 + c];
        gs[nt] = h_g[nt * 16 + c];
        be[nt] = h_beta[nt * 16 + c];
    }
    float b2s[2];
#pragma unroll
    for (int nt = 0; nt < 2; ++nt) b2s[nt] = h_b2[nt * 16 + c];

    unsigned short* zw = zl[w];
    int T = n >> 4;
    int stride = gridDim.x * 4;
    for (int t = __builtin_amdgcn_readfirstlane(blockIdx.x * 4 + w); t < T; t += stride) {
        int r0 = t << 4;
        // stage 1: K=160 (hb: k 0..63, fused: k 64..159)
        const unsigned short* xh = hb + (size_t)(r0 + c) * 64 + q * 8;
        const unsigned short* xf = fused + (size_t)(r0 + c) * 96 + q * 8;
        float4v acc[4] = {{0,0,0,0},{0,0,0,0},{0,0,0,0},{0,0,0,0}};
#pragma unroll
        for (int s = 0; s < 2; ++s) {
            short8 a = *(const short8*)(xh + s * 32);
#pragma unroll
            for (int nt = 0; nt < 4; ++nt)
                acc[nt] = __builtin_amdgcn_mfma_f32_16x16x32_bf16(a, b1f[s][nt], acc[nt], 0, 0, 0);
        }
#pragma unroll
        for (int s = 0; s < 3; ++s) {
            short8 a = *(const short8*)(xf + s * 32);
#pragma unroll
            for (int nt = 0; nt < 4; ++nt)
                acc[nt] = __builtin_amdgcn_mfma_f32_16x16x32_bf16(a, b1f[2 + s][nt], acc[nt], 0, 0, 0);
        }
        // epilogue: +b1, LN per row (q*4+reg), gelu -> zl (wave-private)
#pragma unroll
        for (int reg = 0; reg < 4; ++reg) {
            float v0 = acc[0][reg] + bs[0];
            float v1 = acc[1][reg] + bs[1];
            float v2 = acc[2][reg] + bs[2];
            float v3 = acc[3][reg] + bs[3];
            float mean = qsum16((v0 + v1) + (v2 + v3)) * (1.0f / 64.0f);
            float x0 = v0 - mean, x1 = v1 - mean, x2 = v2 - mean, x3 = v3 - mean;
            float var = qsum16((x0 * x0 + x1 * x1) + (x2 * x2 + x3 * x3)) * (1.0f / 64.0f);
            float rstd = rsqrtf(var + LN_EPS);
            int row = q * 4 + reg;
            zw[row * ST2 + 0 * 16 + c] = f32_to_bf16(gelu_exact(x0 * rstd * gs[0] + be[0]));
            zw[row * ST2 + 1 * 16 + c] = f32_to_bf16(gelu_exact(x1 * rstd * gs[1] + be[1]));
            zw[row * ST2 + 2 * 16 + c] = f32_to_bf16(gelu_exact(x2 * rstd * gs[2] + be[2]));
            zw[row * ST2 + 3 * 16 + c] = f32_to_bf16(gelu_exact(x3 * rstd * gs[3] + be[3]));
        }
        // stage 2: z (16x64) @ W2 (64x32); same-wave LDS write->read, no barrier
        float4v acc2[2] = {{0,0,0,0},{0,0,0,0}};
#pragma unroll
        for (int s = 0; s < 2; ++s) {
            short8 a2 = *(const short8*)&zw[c * ST2 + s * 32 + q * 8];
#pragma unroll
            for (int nt = 0; nt < 2; ++nt)
                acc2[nt] = __builtin_amdgcn_mfma_f32_16x16x32_bf16(a2, b2f[s][nt], acc2[nt], 0, 0, 0);
        }
#pragma unroll
        for (int nt = 0; nt < 2; ++nt)
#pragma unroll
            for (int reg = 0; reg < 4; ++reg)
                out[(size_t)(r0 + q * 4 + reg) * 32 + nt * 16 + c] = acc2[nt][reg] + b2s[nt];
    }
}

extern "C" void kernel_launch(void* const* d_in, const int* in_sizes, int n_in,
                              void* d_out, int out_size, void* d_ws, size_t ws_size,
                              hipStream_t stream) {
    const float* context    = (const float*)d_in[0];
    const float* target     = (const float*)d_in[1];
    const void*  mask       = d_in[2];
    const void*  adj_ei     = d_in[3];
    const void*  tr_ei      = d_in[4];
    const float* mask_token = (const float*)d_in[5];
    const float* ce_W1 = (const float*)d_in[6];
    const float* ce_b1 = (const float*)d_in[7];
    const float* ce_g  = (const float*)d_in[8];
    const float* ce_be = (const float*)d_in[9];
    const float* ce_W2 = (const float*)d_in[10];
    const float* ce_b2 = (const float*)d_in[11];
    const float* te_W  = (const float*)d_in[12];
    const float* te_b  = (const float*)d_in[13];
    const float* g1_W  = (const float*)d_in[14];
    const float* g1_b  = (const float*)d_in[15];
    const float* g2_W  = (const float*)d_in[16];
    const float* g2_b  = (const float*)d_in[17];
    const float* t1_W  = (const float*)d_in[18];
    const float* t1_b  = (const float*)d_in[19];
    const float* t2_W  = (const float*)d_in[20];
    const float* t2_b  = (const float*)d_in[21];
    const float* alpha = (const float*)d_in[22];
    const float* h_W1  = (const float*)d_in[23];
    const float* h_b1  = (const float*)d_in[24];
    const float* h_g   = (const float*)d_in[25];
    const float* h_be  = (const float*)d_in[26];
    const float* h_W2  = (const float*)d_in[27];
    const float* h_b2  = (const float*)d_in[28];

    const int N  = in_sizes[0] / 128;
    const int E1 = in_sizes[3] / 2;
    const int E2 = in_sizes[4] / 2;
    const int E  = E1 + E2;
    const int N2 = 2 * N;

    // per-range bucket capacity (range = node & 511 -> uniform load)
    long expct = (E + NRANGES - 1) / NRANGES;
    int cap = (int)((expct * 4 / 3) & ~255L);
    long avail = (long)N * 256;                       // hacc alias bytes
    int capmax = (int)((avail / ((long)NRANGES * 8)) & ~255L);
    if (cap > capmax) cap = capmax;
    if (cap < 1024) cap = 1024;

    // ---- workspace layout ----
    char* p = (char*)d_ws;
    int*   flags  = (int*)p;                    p += 256;
    unsigned short* ctxb  = (unsigned short*)p; p += (size_t)N * 128 * 2;
    unsigned short* fused = (unsigned short*)p; p += (size_t)N * 96 * 2;
    unsigned short* cb    = (unsigned short*)p; p += (size_t)N * 64 * 2;
    unsigned short* lin   = (unsigned short*)p; p += (size_t)N * 64 * 2;
    unsigned short* h1    = (unsigned short*)p; p += (size_t)N * 64 * 2;
    unsigned short* hb    = (unsigned short*)p; p += (size_t)N * 64 * 2;
    float* hacc   = (float*)p;                  p += (size_t)N * 64 * 4;
    float* dinv   = (float*)p;                  p += (size_t)N2 * 4;
    int*   rowptr = (int*)p;                    p += (size_t)(N2 + 64) * 4;
    int*   rowcnt = (int*)p;                    p += (size_t)(N2 + 64) * 4;
    int*   gcur   = (int*)p;                    p += (size_t)NRANGES * 4;
    int*   rstart = (int*)p;                    p += (size_t)(NRANGES + 8) * 4;
    int*   srcs   = (int*)p;                    p += (size_t)E * 4;
    // edge buckets (int2, NRANGES*cap*8 <= N*256) alias hacc (dead until gather mode 1)
    int2*  ebuf   = (int2*)hacc;
    float* out    = (float*)d_out;

    const unsigned rowBlocks32 = (unsigned)((N + 31) / 32);
    const unsigned nodeBlocks  = (unsigned)((N + 3) / 4);
    const unsigned ppBlocks    = (unsigned)((E + PASSP_EDGES - 1) / PASSP_EDGES);
    const unsigned mmBlocks    = 391;

    // [detect | initcur]
    detect_kernel<<<3, 256, 0, stream>>>((const unsigned char*)mask, (const int*)adj_ei,
                                         flags, gcur, cap);
    // [passp | prep]
    passp_prep_kernel<<<ppBlocks + rowBlocks32, 256, 0, stream>>>(
        adj_ei, E1, tr_ei, E2, N, flags, gcur, cap, ebuf, (int)ppBlocks,
        context, target, mask, mask_token, te_W, te_b, ctxb, fused);
    // [mfma_ln | rscan]
    ln_rscan_kernel<<<mmBlocks + 1, 256, 0, stream>>>(
        ctxb, ce_W1, ce_b1, ce_g, ce_be, cb, N, (int)mmBlocks,
        gcur, cap, rstart, rowptr, N2);
    // [passq | mfma_gelu]
    passq_gelu_kernel<<<NRANGES + mmBlocks, 256, 0, stream>>>(
        rstart, ebuf, cap, N2, rowptr, rowcnt, dinv, srcs,
        cb, ce_W2, ce_b2, fused, N, (int)mmBlocks);

    const float* dinv_a = dinv;
    const float* dinv_t = dinv + N;
    const int*   row_a  = rowptr;
    const int*   row_t  = rowptr + N;
    const int*   cnt_a  = rowcnt;
    const int*   cnt_t  = rowcnt + N;

    // ---- spatial branch ----
    mfma_matmul<96><<<mmBlocks, 256, 0, stream>>>(fused, g1_W, dinv_a, lin, N);
    gather_kernel<<<nodeBlocks, 256, 0, stream>>>(row_a, cnt_a, srcs, dinv_a, lin, g1_b, alpha, 0, h1, hacc, N);
    mfma_matmul<64><<<mmBlocks, 256, 0, stream>>>(h1, g2_W, dinv_a, lin, N);
    gather_kernel<<<nodeBlocks, 256, 0, stream>>>(row_a, cnt_a, srcs, dinv_a, lin, g2_b, alpha, 1, hb, hacc, N);

    // ---- transit branch ----
    mfma_matmul<96><<<mmBlocks, 256, 0, stream>>>(fused, t1_W, dinv_t, lin, N);
    gather_kernel<<<nodeBlocks, 256, 0, stream>>>(row_t, cnt_t, srcs, dinv_t, lin, t1_b, alpha, 0, h1, hacc, N);
    mfma_matmul<64><<<mmBlocks, 256, 0, stream>>>(h1, t2_W, dinv_t, lin, N);
    gather_kernel<<<nodeBlocks, 256, 0, stream>>>(row_t, cnt_t, srcs, dinv_t, lin, t2_b, alpha, 2, hb, hacc, N);

    // ---- head (MFMA) ----
    head_mfma_kernel<<<mmBlocks, 256, 0, stream>>>(hb, fused, h_W1, h_b1, h_g, h_be,
                                                   h_W2, h_b2, out, N);
}

// Round 5
// 484.613 us; speedup vs baseline: 1.4575x; 1.1203x over previous
//
#include <hip/hip_runtime.h>
#include <math.h>

// UrbanModelV2: encoder MLPs -> 4x GCNConv (2 graphs) -> gated combine -> LN-MLP head.
// N=100000, CTX=128, TGT=32, H=64, FUS=96, E1=1.6M, E2=0.8M. fp32 in/out.
//
// R14: (1) passp: u32-packed edges (src | localdst<<sbits), PASSP_EDGES=8192
//   (full-line bucket runs, half the alloc atomics), gcur strided 64B.
//   (2) gathers fused across graphs: one wave does adj+transit for its node;
//   layer2 applies the gated combine in-register -> hacc eliminated.
//   (3) matmuls paired: layer1 dual-weight (shared A-fragments), layer2
//   block-split. 9 launches.

#define LN_EPS 1e-5f
#define NRANGES 512
#define RMASK 511
#define LSHIFT 9
#define PASSP_EDGES 8192
#define GSTRIDE 16            // gcur element stride (64B lines)

typedef __attribute__((ext_vector_type(8))) short short8;            // 8 bf16
typedef __attribute__((ext_vector_type(4))) float float4v;           // MFMA acc
typedef __attribute__((ext_vector_type(4))) unsigned short ushort4v; // 4 bf16

__device__ __forceinline__ float gelu_exact(float x) {
    return 0.5f * x * (1.0f + erff(x * 0.70710678118654752440f));
}

// reduce across the 16-lane quad-group (lane masks 1..8 stay within group)
__device__ __forceinline__ float qsum16(float v) {
#pragma unroll
    for (int m = 1; m < 16; m <<= 1)
        v += __shfl_xor(v, m, 64);
    return v;
}

__device__ __forceinline__ int load_edge(const void* ei, int is32, long idx) {
    return is32 ? ((const int*)ei)[idx] : (int)((const long long*)ei)[idx];
}

__device__ __forceinline__ unsigned short f32_to_bf16(float f) {
    unsigned int x = __float_as_uint(f);
    x += 0x7fffu + ((x >> 16) & 1u);   // RNE, finite values
    return (unsigned short)(x >> 16);
}
__device__ __forceinline__ float bf16_to_f32(unsigned short u) {
    return __uint_as_float((unsigned int)u << 16);
}

// load dst-nodes (transit offset by n) for edges base..base+3; nv = #valid
__device__ __forceinline__ void load_dst4(const void* ei1, int e1, const void* ei2, int e2,
                                          int n, int is32, int base, int nv, int nd[4]) {
    if (is32 && nv == 4) {
        if (base + 3 < e1 && (((e1 + base) & 3) == 0)) {
            int4 v = *(const int4*)((const int*)ei1 + (size_t)e1 + base);
            nd[0] = v.x; nd[1] = v.y; nd[2] = v.z; nd[3] = v.w;
            return;
        }
        if (base >= e1 && (((e2 + base - e1) & 3) == 0)) {
            int4 v = *(const int4*)((const int*)ei2 + (size_t)e2 + (base - e1));
            nd[0] = v.x + n; nd[1] = v.y + n; nd[2] = v.z + n; nd[3] = v.w + n;
            return;
        }
    }
#pragma unroll
    for (int u = 0; u < 4; ++u) {
        int i = base + u;
        if (u >= nv) { nd[u] = -1; continue; }
        if (i < e1) nd[u] = load_edge(ei1, is32, (long)e1 + i);
        else        nd[u] = load_edge(ei2, is32, (long)e2 + (i - e1)) + n;
    }
}

// load src-nodes for edges base..base+3; nv = #valid
__device__ __forceinline__ void load_src4(const void* ei1, int e1, const void* ei2, int e2,
                                          int is32, int base, int nv, int ns[4]) {
    if (is32 && nv == 4) {
        if (base + 3 < e1 && ((base & 3) == 0)) {
            int4 v = *(const int4*)((const int*)ei1 + base);
            ns[0] = v.x; ns[1] = v.y; ns[2] = v.z; ns[3] = v.w;
            return;
        }
        if (base >= e1 && (((base - e1) & 3) == 0)) {
            int4 v = *(const int4*)((const int*)ei2 + (base - e1));
            ns[0] = v.x; ns[1] = v.y; ns[2] = v.z; ns[3] = v.w;
            return;
        }
    }
#pragma unroll
    for (int u = 0; u < 4; ++u) {
        int i = base + u;
        if (u >= nv) { ns[u] = 0; continue; }
        if (i < e1) ns[u] = load_edge(ei1, is32, i);
        else        ns[u] = load_edge(ei2, is32, (long)(i - e1));
    }
}

// ---------------- dtype detection + cursor init ----------------
__global__ __launch_bounds__(256) void detect_kernel(const unsigned char* __restrict__ mask_bytes,
                                                     const int* __restrict__ ei_words,
                                                     int* __restrict__ flags,
                                                     int* __restrict__ gcur, int cap) {
    if (blockIdx.x == 0) {
        __shared__ int f0, f1;
        if (threadIdx.x == 0) { f0 = 0; f1 = 0; }
        __syncthreads();
        int i = threadIdx.x;
        if ((i & 3) != 0 && mask_bytes[i] != 0) f0 = 1;
        if (i < 64 && ei_words[2 * i + 1] != 0) f1 = 1;
        __syncthreads();
        if (threadIdx.x == 0) { flags[0] = f0; flags[1] = f1; }
    } else {
        int r = (blockIdx.x - 1) * 256 + threadIdx.x;
        if (r < NRANGES) gcur[r * GSTRIDE] = r * cap;
    }
}

// ---------------- CSR stage 1 body: partition edges into range buckets ----------------
__device__ __forceinline__ void passp_body(
    const void* ei1, int e1, const void* ei2, int e2,
    int n, const int* flags, int* gcur, int cap, unsigned* ebuf, int sbits, int bid)
{
    __shared__ int hist[NRANGES];
    __shared__ int base[NRANGES];
    const int E = e1 + e2;
    const int is32 = flags[1];
    const int b0 = bid * PASSP_EDGES;
    const int bend = (b0 + PASSP_EDGES < E) ? b0 + PASSP_EDGES : E;

    for (int k = threadIdx.x; k < NRANGES; k += 256) hist[k] = 0;
    __syncthreads();

    // pass 1: histogram; the atomic return IS the local rank (kept in regs)
    int nd[32], rk[32];
#pragma unroll
    for (int j = 0; j < 8; ++j) {
        int bi = b0 + j * 1024 + (int)threadIdx.x * 4;
        int nv = bend - bi; nv = (nv < 0) ? 0 : (nv > 4 ? 4 : nv);
        load_dst4(ei1, e1, ei2, e2, n, is32, bi, nv, &nd[j * 4]);
#pragma unroll
        for (int u = 0; u < 4; ++u)
            if (u < nv) rk[j * 4 + u] = atomicAdd(&hist[nd[j * 4 + u] & RMASK], 1);
    }
    __syncthreads();

    // allocate: one device atomic per nonempty (block,range); gcur strided 64B
    for (int r = threadIdx.x; r < NRANGES; r += 256) {
        int c = hist[r];
        base[r] = c ? atomicAdd(&gcur[r * GSTRIDE], c) : 0;
    }
    __syncthreads();

    // pass 2: pure 4B packed scatter, no LDS ops
#pragma unroll
    for (int j = 0; j < 8; ++j) {
        int bi = b0 + j * 1024 + (int)threadIdx.x * 4;
        int nv = bend - bi; nv = (nv < 0) ? 0 : (nv > 4 ? 4 : nv);
        int sv[4];
        load_src4(ei1, e1, ei2, e2, is32, bi, nv, sv);
#pragma unroll
        for (int u = 0; u < 4; ++u) {
            if (u < nv) {
                int d = nd[j * 4 + u];
                int r = d & RMASK;
                int pos = base[r] + rk[j * 4 + u];
                if (pos < (r + 1) * cap)   // capacity guard (memory safety)
                    ebuf[pos] = (unsigned)sv[u] | ((unsigned)(d >> LSHIFT) << sbits);
            }
        }
    }
}

// ---------------- prep body: ctx->bf16 + masked-target encoder -> fused[:,64:96] ----------------
__device__ __forceinline__ void prep_body(
    const float* context, const float* target, const void* mask, const int* flags,
    const float* mask_token, const float* te_W, const float* te_b,
    unsigned short* ctxb, unsigned short* fused, int n, int bid)
{
    __shared__ float tbuf[32][32];
    int w = threadIdx.x >> 6;
    int j = threadIdx.x & 63;
    int r0 = __builtin_amdgcn_readfirstlane(bid * 32 + w * 8);
    if (r0 >= n) return;  // N % 32 == 0

    const float4* src = (const float4*)(context + (size_t)r0 * 128);
    ushort4v* dst = (ushort4v*)(ctxb + (size_t)r0 * 128);
#pragma unroll
    for (int p = 0; p < 4; ++p) {
        float4 v = src[p * 64 + j];
        ushort4v o;
        o.x = f32_to_bf16(v.x); o.y = f32_to_bf16(v.y);
        o.z = f32_to_bf16(v.z); o.w = f32_to_bf16(v.w);
        dst[p * 64 + j] = o;
    }

    int tr = j >> 5;
    int tj = j & 31;
#pragma unroll
    for (int rr = 0; rr < 4; ++rr) {
        int r = tr + rr * 2;
        long mi = (long)(r0 + r) * 32 + tj;
        int mraw = flags[0] ? (int)((const unsigned char*)mask)[mi]
                            : ((const int*)mask)[mi];
        float m = mraw ? 1.0f : 0.0f;
        tbuf[w * 8 + r][tj] = target[mi] * (1.0f - m) + mask_token[tj] * m;
    }

#pragma unroll
    for (int rr = 0; rr < 4; ++rr) {
        int r = tr + rr * 2;
        float y3 = te_b[tj];
#pragma unroll
        for (int k = 0; k < 32; ++k)
            y3 = fmaf(tbuf[w * 8 + r][k], te_W[k * 32 + tj], y3);
        fused[(long)(r0 + r) * 96 + 64 + tj] = f32_to_bf16(gelu_exact(y3));
    }
}

// ---------------- fused kernel A: passp | prep ----------------
__global__ __launch_bounds__(256) void passp_prep_kernel(
    const void* __restrict__ ei1, int e1, const void* __restrict__ ei2, int e2,
    int n, const int* __restrict__ flags, int* __restrict__ gcur, int cap,
    unsigned* __restrict__ ebuf, int sbits, int ppBlocks,
    const float* __restrict__ context, const float* __restrict__ target,
    const void* __restrict__ mask, const float* __restrict__ mask_token,
    const float* __restrict__ te_W, const float* __restrict__ te_b,
    unsigned short* __restrict__ ctxb, unsigned short* __restrict__ fused)
{
    if ((int)blockIdx.x < ppBlocks)
        passp_body(ei1, e1, ei2, e2, n, flags, gcur, cap, ebuf, sbits, blockIdx.x);
    else
        prep_body(context, target, mask, flags, mask_token, te_W, te_b,
                  ctxb, fused, n, blockIdx.x - ppBlocks);
}

// ---------------- CSR stage 2 body: prefix over 512 range totals (256 thr) ----------------
__device__ __forceinline__ void rscan_body(const int* gcur, int cap,
                                           int* rstart, int* rowptr, int n2) {
    __shared__ int ws[256];
    int t = threadIdx.x;
    int i0 = 2 * t, i1 = 2 * t + 1;
    int a0 = gcur[i0 * GSTRIDE] - i0 * cap;
    int a1 = gcur[i1 * GSTRIDE] - i1 * cap;
    ws[t] = a0 + a1;
    __syncthreads();
    for (int off = 1; off < 256; off <<= 1) {
        int v = (t >= off) ? ws[t - off] : 0;
        __syncthreads();
        if (t >= off) ws[t] += v;
        __syncthreads();
    }
    int ex = t ? ws[t - 1] : 0;
    rstart[i0] = ex;
    rstart[i1] = ex + a0;
    if (t == 255) { rstart[NRANGES] = ws[255]; rowptr[n2] = ws[255]; }
}

// ---------------- MFMA encoder layer 1 body: LN+GELU epilogue ----------------
__device__ __forceinline__ void mfma_ln_body(
    const unsigned short* x, const float* W, const float* bias, const float* g,
    const float* beta, unsigned short* y, int n, int bid, int nblk)
{
    constexpr int K = 128, KS = K / 32, STRIDE = K + 8;
    __shared__ __align__(16) unsigned short wt[64 * STRIDE];
    int n0 = threadIdx.x & 63;
    int kk = threadIdx.x >> 6;
    for (int k = kk; k < K; k += 4)
        wt[n0 * STRIDE + k] = f32_to_bf16(W[k * 64 + n0]);
    __syncthreads();

    int w = threadIdx.x >> 6;
    int lane = threadIdx.x & 63;
    int c = lane & 15;
    int q = lane >> 4;

    short8 bfrag[KS][4];
#pragma unroll
    for (int s = 0; s < KS; ++s)
#pragma unroll
        for (int nt = 0; nt < 4; ++nt)
            bfrag[s][nt] = *(const short8*)&wt[(nt * 16 + c) * STRIDE + s * 32 + q * 8];

    float bs[4], gs[4], be[4];
#pragma unroll
    for (int nt = 0; nt < 4; ++nt) {
        bs[nt] = bias[nt * 16 + c];
        gs[nt] = g[nt * 16 + c];
        be[nt] = beta[nt * 16 + c];
    }

    int T = n >> 4;
    int stride = nblk * 4;
    for (int t = __builtin_amdgcn_readfirstlane(bid * 4 + w); t < T; t += stride) {
        int r0 = t << 4;
        const unsigned short* xa = x + (size_t)(r0 + c) * K + q * 8;
        float4v acc[4] = {{0,0,0,0},{0,0,0,0},{0,0,0,0},{0,0,0,0}};
#pragma unroll
        for (int s = 0; s < KS; ++s) {
            short8 a = *(const short8*)(xa + s * 32);
#pragma unroll
            for (int nt = 0; nt < 4; ++nt)
                acc[nt] = __builtin_amdgcn_mfma_f32_16x16x32_bf16(a, bfrag[s][nt], acc[nt], 0, 0, 0);
        }
#pragma unroll
        for (int reg = 0; reg < 4; ++reg) {
            float v0 = acc[0][reg] + bs[0];
            float v1 = acc[1][reg] + bs[1];
            float v2 = acc[2][reg] + bs[2];
            float v3 = acc[3][reg] + bs[3];
            float mean = qsum16((v0 + v1) + (v2 + v3)) * (1.0f / 64.0f);
            float x0 = v0 - mean, x1 = v1 - mean, x2 = v2 - mean, x3 = v3 - mean;
            float var = qsum16((x0 * x0 + x1 * x1) + (x2 * x2 + x3 * x3)) * (1.0f / 64.0f);
            float rstd = rsqrtf(var + LN_EPS);
            size_t row = (size_t)(r0 + q * 4 + reg) * 64;
            y[row + 0 * 16 + c] = f32_to_bf16(gelu_exact(x0 * rstd * gs[0] + be[0]));
            y[row + 1 * 16 + c] = f32_to_bf16(gelu_exact(x1 * rstd * gs[1] + be[1]));
            y[row + 2 * 16 + c] = f32_to_bf16(gelu_exact(x2 * rstd * gs[2] + be[2]));
            y[row + 3 * 16 + c] = f32_to_bf16(gelu_exact(x3 * rstd * gs[3] + be[3]));
        }
    }
}

// ---------------- fused kernel B: mfma_ln | rscan ----------------
__global__ __launch_bounds__(256) void ln_rscan_kernel(
    const unsigned short* __restrict__ x, const float* __restrict__ W,
    const float* __restrict__ bias, const float* __restrict__ g,
    const float* __restrict__ beta, unsigned short* __restrict__ y, int n, int nblk,
    const int* __restrict__ gcur, int cap, int* __restrict__ rstart,
    int* __restrict__ rowptr, int n2)
{
    if ((int)blockIdx.x == nblk)
        rscan_body(gcur, cap, rstart, rowptr, n2);
    else
        mfma_ln_body(x, W, bias, g, beta, y, n, blockIdx.x, nblk);
}

// ---------------- CSR stage 3 body: per-range CSR build ----------------
// range g owns nodes {d : (d & 511) == g}, local id l = d >> 9.
__device__ __forceinline__ void passq_body(
    const int* rstart, const unsigned* ebuf, int cap, int n2, int sbits,
    int* rowptr, int* rowcnt, float* dinv, int* srcs, int g)
{
    __shared__ int deg[NRANGES];
    __shared__ int cur[NRANGES];
    __shared__ int ws[256];
    const int t = threadIdx.x;
    const int gbase = rstart[g];
    const int total = rstart[g + 1] - gbase;
    const unsigned* eb = ebuf + (size_t)g * cap;
    const unsigned smask = (1u << sbits) - 1u;

    deg[2 * t] = 0; deg[2 * t + 1] = 0;
    __syncthreads();
    for (int i = t; i < total; i += 256)
        atomicAdd(&deg[eb[i] >> sbits], 1);
    __syncthreads();

    int a0 = deg[2 * t], a1 = deg[2 * t + 1];
    ws[t] = a0 + a1;
    __syncthreads();
    for (int off = 1; off < 256; off <<= 1) {
        int v = (t >= off) ? ws[t - off] : 0;
        __syncthreads();
        if (t >= off) ws[t] += v;
        __syncthreads();
    }
    int ex = t ? ws[t - 1] : 0;
    cur[2 * t] = ex;
    cur[2 * t + 1] = ex + a0;
    int node0 = ((2 * t) << LSHIFT) | g;
    int node1 = ((2 * t + 1) << LSHIFT) | g;
    if (node0 < n2) { rowptr[node0] = gbase + ex;      rowcnt[node0] = a0; dinv[node0] = rsqrtf((float)a0 + 1.0f); }
    if (node1 < n2) { rowptr[node1] = gbase + ex + a0; rowcnt[node1] = a1; dinv[node1] = rsqrtf((float)a1 + 1.0f); }
    __syncthreads();

    for (int i = t; i < total; i += 256) {
        unsigned e = eb[i];
        int rk = atomicAdd(&cur[e >> sbits], 1);
        srcs[gbase + rk] = (int)(e & smask);
    }
}

// ---------------- MFMA encoder layer 2 body: GELU epilogue, out stride 96 ----------------
__device__ __forceinline__ void mfma_gelu_body(
    const unsigned short* x, const float* W, const float* bias,
    unsigned short* y, int n, int bid, int nblk)
{
    constexpr int K = 64, KS = K / 32, STRIDE = K + 8;
    __shared__ __align__(16) unsigned short wt[64 * STRIDE];
    int n0 = threadIdx.x & 63;
    int kk = threadIdx.x >> 6;
    for (int k = kk; k < K; k += 4)
        wt[n0 * STRIDE + k] = f32_to_bf16(W[k * 64 + n0]);
    __syncthreads();

    int w = threadIdx.x >> 6;
    int lane = threadIdx.x & 63;
    int c = lane & 15;
    int q = lane >> 4;

    short8 bfrag[KS][4];
#pragma unroll
    for (int s = 0; s < KS; ++s)
#pragma unroll
        for (int nt = 0; nt < 4; ++nt)
            bfrag[s][nt] = *(const short8*)&wt[(nt * 16 + c) * STRIDE + s * 32 + q * 8];

    float bs[4];
#pragma unroll
    for (int nt = 0; nt < 4; ++nt) bs[nt] = bias[nt * 16 + c];

    int T = n >> 4;
    int stride = nblk * 4;
    for (int t = __builtin_amdgcn_readfirstlane(bid * 4 + w); t < T; t += stride) {
        int r0 = t << 4;
        const unsigned short* xa = x + (size_t)(r0 + c) * K + q * 8;
        float4v acc[4] = {{0,0,0,0},{0,0,0,0},{0,0,0,0},{0,0,0,0}};
#pragma unroll
        for (int s = 0; s < KS; ++s) {
            short8 a = *(const short8*)(xa + s * 32);
#pragma unroll
            for (int nt = 0; nt < 4; ++nt)
                acc[nt] = __builtin_amdgcn_mfma_f32_16x16x32_bf16(a, bfrag[s][nt], acc[nt], 0, 0, 0);
        }
#pragma unroll
        for (int nt = 0; nt < 4; ++nt)
#pragma unroll
            for (int reg = 0; reg < 4; ++reg)
                y[(size_t)(r0 + q * 4 + reg) * 96 + nt * 16 + c] =
                    f32_to_bf16(gelu_exact(acc[nt][reg] + bs[nt]));
    }
}

// ---------------- fused kernel C: passq | mfma_gelu ----------------
__global__ __launch_bounds__(256) void passq_gelu_kernel(
    const int* __restrict__ rstart, const unsigned* __restrict__ ebuf, int cap, int n2,
    int sbits, int* __restrict__ rowptr, int* __restrict__ rowcnt,
    float* __restrict__ dinv, int* __restrict__ srcs,
    const unsigned short* __restrict__ x, const float* __restrict__ W,
    const float* __restrict__ bias, unsigned short* __restrict__ y, int n, int nblk)
{
    if ((int)blockIdx.x < NRANGES)
        passq_body(rstart, ebuf, cap, n2, sbits, rowptr, rowcnt, dinv, srcs, blockIdx.x);
    else
        mfma_gelu_body(x, W, bias, y, n, blockIdx.x - NRANGES, nblk);
}

// ---------------- MFMA GCN matmul layer1 (dual-weight, shared A): ----------------
// yg = (x @ Wg) * dinv[row], yt = (x @ Wt) * dinv[n+row]
__global__ __launch_bounds__(256) void mm_l1_dual_kernel(
    const unsigned short* __restrict__ x, const float* __restrict__ Wg,
    const float* __restrict__ Wt, const float* __restrict__ dinv,
    unsigned short* __restrict__ yg, unsigned short* __restrict__ yt, int n)
{
    constexpr int K = 96, KS = K / 32, STRIDE = K + 8;
    __shared__ __align__(16) unsigned short wtg[64 * STRIDE];
    __shared__ __align__(16) unsigned short wtt[64 * STRIDE];
    int n0 = threadIdx.x & 63;
    int kk = threadIdx.x >> 6;
    for (int k = kk; k < K; k += 4) {
        wtg[n0 * STRIDE + k] = f32_to_bf16(Wg[k * 64 + n0]);
        wtt[n0 * STRIDE + k] = f32_to_bf16(Wt[k * 64 + n0]);
    }
    __syncthreads();

    int w = threadIdx.x >> 6;
    int lane = threadIdx.x & 63;
    int c = lane & 15;
    int q = lane >> 4;

    short8 bg[KS][4], bt[KS][4];
#pragma unroll
    for (int s = 0; s < KS; ++s)
#pragma unroll
        for (int nt = 0; nt < 4; ++nt) {
            bg[s][nt] = *(const short8*)&wtg[(nt * 16 + c) * STRIDE + s * 32 + q * 8];
            bt[s][nt] = *(const short8*)&wtt[(nt * 16 + c) * STRIDE + s * 32 + q * 8];
        }

    int T = n >> 4;
    int stride = gridDim.x * 4;
    for (int t = __builtin_amdgcn_readfirstlane(blockIdx.x * 4 + w); t < T; t += stride) {
        int r0 = t << 4;
        const unsigned short* xa = x + (size_t)(r0 + c) * K + q * 8;
        float4v ag[4] = {{0,0,0,0},{0,0,0,0},{0,0,0,0},{0,0,0,0}};
        float4v at[4] = {{0,0,0,0},{0,0,0,0},{0,0,0,0},{0,0,0,0}};
#pragma unroll
        for (int s = 0; s < KS; ++s) {
            short8 a = *(const short8*)(xa + s * 32);
#pragma unroll
            for (int nt = 0; nt < 4; ++nt) {
                ag[nt] = __builtin_amdgcn_mfma_f32_16x16x32_bf16(a, bg[s][nt], ag[nt], 0, 0, 0);
                at[nt] = __builtin_amdgcn_mfma_f32_16x16x32_bf16(a, bt[s][nt], at[nt], 0, 0, 0);
            }
        }
        float sg[4], st[4];
#pragma unroll
        for (int reg = 0; reg < 4; ++reg) {
            sg[reg] = dinv[r0 + q * 4 + reg];
            st[reg] = dinv[n + r0 + q * 4 + reg];
        }
#pragma unroll
        for (int nt = 0; nt < 4; ++nt)
#pragma unroll
            for (int reg = 0; reg < 4; ++reg) {
                size_t row = (size_t)(r0 + q * 4 + reg) * 64 + nt * 16 + c;
                yg[row] = f32_to_bf16(ag[nt][reg] * sg[reg]);
                yt[row] = f32_to_bf16(at[nt][reg] * st[reg]);
            }
    }
}

// ---------------- MFMA GCN matmul body (single), K=64 ----------------
__device__ __forceinline__ void mm64_body(const unsigned short* x, const float* W,
                                          const float* scale, unsigned short* y,
                                          int n, int bid, int nblk) {
    constexpr int K = 64, KS = K / 32, STRIDE = K + 8;
    __shared__ __align__(16) unsigned short wt[64 * STRIDE];
    int n0 = threadIdx.x & 63;
    int kk = threadIdx.x >> 6;
    for (int k = kk; k < K; k += 4)
        wt[n0 * STRIDE + k] = f32_to_bf16(W[k * 64 + n0]);
    __syncthreads();

    int w = threadIdx.x >> 6;
    int lane = threadIdx.x & 63;
    int c = lane & 15;
    int q = lane >> 4;

    short8 bfrag[KS][4];
#pragma unroll
    for (int s = 0; s < KS; ++s)
#pragma unroll
        for (int nt = 0; nt < 4; ++nt)
            bfrag[s][nt] = *(const short8*)&wt[(nt * 16 + c) * STRIDE + s * 32 + q * 8];

    int T = n >> 4;
    int stride = nblk * 4;
    for (int t = __builtin_amdgcn_readfirstlane(bid * 4 + w); t < T; t += stride) {
        int r0 = t << 4;
        const unsigned short* xa = x + (size_t)(r0 + c) * K + q * 8;
        float4v acc[4] = {{0,0,0,0},{0,0,0,0},{0,0,0,0},{0,0,0,0}};
#pragma unroll
        for (int s = 0; s < KS; ++s) {
            short8 a = *(const short8*)(xa + s * 32);
#pragma unroll
            for (int nt = 0; nt < 4; ++nt)
                acc[nt] = __builtin_amdgcn_mfma_f32_16x16x32_bf16(a, bfrag[s][nt], acc[nt], 0, 0, 0);
        }
        float sc[4];
#pragma unroll
        for (int reg = 0; reg < 4; ++reg)
            sc[reg] = scale[r0 + q * 4 + reg];
#pragma unroll
        for (int nt = 0; nt < 4; ++nt)
#pragma unroll
            for (int reg = 0; reg < 4; ++reg)
                y[(size_t)(r0 + q * 4 + reg) * 64 + nt * 16 + c] = f32_to_bf16(acc[nt][reg] * sc[reg]);
    }
}

// ---------------- layer2 matmuls, block-split ----------------
__global__ __launch_bounds__(256) void mm_l2_kernel(
    const unsigned short* __restrict__ xg, const unsigned short* __restrict__ xt,
    const float* __restrict__ Wg, const float* __restrict__ Wt,
    const float* __restrict__ dinv,
    unsigned short* __restrict__ yg, unsigned short* __restrict__ yt, int n, int nblk)
{
    if ((int)blockIdx.x < nblk)
        mm64_body(xg, Wg, dinv, yg, n, blockIdx.x, nblk);
    else
        mm64_body(xt, Wt, dinv + n, yt, n, blockIdx.x - nblk, nblk);
}

// ---------------- fused gather: both graphs per wave ----------------
__device__ __forceinline__ float gather_row(const int* srcs, const unsigned short* lin,
                                            int beg, int cnt, int j) {
    float acc = 0.0f;
    for (int base = beg; base < beg + cnt; base += 64) {
        int c2 = beg + cnt - base;
        if (c2 > 64) c2 = 64;
        int sj = (j < c2) ? srcs[base + j] : 0;
        int t = 0;
        for (; t + 8 <= c2; t += 8) {
            float v[8];
#pragma unroll
            for (int u = 0; u < 8; ++u) {
                int s = __shfl(sj, t + u, 64);
                v[u] = bf16_to_f32(lin[(long)s * 64 + j]);
            }
            acc += ((v[0] + v[1]) + (v[2] + v[3])) + ((v[4] + v[5]) + (v[6] + v[7]));
        }
        for (; t < c2; ++t) {
            int s = __shfl(sj, t, 64);
            acc += bf16_to_f32(lin[(long)s * 64 + j]);
        }
    }
    return acc;
}

// layer 1: h1g = gelu(gcn_pre(adj, lin_g, g1_b)); h1t = gelu(gcn_pre(tr, lin_t, t1_b))
__global__ __launch_bounds__(256) void gather_l1_kernel(
    const int* __restrict__ rowptr, const int* __restrict__ rowcnt,
    const int* __restrict__ srcs, const float* __restrict__ dinv,
    const unsigned short* __restrict__ ling, const unsigned short* __restrict__ lint,
    const float* __restrict__ bg, const float* __restrict__ bt,
    unsigned short* __restrict__ h1g, unsigned short* __restrict__ h1t, int n)
{
    int w = threadIdx.x >> 6;
    int j = threadIdx.x & 63;
    int node = __builtin_amdgcn_readfirstlane(blockIdx.x * 4 + w);
    if (node >= n) return;
    long oi = (long)node * 64 + j;

    float ag = gather_row(srcs, ling, rowptr[node], rowcnt[node], j);
    float pg = fmaf(dinv[node], ag + bf16_to_f32(ling[oi]), bg[j]);
    h1g[oi] = f32_to_bf16(gelu_exact(pg));

    int tn = n + node;
    float at = gather_row(srcs, lint, rowptr[tn], rowcnt[tn], j);
    float pt = fmaf(dinv[tn], at + bf16_to_f32(lint[oi]), bt[j]);
    h1t[oi] = f32_to_bf16(gelu_exact(pt));
}

// layer 2: hb = bf16( a*gcn_pre(adj, lin_g, g2_b) + (1-a)*gcn_pre(tr, lin_t, t2_b) )
__global__ __launch_bounds__(256) void gather_l2_kernel(
    const int* __restrict__ rowptr, const int* __restrict__ rowcnt,
    const int* __restrict__ srcs, const float* __restrict__ dinv,
    const unsigned short* __restrict__ ling, const unsigned short* __restrict__ lint,
    const float* __restrict__ bg, const float* __restrict__ bt,
    const float* __restrict__ alpha_ptr, unsigned short* __restrict__ hb, int n)
{
    int w = threadIdx.x >> 6;
    int j = threadIdx.x & 63;
    int node = __builtin_amdgcn_readfirstlane(blockIdx.x * 4 + w);
    if (node >= n) return;
    long oi = (long)node * 64 + j;

    float ag = gather_row(srcs, ling, rowptr[node], rowcnt[node], j);
    float pg = fmaf(dinv[node], ag + bf16_to_f32(ling[oi]), bg[j]);

    int tn = n + node;
    float at = gather_row(srcs, lint, rowptr[tn], rowcnt[tn], j);
    float pt = fmaf(dinv[tn], at + bf16_to_f32(lint[oi]), bt[j]);

    float a = 1.0f / (1.0f + expf(-alpha_ptr[0]));
    hb[oi] = f32_to_bf16(a * pg + (1.0f - a) * pt);
}

// ---------------- MFMA head: [hb|fused] @ W1 -> LN -> gelu -> @ W2 + b2 ----------------
__global__ __launch_bounds__(256) void head_mfma_kernel(
    const unsigned short* __restrict__ hb, const unsigned short* __restrict__ fused,
    const float* __restrict__ h_W1, const float* __restrict__ h_b1,
    const float* __restrict__ h_g, const float* __restrict__ h_beta,
    const float* __restrict__ h_W2, const float* __restrict__ h_b2,
    float* __restrict__ out, int n)
{
    constexpr int ST1 = 168;  // 160 + 8
    constexpr int ST2 = 72;   // 64 + 8
    __shared__ __align__(16) unsigned short wt1[64 * ST1];     // 21504 B
    __shared__ __align__(16) unsigned short wt2[32 * ST2];     // 4608 B
    __shared__ __align__(16) unsigned short zl[4][16 * ST2];   // 9216 B

    int n0 = threadIdx.x & 63;
    int kk = threadIdx.x >> 6;
    for (int k = kk; k < 160; k += 4)
        wt1[n0 * ST1 + k] = f32_to_bf16(h_W1[k * 64 + n0]);
    if (n0 < 32)
        for (int k = kk; k < 64; k += 4)
            wt2[n0 * ST2 + k] = f32_to_bf16(h_W2[k * 32 + n0]);
    __syncthreads();

    int w = threadIdx.x >> 6;
    int lane = threadIdx.x & 63;
    int c = lane & 15;
    int q = lane >> 4;

    short8 b1f[5][4];
#pragma unroll
    for (int s = 0; s < 5; ++s)
#pragma unroll
        for (int nt = 0; nt < 4; ++nt)
            b1f[s][nt] = *(const short8*)&wt1[(nt * 16 + c) * ST1 + s * 32 + q * 8];
    short8 b2f[2][2];
#pragma unroll
    for (int s = 0; s < 2; ++s)
#pragma unroll
        for (int nt = 0; nt < 2; ++nt)
            b2f[s][nt] = *(const short8*)&wt2[(nt * 16 + c) * ST2 + s * 32 + q * 8];

    float bs[4], gs[4], be[4];
#pragma unroll
    for (int nt = 0; nt < 4; ++nt) {
        bs[nt] = h_b1[nt * 16 + c];
        gs[nt] = h_g[nt * 16 + c];
        be[nt] = h_beta[nt * 16 + c];
    }
    float b2s[2];
#pragma unroll
    for (int nt = 0; nt < 2; ++nt) b2s[nt] = h_b2[nt * 16 + c];

    unsigned short* zw = zl[w];
    int T = n >> 4;
    int stride = gridDim.x * 4;
    for (int t = __builtin_amdgcn_readfirstlane(blockIdx.x * 4 + w); t < T; t += stride) {
        int r0 = t << 4;
        // stage 1: K=160 (hb: k 0..63, fused: k 64..159)
        const unsigned short* xh = hb + (size_t)(r0 + c) * 64 + q * 8;
        const unsigned short* xf = fused + (size_t)(r0 + c) * 96 + q * 8;
        float4v acc[4] = {{0,0,0,0},{0,0,0,0},{0,0,0,0},{0,0,0,0}};
#pragma unroll
        for (int s = 0; s < 2; ++s) {
            short8 a = *(const short8*)(xh + s * 32);
#pragma unroll
            for (int nt = 0; nt < 4; ++nt)
                acc[nt] = __builtin_amdgcn_mfma_f32_16x16x32_bf16(a, b1f[s][nt], acc[nt], 0, 0, 0);
        }
#pragma unroll
        for (int s = 0; s < 3; ++s) {
            short8 a = *(const short8*)(xf + s * 32);
#pragma unroll
            for (int nt = 0; nt < 4; ++nt)
                acc[nt] = __builtin_amdgcn_mfma_f32_16x16x32_bf16(a, b1f[2 + s][nt], acc[nt], 0, 0, 0);
        }
        // epilogue: +b1, LN per row (q*4+reg), gelu -> zl (wave-private)
#pragma unroll
        for (int reg = 0; reg < 4; ++reg) {
            float v0 = acc[0][reg] + bs[0];
            float v1 = acc[1][reg] + bs[1];
            float v2 = acc[2][reg] + bs[2];
            float v3 = acc[3][reg] + bs[3];
            float mean = qsum16((v0 + v1) + (v2 + v3)) * (1.0f / 64.0f);
            float x0 = v0 - mean, x1 = v1 - mean, x2 = v2 - mean, x3 = v3 - mean;
            float var = qsum16((x0 * x0 + x1 * x1) + (x2 * x2 + x3 * x3)) * (1.0f / 64.0f);
            float rstd = rsqrtf(var + LN_EPS);
            int row = q * 4 + reg;
            zw[row * ST2 + 0 * 16 + c] = f32_to_bf16(gelu_exact(x0 * rstd * gs[0] + be[0]));
            zw[row * ST2 + 1 * 16 + c] = f32_to_bf16(gelu_exact(x1 * rstd * gs[1] + be[1]));
            zw[row * ST2 + 2 * 16 + c] = f32_to_bf16(gelu_exact(x2 * rstd * gs[2] + be[2]));
            zw[row * ST2 + 3 * 16 + c] = f32_to_bf16(gelu_exact(x3 * rstd * gs[3] + be[3]));
        }
        // stage 2: z (16x64) @ W2 (64x32); same-wave LDS write->read, no barrier
        float4v acc2[2] = {{0,0,0,0},{0,0,0,0}};
#pragma unroll
        for (int s = 0; s < 2; ++s) {
            short8 a2 = *(const short8*)&zw[c * ST2 + s * 32 + q * 8];
#pragma unroll
            for (int nt = 0; nt < 2; ++nt)
                acc2[nt] = __builtin_amdgcn_mfma_f32_16x16x32_bf16(a2, b2f[s][nt], acc2[nt], 0, 0, 0);
        }
#pragma unroll
        for (int nt = 0; nt < 2; ++nt)
#pragma unroll
            for (int reg = 0; reg < 4; ++reg)
                out[(size_t)(r0 + q * 4 + reg) * 32 + nt * 16 + c] = acc2[nt][reg] + b2s[nt];
    }
}

extern "C" void kernel_launch(void* const* d_in, const int* in_sizes, int n_in,
                              void* d_out, int out_size, void* d_ws, size_t ws_size,
                              hipStream_t stream) {
    const float* context    = (const float*)d_in[0];
    const float* target     = (const float*)d_in[1];
    const void*  mask       = d_in[2];
    const void*  adj_ei     = d_in[3];
    const void*  tr_ei      = d_in[4];
    const float* mask_token = (const float*)d_in[5];
    const float* ce_W1 = (const float*)d_in[6];
    const float* ce_b1 = (const float*)d_in[7];
    const float* ce_g  = (const float*)d_in[8];
    const float* ce_be = (const float*)d_in[9];
    const float* ce_W2 = (const float*)d_in[10];
    const float* ce_b2 = (const float*)d_in[11];
    const float* te_W  = (const float*)d_in[12];
    const float* te_b  = (const float*)d_in[13];
    const float* g1_W  = (const float*)d_in[14];
    const float* g1_b  = (const float*)d_in[15];
    const float* g2_W  = (const float*)d_in[16];
    const float* g2_b  = (const float*)d_in[17];
    const float* t1_W  = (const float*)d_in[18];
    const float* t1_b  = (const float*)d_in[19];
    const float* t2_W  = (const float*)d_in[20];
    const float* t2_b  = (const float*)d_in[21];
    const float* alpha = (const float*)d_in[22];
    const float* h_W1  = (const float*)d_in[23];
    const float* h_b1  = (const float*)d_in[24];
    const float* h_g   = (const float*)d_in[25];
    const float* h_be  = (const float*)d_in[26];
    const float* h_W2  = (const float*)d_in[27];
    const float* h_b2  = (const float*)d_in[28];

    const int N  = in_sizes[0] / 128;
    const int E1 = in_sizes[3] / 2;
    const int E2 = in_sizes[4] / 2;
    const int E  = E1 + E2;
    const int N2 = 2 * N;

    // src-id bit width for u32 edge packing (src < N)
    int sbits = 1;
    while ((1 << sbits) < N) ++sbits;

    // per-range bucket capacity (range = node & 511 -> uniform load)
    long expct = (E + NRANGES - 1) / NRANGES;
    int cap = (int)((expct * 4 / 3) & ~255L);
    long avail = (long)N * 128;                       // ebuf alias bytes (hacc[0 : N*128])
    int capmax = (int)((avail / ((long)NRANGES * 4)) & ~255L);
    if (cap > capmax) cap = capmax;
    if (cap < 1024) cap = 1024;

    // ---- workspace layout ----
    char* p = (char*)d_ws;
    int*   flags  = (int*)p;                    p += 256;
    unsigned short* ctxb  = (unsigned short*)p; p += (size_t)N * 128 * 2;
    unsigned short* fused = (unsigned short*)p; p += (size_t)N * 96 * 2;
    unsigned short* cb    = (unsigned short*)p; p += (size_t)N * 64 * 2;
    unsigned short* lin   = (unsigned short*)p; p += (size_t)N * 64 * 2;
    unsigned short* h1    = (unsigned short*)p; p += (size_t)N * 64 * 2;
    unsigned short* hb    = (unsigned short*)p; p += (size_t)N * 64 * 2;
    float* hacc   = (float*)p;                  p += (size_t)N * 64 * 4;
    float* dinv   = (float*)p;                  p += (size_t)N2 * 4;
    int*   rowptr = (int*)p;                    p += (size_t)(N2 + 64) * 4;
    int*   rowcnt = (int*)p;                    p += (size_t)(N2 + 64) * 4;
    int*   gcur   = (int*)p;                    p += (size_t)NRANGES * GSTRIDE * 4;
    int*   rstart = (int*)p;                    p += (size_t)(NRANGES + 8) * 4;
    int*   srcs   = (int*)p;                    p += (size_t)E * 4;
    // hacc region (25.6MB) reuse: ebuf (u32, <= N*128 B) then h1t (N*128 B).
    // ebuf dead after passq (launch 4); h1t written launch 6 - disjoint regions anyway.
    unsigned*       ebuf = (unsigned*)hacc;
    unsigned short* h1t  = (unsigned short*)((char*)hacc + (size_t)N * 128);
    unsigned short* h1g  = h1;
    unsigned short* ling = lin;
    unsigned short* lint = cb;   // cb dead after passq_gelu
    float* out    = (float*)d_out;

    const unsigned rowBlocks32 = (unsigned)((N + 31) / 32);
    const unsigned nodeBlocks  = (unsigned)((N + 3) / 4);
    const unsigned ppBlocks    = (unsigned)((E + PASSP_EDGES - 1) / PASSP_EDGES);
    const unsigned mmBlocks    = 391;

    // [detect | initcur]
    detect_kernel<<<3, 256, 0, stream>>>((const unsigned char*)mask, (const int*)adj_ei,
                                         flags, gcur, cap);
    // [passp | prep]
    passp_prep_kernel<<<ppBlocks + rowBlocks32, 256, 0, stream>>>(
        adj_ei, E1, tr_ei, E2, N, flags, gcur, cap, ebuf, sbits, (int)ppBlocks,
        context, target, mask, mask_token, te_W, te_b, ctxb, fused);
    // [mfma_ln | rscan]
    ln_rscan_kernel<<<mmBlocks + 1, 256, 0, stream>>>(
        ctxb, ce_W1, ce_b1, ce_g, ce_be, cb, N, (int)mmBlocks,
        gcur, cap, rstart, rowptr, N2);
    // [passq | mfma_gelu]
    passq_gelu_kernel<<<NRANGES + mmBlocks, 256, 0, stream>>>(
        rstart, ebuf, cap, N2, sbits, rowptr, rowcnt, dinv, srcs,
        cb, ce_W2, ce_b2, fused, N, (int)mmBlocks);

    // ---- GCN layer 1: dual matmul (shared A) -> fused gather (both graphs) ----
    mm_l1_dual_kernel<<<mmBlocks, 256, 0, stream>>>(fused, g1_W, t1_W, dinv, ling, lint, N);
    gather_l1_kernel<<<nodeBlocks, 256, 0, stream>>>(rowptr, rowcnt, srcs, dinv,
                                                     ling, lint, g1_b, t1_b, h1g, h1t, N);
    // ---- GCN layer 2: split matmul -> fused gather + gated combine ----
    mm_l2_kernel<<<2 * mmBlocks, 256, 0, stream>>>(h1g, h1t, g2_W, t2_W, dinv,
                                                   ling, lint, N, (int)mmBlocks);
    gather_l2_kernel<<<nodeBlocks, 256, 0, stream>>>(rowptr, rowcnt, srcs, dinv,
                                                     ling, lint, g2_b, t2_b, alpha, hb, N);

    // ---- head (MFMA) ----
    head_mfma_kernel<<<mmBlocks, 256, 0, stream>>>(hb, fused, h_W1, h_b1, h_g, h_be,
                                                   h_W2, h_b2, out, N);
}

// Round 6
// 419.996 us; speedup vs baseline: 1.6818x; 1.1539x over previous
//
#include <hip/hip_runtime.h>
#include <math.h>

// UrbanModelV2: encoder MLPs -> 4x GCNConv (2 graphs) -> gated combine -> LN-MLP head.
// N=100000, CTX=128, TGT=32, H=64, FUS=96, E1=1.6M, E2=0.8M. fp32 in/out.
//
// R15: gathers restructured to 16-lane groups (4 nodes/wave). Lane l owns
//   features 4l..4l+3 (uint2 = 4 bf16 per edge, 128B/row coalesced per group).
//   4 edges/wave-slot, 16x 8B loads in flight, 32-bit addressing, ushort4
//   stores. (R14 profile: gathers 185us total, L3-latency+VALU bound at
//   1 node/wave - 92us each, VALUBusy 38%, FETCH 153MB all L3-resident.)

#define LN_EPS 1e-5f
#define NRANGES 512
#define RMASK 511
#define LSHIFT 9
#define PASSP_EDGES 8192
#define GSTRIDE 16            // gcur element stride (64B lines)

typedef __attribute__((ext_vector_type(8))) short short8;            // 8 bf16
typedef __attribute__((ext_vector_type(4))) float float4v;           // MFMA acc
typedef __attribute__((ext_vector_type(4))) unsigned short ushort4v; // 4 bf16

__device__ __forceinline__ float gelu_exact(float x) {
    return 0.5f * x * (1.0f + erff(x * 0.70710678118654752440f));
}

// reduce across the 16-lane quad-group (lane masks 1..8 stay within group)
__device__ __forceinline__ float qsum16(float v) {
#pragma unroll
    for (int m = 1; m < 16; m <<= 1)
        v += __shfl_xor(v, m, 64);
    return v;
}

__device__ __forceinline__ int load_edge(const void* ei, int is32, long idx) {
    return is32 ? ((const int*)ei)[idx] : (int)((const long long*)ei)[idx];
}

__device__ __forceinline__ unsigned short f32_to_bf16(float f) {
    unsigned int x = __float_as_uint(f);
    x += 0x7fffu + ((x >> 16) & 1u);   // RNE, finite values
    return (unsigned short)(x >> 16);
}
__device__ __forceinline__ float bf16_to_f32(unsigned short u) {
    return __uint_as_float((unsigned int)u << 16);
}
__device__ __forceinline__ float bflo(unsigned x) { return __uint_as_float(x << 16); }
__device__ __forceinline__ float bfhi(unsigned x) { return __uint_as_float(x & 0xffff0000u); }

// load dst-nodes (transit offset by n) for edges base..base+3; nv = #valid
__device__ __forceinline__ void load_dst4(const void* ei1, int e1, const void* ei2, int e2,
                                          int n, int is32, int base, int nv, int nd[4]) {
    if (is32 && nv == 4) {
        if (base + 3 < e1 && (((e1 + base) & 3) == 0)) {
            int4 v = *(const int4*)((const int*)ei1 + (size_t)e1 + base);
            nd[0] = v.x; nd[1] = v.y; nd[2] = v.z; nd[3] = v.w;
            return;
        }
        if (base >= e1 && (((e2 + base - e1) & 3) == 0)) {
            int4 v = *(const int4*)((const int*)ei2 + (size_t)e2 + (base - e1));
            nd[0] = v.x + n; nd[1] = v.y + n; nd[2] = v.z + n; nd[3] = v.w + n;
            return;
        }
    }
#pragma unroll
    for (int u = 0; u < 4; ++u) {
        int i = base + u;
        if (u >= nv) { nd[u] = -1; continue; }
        if (i < e1) nd[u] = load_edge(ei1, is32, (long)e1 + i);
        else        nd[u] = load_edge(ei2, is32, (long)e2 + (i - e1)) + n;
    }
}

// load src-nodes for edges base..base+3; nv = #valid
__device__ __forceinline__ void load_src4(const void* ei1, int e1, const void* ei2, int e2,
                                          int is32, int base, int nv, int ns[4]) {
    if (is32 && nv == 4) {
        if (base + 3 < e1 && ((base & 3) == 0)) {
            int4 v = *(const int4*)((const int*)ei1 + base);
            ns[0] = v.x; ns[1] = v.y; ns[2] = v.z; ns[3] = v.w;
            return;
        }
        if (base >= e1 && (((base - e1) & 3) == 0)) {
            int4 v = *(const int4*)((const int*)ei2 + (base - e1));
            ns[0] = v.x; ns[1] = v.y; ns[2] = v.z; ns[3] = v.w;
            return;
        }
    }
#pragma unroll
    for (int u = 0; u < 4; ++u) {
        int i = base + u;
        if (u >= nv) { ns[u] = 0; continue; }
        if (i < e1) ns[u] = load_edge(ei1, is32, i);
        else        ns[u] = load_edge(ei2, is32, (long)(i - e1));
    }
}

// ---------------- dtype detection + cursor init ----------------
__global__ __launch_bounds__(256) void detect_kernel(const unsigned char* __restrict__ mask_bytes,
                                                     const int* __restrict__ ei_words,
                                                     int* __restrict__ flags,
                                                     int* __restrict__ gcur, int cap) {
    if (blockIdx.x == 0) {
        __shared__ int f0, f1;
        if (threadIdx.x == 0) { f0 = 0; f1 = 0; }
        __syncthreads();
        int i = threadIdx.x;
        if ((i & 3) != 0 && mask_bytes[i] != 0) f0 = 1;
        if (i < 64 && ei_words[2 * i + 1] != 0) f1 = 1;
        __syncthreads();
        if (threadIdx.x == 0) { flags[0] = f0; flags[1] = f1; }
    } else {
        int r = (blockIdx.x - 1) * 256 + threadIdx.x;
        if (r < NRANGES) gcur[r * GSTRIDE] = r * cap;
    }
}

// ---------------- CSR stage 1 body: partition edges into range buckets ----------------
__device__ __forceinline__ void passp_body(
    const void* ei1, int e1, const void* ei2, int e2,
    int n, const int* flags, int* gcur, int cap, unsigned* ebuf, int sbits, int bid)
{
    __shared__ int hist[NRANGES];
    __shared__ int base[NRANGES];
    const int E = e1 + e2;
    const int is32 = flags[1];
    const int b0 = bid * PASSP_EDGES;
    const int bend = (b0 + PASSP_EDGES < E) ? b0 + PASSP_EDGES : E;

    for (int k = threadIdx.x; k < NRANGES; k += 256) hist[k] = 0;
    __syncthreads();

    // pass 1: histogram; the atomic return IS the local rank (kept in regs)
    int nd[32], rk[32];
#pragma unroll
    for (int j = 0; j < 8; ++j) {
        int bi = b0 + j * 1024 + (int)threadIdx.x * 4;
        int nv = bend - bi; nv = (nv < 0) ? 0 : (nv > 4 ? 4 : nv);
        load_dst4(ei1, e1, ei2, e2, n, is32, bi, nv, &nd[j * 4]);
#pragma unroll
        for (int u = 0; u < 4; ++u)
            if (u < nv) rk[j * 4 + u] = atomicAdd(&hist[nd[j * 4 + u] & RMASK], 1);
    }
    __syncthreads();

    // allocate: one device atomic per nonempty (block,range); gcur strided 64B
    for (int r = threadIdx.x; r < NRANGES; r += 256) {
        int c = hist[r];
        base[r] = c ? atomicAdd(&gcur[r * GSTRIDE], c) : 0;
    }
    __syncthreads();

    // pass 2: pure 4B packed scatter, no LDS ops
#pragma unroll
    for (int j = 0; j < 8; ++j) {
        int bi = b0 + j * 1024 + (int)threadIdx.x * 4;
        int nv = bend - bi; nv = (nv < 0) ? 0 : (nv > 4 ? 4 : nv);
        int sv[4];
        load_src4(ei1, e1, ei2, e2, is32, bi, nv, sv);
#pragma unroll
        for (int u = 0; u < 4; ++u) {
            if (u < nv) {
                int d = nd[j * 4 + u];
                int r = d & RMASK;
                int pos = base[r] + rk[j * 4 + u];
                if (pos < (r + 1) * cap)   // capacity guard (memory safety)
                    ebuf[pos] = (unsigned)sv[u] | ((unsigned)(d >> LSHIFT) << sbits);
            }
        }
    }
}

// ---------------- prep body: ctx->bf16 + masked-target encoder -> fused[:,64:96] ----------------
__device__ __forceinline__ void prep_body(
    const float* context, const float* target, const void* mask, const int* flags,
    const float* mask_token, const float* te_W, const float* te_b,
    unsigned short* ctxb, unsigned short* fused, int n, int bid)
{
    __shared__ float tbuf[32][32];
    int w = threadIdx.x >> 6;
    int j = threadIdx.x & 63;
    int r0 = __builtin_amdgcn_readfirstlane(bid * 32 + w * 8);
    if (r0 >= n) return;  // N % 32 == 0

    const float4* src = (const float4*)(context + (size_t)r0 * 128);
    ushort4v* dst = (ushort4v*)(ctxb + (size_t)r0 * 128);
#pragma unroll
    for (int p = 0; p < 4; ++p) {
        float4 v = src[p * 64 + j];
        ushort4v o;
        o.x = f32_to_bf16(v.x); o.y = f32_to_bf16(v.y);
        o.z = f32_to_bf16(v.z); o.w = f32_to_bf16(v.w);
        dst[p * 64 + j] = o;
    }

    int tr = j >> 5;
    int tj = j & 31;
#pragma unroll
    for (int rr = 0; rr < 4; ++rr) {
        int r = tr + rr * 2;
        long mi = (long)(r0 + r) * 32 + tj;
        int mraw = flags[0] ? (int)((const unsigned char*)mask)[mi]
                            : ((const int*)mask)[mi];
        float m = mraw ? 1.0f : 0.0f;
        tbuf[w * 8 + r][tj] = target[mi] * (1.0f - m) + mask_token[tj] * m;
    }

#pragma unroll
    for (int rr = 0; rr < 4; ++rr) {
        int r = tr + rr * 2;
        float y3 = te_b[tj];
#pragma unroll
        for (int k = 0; k < 32; ++k)
            y3 = fmaf(tbuf[w * 8 + r][k], te_W[k * 32 + tj], y3);
        fused[(long)(r0 + r) * 96 + 64 + tj] = f32_to_bf16(gelu_exact(y3));
    }
}

// ---------------- fused kernel A: passp | prep ----------------
__global__ __launch_bounds__(256) void passp_prep_kernel(
    const void* __restrict__ ei1, int e1, const void* __restrict__ ei2, int e2,
    int n, const int* __restrict__ flags, int* __restrict__ gcur, int cap,
    unsigned* __restrict__ ebuf, int sbits, int ppBlocks,
    const float* __restrict__ context, const float* __restrict__ target,
    const void* __restrict__ mask, const float* __restrict__ mask_token,
    const float* __restrict__ te_W, const float* __restrict__ te_b,
    unsigned short* __restrict__ ctxb, unsigned short* __restrict__ fused)
{
    if ((int)blockIdx.x < ppBlocks)
        passp_body(ei1, e1, ei2, e2, n, flags, gcur, cap, ebuf, sbits, blockIdx.x);
    else
        prep_body(context, target, mask, flags, mask_token, te_W, te_b,
                  ctxb, fused, n, blockIdx.x - ppBlocks);
}

// ---------------- CSR stage 2 body: prefix over 512 range totals (256 thr) ----------------
__device__ __forceinline__ void rscan_body(const int* gcur, int cap,
                                           int* rstart, int* rowptr, int n2) {
    __shared__ int ws[256];
    int t = threadIdx.x;
    int i0 = 2 * t, i1 = 2 * t + 1;
    int a0 = gcur[i0 * GSTRIDE] - i0 * cap;
    int a1 = gcur[i1 * GSTRIDE] - i1 * cap;
    ws[t] = a0 + a1;
    __syncthreads();
    for (int off = 1; off < 256; off <<= 1) {
        int v = (t >= off) ? ws[t - off] : 0;
        __syncthreads();
        if (t >= off) ws[t] += v;
        __syncthreads();
    }
    int ex = t ? ws[t - 1] : 0;
    rstart[i0] = ex;
    rstart[i1] = ex + a0;
    if (t == 255) { rstart[NRANGES] = ws[255]; rowptr[n2] = ws[255]; }
}

// ---------------- MFMA encoder layer 1 body: LN+GELU epilogue ----------------
__device__ __forceinline__ void mfma_ln_body(
    const unsigned short* x, const float* W, const float* bias, const float* g,
    const float* beta, unsigned short* y, int n, int bid, int nblk)
{
    constexpr int K = 128, KS = K / 32, STRIDE = K + 8;
    __shared__ __align__(16) unsigned short wt[64 * STRIDE];
    int n0 = threadIdx.x & 63;
    int kk = threadIdx.x >> 6;
    for (int k = kk; k < K; k += 4)
        wt[n0 * STRIDE + k] = f32_to_bf16(W[k * 64 + n0]);
    __syncthreads();

    int w = threadIdx.x >> 6;
    int lane = threadIdx.x & 63;
    int c = lane & 15;
    int q = lane >> 4;

    short8 bfrag[KS][4];
#pragma unroll
    for (int s = 0; s < KS; ++s)
#pragma unroll
        for (int nt = 0; nt < 4; ++nt)
            bfrag[s][nt] = *(const short8*)&wt[(nt * 16 + c) * STRIDE + s * 32 + q * 8];

    float bs[4], gs[4], be[4];
#pragma unroll
    for (int nt = 0; nt < 4; ++nt) {
        bs[nt] = bias[nt * 16 + c];
        gs[nt] = g[nt * 16 + c];
        be[nt] = beta[nt * 16 + c];
    }

    int T = n >> 4;
    int stride = nblk * 4;
    for (int t = __builtin_amdgcn_readfirstlane(bid * 4 + w); t < T; t += stride) {
        int r0 = t << 4;
        const unsigned short* xa = x + (size_t)(r0 + c) * K + q * 8;
        float4v acc[4] = {{0,0,0,0},{0,0,0,0},{0,0,0,0},{0,0,0,0}};
#pragma unroll
        for (int s = 0; s < KS; ++s) {
            short8 a = *(const short8*)(xa + s * 32);
#pragma unroll
            for (int nt = 0; nt < 4; ++nt)
                acc[nt] = __builtin_amdgcn_mfma_f32_16x16x32_bf16(a, bfrag[s][nt], acc[nt], 0, 0, 0);
        }
#pragma unroll
        for (int reg = 0; reg < 4; ++reg) {
            float v0 = acc[0][reg] + bs[0];
            float v1 = acc[1][reg] + bs[1];
            float v2 = acc[2][reg] + bs[2];
            float v3 = acc[3][reg] + bs[3];
            float mean = qsum16((v0 + v1) + (v2 + v3)) * (1.0f / 64.0f);
            float x0 = v0 - mean, x1 = v1 - mean, x2 = v2 - mean, x3 = v3 - mean;
            float var = qsum16((x0 * x0 + x1 * x1) + (x2 * x2 + x3 * x3)) * (1.0f / 64.0f);
            float rstd = rsqrtf(var + LN_EPS);
            size_t row = (size_t)(r0 + q * 4 + reg) * 64;
            y[row + 0 * 16 + c] = f32_to_bf16(gelu_exact(x0 * rstd * gs[0] + be[0]));
            y[row + 1 * 16 + c] = f32_to_bf16(gelu_exact(x1 * rstd * gs[1] + be[1]));
            y[row + 2 * 16 + c] = f32_to_bf16(gelu_exact(x2 * rstd * gs[2] + be[2]));
            y[row + 3 * 16 + c] = f32_to_bf16(gelu_exact(x3 * rstd * gs[3] + be[3]));
        }
    }
}

// ---------------- fused kernel B: mfma_ln | rscan ----------------
__global__ __launch_bounds__(256) void ln_rscan_kernel(
    const unsigned short* __restrict__ x, const float* __restrict__ W,
    const float* __restrict__ bias, const float* __restrict__ g,
    const float* __restrict__ beta, unsigned short* __restrict__ y, int n, int nblk,
    const int* __restrict__ gcur, int cap, int* __restrict__ rstart,
    int* __restrict__ rowptr, int n2)
{
    if ((int)blockIdx.x == nblk)
        rscan_body(gcur, cap, rstart, rowptr, n2);
    else
        mfma_ln_body(x, W, bias, g, beta, y, n, blockIdx.x, nblk);
}

// ---------------- CSR stage 3 body: per-range CSR build ----------------
// range g owns nodes {d : (d & 511) == g}, local id l = d >> 9.
__device__ __forceinline__ void passq_body(
    const int* rstart, const unsigned* ebuf, int cap, int n2, int sbits,
    int* rowptr, int* rowcnt, float* dinv, int* srcs, int g)
{
    __shared__ int deg[NRANGES];
    __shared__ int cur[NRANGES];
    __shared__ int ws[256];
    const int t = threadIdx.x;
    const int gbase = rstart[g];
    const int total = rstart[g + 1] - gbase;
    const unsigned* eb = ebuf + (size_t)g * cap;
    const unsigned smask = (1u << sbits) - 1u;

    deg[2 * t] = 0; deg[2 * t + 1] = 0;
    __syncthreads();
    for (int i = t; i < total; i += 256)
        atomicAdd(&deg[eb[i] >> sbits], 1);
    __syncthreads();

    int a0 = deg[2 * t], a1 = deg[2 * t + 1];
    ws[t] = a0 + a1;
    __syncthreads();
    for (int off = 1; off < 256; off <<= 1) {
        int v = (t >= off) ? ws[t - off] : 0;
        __syncthreads();
        if (t >= off) ws[t] += v;
        __syncthreads();
    }
    int ex = t ? ws[t - 1] : 0;
    cur[2 * t] = ex;
    cur[2 * t + 1] = ex + a0;
    int node0 = ((2 * t) << LSHIFT) | g;
    int node1 = ((2 * t + 1) << LSHIFT) | g;
    if (node0 < n2) { rowptr[node0] = gbase + ex;      rowcnt[node0] = a0; dinv[node0] = rsqrtf((float)a0 + 1.0f); }
    if (node1 < n2) { rowptr[node1] = gbase + ex + a0; rowcnt[node1] = a1; dinv[node1] = rsqrtf((float)a1 + 1.0f); }
    __syncthreads();

    for (int i = t; i < total; i += 256) {
        unsigned e = eb[i];
        int rk = atomicAdd(&cur[e >> sbits], 1);
        srcs[gbase + rk] = (int)(e & smask);
    }
}

// ---------------- MFMA encoder layer 2 body: GELU epilogue, out stride 96 ----------------
__device__ __forceinline__ void mfma_gelu_body(
    const unsigned short* x, const float* W, const float* bias,
    unsigned short* y, int n, int bid, int nblk)
{
    constexpr int K = 64, KS = K / 32, STRIDE = K + 8;
    __shared__ __align__(16) unsigned short wt[64 * STRIDE];
    int n0 = threadIdx.x & 63;
    int kk = threadIdx.x >> 6;
    for (int k = kk; k < K; k += 4)
        wt[n0 * STRIDE + k] = f32_to_bf16(W[k * 64 + n0]);
    __syncthreads();

    int w = threadIdx.x >> 6;
    int lane = threadIdx.x & 63;
    int c = lane & 15;
    int q = lane >> 4;

    short8 bfrag[KS][4];
#pragma unroll
    for (int s = 0; s < KS; ++s)
#pragma unroll
        for (int nt = 0; nt < 4; ++nt)
            bfrag[s][nt] = *(const short8*)&wt[(nt * 16 + c) * STRIDE + s * 32 + q * 8];

    float bs[4];
#pragma unroll
    for (int nt = 0; nt < 4; ++nt) bs[nt] = bias[nt * 16 + c];

    int T = n >> 4;
    int stride = nblk * 4;
    for (int t = __builtin_amdgcn_readfirstlane(bid * 4 + w); t < T; t += stride) {
        int r0 = t << 4;
        const unsigned short* xa = x + (size_t)(r0 + c) * K + q * 8;
        float4v acc[4] = {{0,0,0,0},{0,0,0,0},{0,0,0,0},{0,0,0,0}};
#pragma unroll
        for (int s = 0; s < KS; ++s) {
            short8 a = *(const short8*)(xa + s * 32);
#pragma unroll
            for (int nt = 0; nt < 4; ++nt)
                acc[nt] = __builtin_amdgcn_mfma_f32_16x16x32_bf16(a, bfrag[s][nt], acc[nt], 0, 0, 0);
        }
#pragma unroll
        for (int nt = 0; nt < 4; ++nt)
#pragma unroll
            for (int reg = 0; reg < 4; ++reg)
                y[(size_t)(r0 + q * 4 + reg) * 96 + nt * 16 + c] =
                    f32_to_bf16(gelu_exact(acc[nt][reg] + bs[nt]));
    }
}

// ---------------- fused kernel C: passq | mfma_gelu ----------------
__global__ __launch_bounds__(256) void passq_gelu_kernel(
    const int* __restrict__ rstart, const unsigned* __restrict__ ebuf, int cap, int n2,
    int sbits, int* __restrict__ rowptr, int* __restrict__ rowcnt,
    float* __restrict__ dinv, int* __restrict__ srcs,
    const unsigned short* __restrict__ x, const float* __restrict__ W,
    const float* __restrict__ bias, unsigned short* __restrict__ y, int n, int nblk)
{
    if ((int)blockIdx.x < NRANGES)
        passq_body(rstart, ebuf, cap, n2, sbits, rowptr, rowcnt, dinv, srcs, blockIdx.x);
    else
        mfma_gelu_body(x, W, bias, y, n, blockIdx.x - NRANGES, nblk);
}

// ---------------- MFMA GCN matmul layer1 (dual-weight, shared A): ----------------
// yg = (x @ Wg) * dinv[row], yt = (x @ Wt) * dinv[n+row]
__global__ __launch_bounds__(256) void mm_l1_dual_kernel(
    const unsigned short* __restrict__ x, const float* __restrict__ Wg,
    const float* __restrict__ Wt, const float* __restrict__ dinv,
    unsigned short* __restrict__ yg, unsigned short* __restrict__ yt, int n)
{
    constexpr int K = 96, KS = K / 32, STRIDE = K + 8;
    __shared__ __align__(16) unsigned short wtg[64 * STRIDE];
    __shared__ __align__(16) unsigned short wtt[64 * STRIDE];
    int n0 = threadIdx.x & 63;
    int kk = threadIdx.x >> 6;
    for (int k = kk; k < K; k += 4) {
        wtg[n0 * STRIDE + k] = f32_to_bf16(Wg[k * 64 + n0]);
        wtt[n0 * STRIDE + k] = f32_to_bf16(Wt[k * 64 + n0]);
    }
    __syncthreads();

    int w = threadIdx.x >> 6;
    int lane = threadIdx.x & 63;
    int c = lane & 15;
    int q = lane >> 4;

    short8 bg[KS][4], bt[KS][4];
#pragma unroll
    for (int s = 0; s < KS; ++s)
#pragma unroll
        for (int nt = 0; nt < 4; ++nt) {
            bg[s][nt] = *(const short8*)&wtg[(nt * 16 + c) * STRIDE + s * 32 + q * 8];
            bt[s][nt] = *(const short8*)&wtt[(nt * 16 + c) * STRIDE + s * 32 + q * 8];
        }

    int T = n >> 4;
    int stride = gridDim.x * 4;
    for (int t = __builtin_amdgcn_readfirstlane(blockIdx.x * 4 + w); t < T; t += stride) {
        int r0 = t << 4;
        const unsigned short* xa = x + (size_t)(r0 + c) * K + q * 8;
        float4v ag[4] = {{0,0,0,0},{0,0,0,0},{0,0,0,0},{0,0,0,0}};
        float4v at[4] = {{0,0,0,0},{0,0,0,0},{0,0,0,0},{0,0,0,0}};
#pragma unroll
        for (int s = 0; s < KS; ++s) {
            short8 a = *(const short8*)(xa + s * 32);
#pragma unroll
            for (int nt = 0; nt < 4; ++nt) {
                ag[nt] = __builtin_amdgcn_mfma_f32_16x16x32_bf16(a, bg[s][nt], ag[nt], 0, 0, 0);
                at[nt] = __builtin_amdgcn_mfma_f32_16x16x32_bf16(a, bt[s][nt], at[nt], 0, 0, 0);
            }
        }
        float sg[4], st[4];
#pragma unroll
        for (int reg = 0; reg < 4; ++reg) {
            sg[reg] = dinv[r0 + q * 4 + reg];
            st[reg] = dinv[n + r0 + q * 4 + reg];
        }
#pragma unroll
        for (int nt = 0; nt < 4; ++nt)
#pragma unroll
            for (int reg = 0; reg < 4; ++reg) {
                size_t row = (size_t)(r0 + q * 4 + reg) * 64 + nt * 16 + c;
                yg[row] = f32_to_bf16(ag[nt][reg] * sg[reg]);
                yt[row] = f32_to_bf16(at[nt][reg] * st[reg]);
            }
    }
}

// ---------------- MFMA GCN matmul body (single), K=64 ----------------
__device__ __forceinline__ void mm64_body(const unsigned short* x, const float* W,
                                          const float* scale, unsigned short* y,
                                          int n, int bid, int nblk) {
    constexpr int K = 64, KS = K / 32, STRIDE = K + 8;
    __shared__ __align__(16) unsigned short wt[64 * STRIDE];
    int n0 = threadIdx.x & 63;
    int kk = threadIdx.x >> 6;
    for (int k = kk; k < K; k += 4)
        wt[n0 * STRIDE + k] = f32_to_bf16(W[k * 64 + n0]);
    __syncthreads();

    int w = threadIdx.x >> 6;
    int lane = threadIdx.x & 63;
    int c = lane & 15;
    int q = lane >> 4;

    short8 bfrag[KS][4];
#pragma unroll
    for (int s = 0; s < KS; ++s)
#pragma unroll
        for (int nt = 0; nt < 4; ++nt)
            bfrag[s][nt] = *(const short8*)&wt[(nt * 16 + c) * STRIDE + s * 32 + q * 8];

    int T = n >> 4;
    int stride = nblk * 4;
    for (int t = __builtin_amdgcn_readfirstlane(bid * 4 + w); t < T; t += stride) {
        int r0 = t << 4;
        const unsigned short* xa = x + (size_t)(r0 + c) * K + q * 8;
        float4v acc[4] = {{0,0,0,0},{0,0,0,0},{0,0,0,0},{0,0,0,0}};
#pragma unroll
        for (int s = 0; s < KS; ++s) {
            short8 a = *(const short8*)(xa + s * 32);
#pragma unroll
            for (int nt = 0; nt < 4; ++nt)
                acc[nt] = __builtin_amdgcn_mfma_f32_16x16x32_bf16(a, bfrag[s][nt], acc[nt], 0, 0, 0);
        }
        float sc[4];
#pragma unroll
        for (int reg = 0; reg < 4; ++reg)
            sc[reg] = scale[r0 + q * 4 + reg];
#pragma unroll
        for (int nt = 0; nt < 4; ++nt)
#pragma unroll
            for (int reg = 0; reg < 4; ++reg)
                y[(size_t)(r0 + q * 4 + reg) * 64 + nt * 16 + c] = f32_to_bf16(acc[nt][reg] * sc[reg]);
    }
}

// ---------------- layer2 matmuls, block-split ----------------
__global__ __launch_bounds__(256) void mm_l2_kernel(
    const unsigned short* __restrict__ xg, const unsigned short* __restrict__ xt,
    const float* __restrict__ Wg, const float* __restrict__ Wt,
    const float* __restrict__ dinv,
    unsigned short* __restrict__ yg, unsigned short* __restrict__ yt, int n, int nblk)
{
    if ((int)blockIdx.x < nblk)
        mm64_body(xg, Wg, dinv, yg, n, blockIdx.x, nblk);
    else
        mm64_body(xt, Wt, dinv + n, yt, n, blockIdx.x - nblk, nblk);
}

// ---------------- 16-lane-group gather: lane l owns features 4l..4l+3 ----------------
__device__ __forceinline__ void gather4(const int* __restrict__ srcs,
                                        const unsigned short* __restrict__ lin,
                                        int beg, int cnt, int l, float acc[4]) {
    for (int base = 0; base < cnt; base += 16) {
        int c2 = cnt - base;
        if (c2 > 16) c2 = 16;
        int sj = (l < c2) ? srcs[beg + base + l] : 0;
        int t = 0;
        for (; t + 4 <= c2; t += 4) {
            uint2 v[4];
#pragma unroll
            for (int u = 0; u < 4; ++u) {
                int s = __shfl(sj, t + u, 16);
                v[u] = *(const uint2*)(lin + (size_t)((unsigned)s * 64u + (unsigned)(l * 4)));
            }
#pragma unroll
            for (int u = 0; u < 4; ++u) {
                acc[0] += bflo(v[u].x); acc[1] += bfhi(v[u].x);
                acc[2] += bflo(v[u].y); acc[3] += bfhi(v[u].y);
            }
        }
        for (; t < c2; ++t) {
            int s = __shfl(sj, t, 16);
            uint2 vv = *(const uint2*)(lin + (size_t)((unsigned)s * 64u + (unsigned)(l * 4)));
            acc[0] += bflo(vv.x); acc[1] += bfhi(vv.x);
            acc[2] += bflo(vv.y); acc[3] += bfhi(vv.y);
        }
    }
}

// layer 1: h1g = gelu(gcn_pre(adj, ling, bg)); h1t = gelu(gcn_pre(tr, lint, bt))
// 4 nodes per wave (16 lanes each).
__global__ __launch_bounds__(256) void gather_l1_kernel(
    const int* __restrict__ rowptr, const int* __restrict__ rowcnt,
    const int* __restrict__ srcs, const float* __restrict__ dinv,
    const unsigned short* __restrict__ ling, const unsigned short* __restrict__ lint,
    const float* __restrict__ bg, const float* __restrict__ bt,
    unsigned short* __restrict__ h1g, unsigned short* __restrict__ h1t, int n)
{
    int w = threadIdx.x >> 6;
    int lane = threadIdx.x & 63;
    int g = lane >> 4;
    int l = lane & 15;
    int node = blockIdx.x * 16 + w * 4 + g;
    if (node >= n) return;

    float4 b4g = ((const float4*)bg)[l];
    float4 b4t = ((const float4*)bt)[l];
    unsigned off = (unsigned)node * 64u + (unsigned)(l * 4);

    {   // adj graph
        float acc[4] = {0, 0, 0, 0};
        gather4(srcs, ling, rowptr[node], rowcnt[node], l, acc);
        uint2 sv = *(const uint2*)(ling + off);
        acc[0] += bflo(sv.x); acc[1] += bfhi(sv.x);
        acc[2] += bflo(sv.y); acc[3] += bfhi(sv.y);
        float dd = dinv[node];
        ushort4v o;
        o.x = f32_to_bf16(gelu_exact(fmaf(dd, acc[0], b4g.x)));
        o.y = f32_to_bf16(gelu_exact(fmaf(dd, acc[1], b4g.y)));
        o.z = f32_to_bf16(gelu_exact(fmaf(dd, acc[2], b4g.z)));
        o.w = f32_to_bf16(gelu_exact(fmaf(dd, acc[3], b4g.w)));
        *(ushort4v*)(h1g + off) = o;
    }
    {   // transit graph
        int tn = n + node;
        float acc[4] = {0, 0, 0, 0};
        gather4(srcs, lint, rowptr[tn], rowcnt[tn], l, acc);
        uint2 sv = *(const uint2*)(lint + off);
        acc[0] += bflo(sv.x); acc[1] += bfhi(sv.x);
        acc[2] += bflo(sv.y); acc[3] += bfhi(sv.y);
        float dd = dinv[tn];
        ushort4v o;
        o.x = f32_to_bf16(gelu_exact(fmaf(dd, acc[0], b4t.x)));
        o.y = f32_to_bf16(gelu_exact(fmaf(dd, acc[1], b4t.y)));
        o.z = f32_to_bf16(gelu_exact(fmaf(dd, acc[2], b4t.z)));
        o.w = f32_to_bf16(gelu_exact(fmaf(dd, acc[3], b4t.w)));
        *(ushort4v*)(h1t + off) = o;
    }
}

// layer 2: hb = bf16( a*gcn_pre(adj, ling, bg) + (1-a)*gcn_pre(tr, lint, bt) )
__global__ __launch_bounds__(256) void gather_l2_kernel(
    const int* __restrict__ rowptr, const int* __restrict__ rowcnt,
    const int* __restrict__ srcs, const float* __restrict__ dinv,
    const unsigned short* __restrict__ ling, const unsigned short* __restrict__ lint,
    const float* __restrict__ bg, const float* __restrict__ bt,
    const float* __restrict__ alpha_ptr, unsigned short* __restrict__ hb, int n)
{
    int w = threadIdx.x >> 6;
    int lane = threadIdx.x & 63;
    int g = lane >> 4;
    int l = lane & 15;
    int node = blockIdx.x * 16 + w * 4 + g;
    if (node >= n) return;

    float4 b4g = ((const float4*)bg)[l];
    float4 b4t = ((const float4*)bt)[l];
    unsigned off = (unsigned)node * 64u + (unsigned)(l * 4);

    float pg[4], pt[4];
    {
        float acc[4] = {0, 0, 0, 0};
        gather4(srcs, ling, rowptr[node], rowcnt[node], l, acc);
        uint2 sv = *(const uint2*)(ling + off);
        acc[0] += bflo(sv.x); acc[1] += bfhi(sv.x);
        acc[2] += bflo(sv.y); acc[3] += bfhi(sv.y);
        float dd = dinv[node];
        pg[0] = fmaf(dd, acc[0], b4g.x); pg[1] = fmaf(dd, acc[1], b4g.y);
        pg[2] = fmaf(dd, acc[2], b4g.z); pg[3] = fmaf(dd, acc[3], b4g.w);
    }
    {
        int tn = n + node;
        float acc[4] = {0, 0, 0, 0};
        gather4(srcs, lint, rowptr[tn], rowcnt[tn], l, acc);
        uint2 sv = *(const uint2*)(lint + off);
        acc[0] += bflo(sv.x); acc[1] += bfhi(sv.x);
        acc[2] += bflo(sv.y); acc[3] += bfhi(sv.y);
        float dd = dinv[tn];
        pt[0] = fmaf(dd, acc[0], b4t.x); pt[1] = fmaf(dd, acc[1], b4t.y);
        pt[2] = fmaf(dd, acc[2], b4t.z); pt[3] = fmaf(dd, acc[3], b4t.w);
    }
    float a = 1.0f / (1.0f + expf(-alpha_ptr[0]));
    float b = 1.0f - a;
    ushort4v o;
    o.x = f32_to_bf16(a * pg[0] + b * pt[0]);
    o.y = f32_to_bf16(a * pg[1] + b * pt[1]);
    o.z = f32_to_bf16(a * pg[2] + b * pt[2]);
    o.w = f32_to_bf16(a * pg[3] + b * pt[3]);
    *(ushort4v*)(hb + off) = o;
}

// ---------------- MFMA head: [hb|fused] @ W1 -> LN -> gelu -> @ W2 + b2 ----------------
__global__ __launch_bounds__(256) void head_mfma_kernel(
    const unsigned short* __restrict__ hb, const unsigned short* __restrict__ fused,
    const float* __restrict__ h_W1, const float* __restrict__ h_b1,
    const float* __restrict__ h_g, const float* __restrict__ h_beta,
    const float* __restrict__ h_W2, const float* __restrict__ h_b2,
    float* __restrict__ out, int n)
{
    constexpr int ST1 = 168;  // 160 + 8
    constexpr int ST2 = 72;   // 64 + 8
    __shared__ __align__(16) unsigned short wt1[64 * ST1];     // 21504 B
    __shared__ __align__(16) unsigned short wt2[32 * ST2];     // 4608 B
    __shared__ __align__(16) unsigned short zl[4][16 * ST2];   // 9216 B

    int n0 = threadIdx.x & 63;
    int kk = threadIdx.x >> 6;
    for (int k = kk; k < 160; k += 4)
        wt1[n0 * ST1 + k] = f32_to_bf16(h_W1[k * 64 + n0]);
    if (n0 < 32)
        for (int k = kk; k < 64; k += 4)
            wt2[n0 * ST2 + k] = f32_to_bf16(h_W2[k * 32 + n0]);
    __syncthreads();

    int w = threadIdx.x >> 6;
    int lane = threadIdx.x & 63;
    int c = lane & 15;
    int q = lane >> 4;

    short8 b1f[5][4];
#pragma unroll
    for (int s = 0; s < 5; ++s)
#pragma unroll
        for (int nt = 0; nt < 4; ++nt)
            b1f[s][nt] = *(const short8*)&wt1[(nt * 16 + c) * ST1 + s * 32 + q * 8];
    short8 b2f[2][2];
#pragma unroll
    for (int s = 0; s < 2; ++s)
#pragma unroll
        for (int nt = 0; nt < 2; ++nt)
            b2f[s][nt] = *(const short8*)&wt2[(nt * 16 + c) * ST2 + s * 32 + q * 8];

    float bs[4], gs[4], be[4];
#pragma unroll
    for (int nt = 0; nt < 4; ++nt) {
        bs[nt] = h_b1[nt * 16 + c];
        gs[nt] = h_g[nt * 16 + c];
        be[nt] = h_beta[nt * 16 + c];
    }
    float b2s[2];
#pragma unroll
    for (int nt = 0; nt < 2; ++nt) b2s[nt] = h_b2[nt * 16 + c];

    unsigned short* zw = zl[w];
    int T = n >> 4;
    int stride = gridDim.x * 4;
    for (int t = __builtin_amdgcn_readfirstlane(blockIdx.x * 4 + w); t < T; t += stride) {
        int r0 = t << 4;
        // stage 1: K=160 (hb: k 0..63, fused: k 64..159)
        const unsigned short* xh = hb + (size_t)(r0 + c) * 64 + q * 8;
        const unsigned short* xf = fused + (size_t)(r0 + c) * 96 + q * 8;
        float4v acc[4] = {{0,0,0,0},{0,0,0,0},{0,0,0,0},{0,0,0,0}};
#pragma unroll
        for (int s = 0; s < 2; ++s) {
            short8 a = *(const short8*)(xh + s * 32);
#pragma unroll
            for (int nt = 0; nt < 4; ++nt)
                acc[nt] = __builtin_amdgcn_mfma_f32_16x16x32_bf16(a, b1f[s][nt], acc[nt], 0, 0, 0);
        }
#pragma unroll
        for (int s = 0; s < 3; ++s) {
            short8 a = *(const short8*)(xf + s * 32);
#pragma unroll
            for (int nt = 0; nt < 4; ++nt)
                acc[nt] = __builtin_amdgcn_mfma_f32_16x16x32_bf16(a, b1f[2 + s][nt], acc[nt], 0, 0, 0);
        }
        // epilogue: +b1, LN per row (q*4+reg), gelu -> zl (wave-private)
#pragma unroll
        for (int reg = 0; reg < 4; ++reg) {
            float v0 = acc[0][reg] + bs[0];
            float v1 = acc[1][reg] + bs[1];
            float v2 = acc[2][reg] + bs[2];
            float v3 = acc[3][reg] + bs[3];
            float mean = qsum16((v0 + v1) + (v2 + v3)) * (1.0f / 64.0f);
            float x0 = v0 - mean, x1 = v1 - mean, x2 = v2 - mean, x3 = v3 - mean;
            float var = qsum16((x0 * x0 + x1 * x1) + (x2 * x2 + x3 * x3)) * (1.0f / 64.0f);
            float rstd = rsqrtf(var + LN_EPS);
            int row = q * 4 + reg;
            zw[row * ST2 + 0 * 16 + c] = f32_to_bf16(gelu_exact(x0 * rstd * gs[0] + be[0]));
            zw[row * ST2 + 1 * 16 + c] = f32_to_bf16(gelu_exact(x1 * rstd * gs[1] + be[1]));
            zw[row * ST2 + 2 * 16 + c] = f32_to_bf16(gelu_exact(x2 * rstd * gs[2] + be[2]));
            zw[row * ST2 + 3 * 16 + c] = f32_to_bf16(gelu_exact(x3 * rstd * gs[3] + be[3]));
        }
        // stage 2: z (16x64) @ W2 (64x32); same-wave LDS write->read, no barrier
        float4v acc2[2] = {{0,0,0,0},{0,0,0,0}};
#pragma unroll
        for (int s = 0; s < 2; ++s) {
            short8 a2 = *(const short8*)&zw[c * ST2 + s * 32 + q * 8];
#pragma unroll
            for (int nt = 0; nt < 2; ++nt)
                acc2[nt] = __builtin_amdgcn_mfma_f32_16x16x32_bf16(a2, b2f[s][nt], acc2[nt], 0, 0, 0);
        }
#pragma unroll
        for (int nt = 0; nt < 2; ++nt)
#pragma unroll
            for (int reg = 0; reg < 4; ++reg)
                out[(size_t)(r0 + q * 4 + reg) * 32 + nt * 16 + c] = acc2[nt][reg] + b2s[nt];
    }
}

extern "C" void kernel_launch(void* const* d_in, const int* in_sizes, int n_in,
                              void* d_out, int out_size, void* d_ws, size_t ws_size,
                              hipStream_t stream) {
    const float* context    = (const float*)d_in[0];
    const float* target     = (const float*)d_in[1];
    const void*  mask       = d_in[2];
    const void*  adj_ei     = d_in[3];
    const void*  tr_ei      = d_in[4];
    const float* mask_token = (const float*)d_in[5];
    const float* ce_W1 = (const float*)d_in[6];
    const float* ce_b1 = (const float*)d_in[7];
    const float* ce_g  = (const float*)d_in[8];
    const float* ce_be = (const float*)d_in[9];
    const float* ce_W2 = (const float*)d_in[10];
    const float* ce_b2 = (const float*)d_in[11];
    const float* te_W  = (const float*)d_in[12];
    const float* te_b  = (const float*)d_in[13];
    const float* g1_W  = (const float*)d_in[14];
    const float* g1_b  = (const float*)d_in[15];
    const float* g2_W  = (const float*)d_in[16];
    const float* g2_b  = (const float*)d_in[17];
    const float* t1_W  = (const float*)d_in[18];
    const float* t1_b  = (const float*)d_in[19];
    const float* t2_W  = (const float*)d_in[20];
    const float* t2_b  = (const float*)d_in[21];
    const float* alpha = (const float*)d_in[22];
    const float* h_W1  = (const float*)d_in[23];
    const float* h_b1  = (const float*)d_in[24];
    const float* h_g   = (const float*)d_in[25];
    const float* h_be  = (const float*)d_in[26];
    const float* h_W2  = (const float*)d_in[27];
    const float* h_b2  = (const float*)d_in[28];

    const int N  = in_sizes[0] / 128;
    const int E1 = in_sizes[3] / 2;
    const int E2 = in_sizes[4] / 2;
    const int E  = E1 + E2;
    const int N2 = 2 * N;

    // src-id bit width for u32 edge packing (src < N)
    int sbits = 1;
    while ((1 << sbits) < N) ++sbits;

    // per-range bucket capacity (range = node & 511 -> uniform load)
    long expct = (E + NRANGES - 1) / NRANGES;
    int cap = (int)((expct * 4 / 3) & ~255L);
    long avail = (long)N * 128;                       // ebuf alias bytes (hacc[0 : N*128])
    int capmax = (int)((avail / ((long)NRANGES * 4)) & ~255L);
    if (cap > capmax) cap = capmax;
    if (cap < 1024) cap = 1024;

    // ---- workspace layout ----
    char* p = (char*)d_ws;
    int*   flags  = (int*)p;                    p += 256;
    unsigned short* ctxb  = (unsigned short*)p; p += (size_t)N * 128 * 2;
    unsigned short* fused = (unsigned short*)p; p += (size_t)N * 96 * 2;
    unsigned short* cb    = (unsigned short*)p; p += (size_t)N * 64 * 2;
    unsigned short* lin   = (unsigned short*)p; p += (size_t)N * 64 * 2;
    unsigned short* h1    = (unsigned short*)p; p += (size_t)N * 64 * 2;
    unsigned short* hb    = (unsigned short*)p; p += (size_t)N * 64 * 2;
    float* hacc   = (float*)p;                  p += (size_t)N * 64 * 4;
    float* dinv   = (float*)p;                  p += (size_t)N2 * 4;
    int*   rowptr = (int*)p;                    p += (size_t)(N2 + 64) * 4;
    int*   rowcnt = (int*)p;                    p += (size_t)(N2 + 64) * 4;
    int*   gcur   = (int*)p;                    p += (size_t)NRANGES * GSTRIDE * 4;
    int*   rstart = (int*)p;                    p += (size_t)(NRANGES + 8) * 4;
    int*   srcs   = (int*)p;                    p += (size_t)E * 4;
    // hacc region (25.6MB) reuse: ebuf (u32, <= N*128 B) then h1t (N*128 B).
    unsigned*       ebuf = (unsigned*)hacc;
    unsigned short* h1t  = (unsigned short*)((char*)hacc + (size_t)N * 128);
    unsigned short* h1g  = h1;
    unsigned short* ling = lin;
    unsigned short* lint = cb;   // cb dead after passq_gelu
    float* out    = (float*)d_out;

    const unsigned rowBlocks32 = (unsigned)((N + 31) / 32);
    const unsigned nodeBlocks16 = (unsigned)((N + 15) / 16);
    const unsigned ppBlocks    = (unsigned)((E + PASSP_EDGES - 1) / PASSP_EDGES);
    const unsigned mmBlocks    = 391;

    // [detect | initcur]
    detect_kernel<<<3, 256, 0, stream>>>((const unsigned char*)mask, (const int*)adj_ei,
                                         flags, gcur, cap);
    // [passp | prep]
    passp_prep_kernel<<<ppBlocks + rowBlocks32, 256, 0, stream>>>(
        adj_ei, E1, tr_ei, E2, N, flags, gcur, cap, ebuf, sbits, (int)ppBlocks,
        context, target, mask, mask_token, te_W, te_b, ctxb, fused);
    // [mfma_ln | rscan]
    ln_rscan_kernel<<<mmBlocks + 1, 256, 0, stream>>>(
        ctxb, ce_W1, ce_b1, ce_g, ce_be, cb, N, (int)mmBlocks,
        gcur, cap, rstart, rowptr, N2);
    // [passq | mfma_gelu]
    passq_gelu_kernel<<<NRANGES + mmBlocks, 256, 0, stream>>>(
        rstart, ebuf, cap, N2, sbits, rowptr, rowcnt, dinv, srcs,
        cb, ce_W2, ce_b2, fused, N, (int)mmBlocks);

    // ---- GCN layer 1: dual matmul (shared A) -> fused gather (both graphs) ----
    mm_l1_dual_kernel<<<mmBlocks, 256, 0, stream>>>(fused, g1_W, t1_W, dinv, ling, lint, N);
    gather_l1_kernel<<<nodeBlocks16, 256, 0, stream>>>(rowptr, rowcnt, srcs, dinv,
                                                       ling, lint, g1_b, t1_b, h1g, h1t, N);
    // ---- GCN layer 2: split matmul -> fused gather + gated combine ----
    mm_l2_kernel<<<2 * mmBlocks, 256, 0, stream>>>(h1g, h1t, g2_W, t2_W, dinv,
                                                   ling, lint, N, (int)mmBlocks);
    gather_l2_kernel<<<nodeBlocks16, 256, 0, stream>>>(rowptr, rowcnt, srcs, dinv,
                                                       ling, lint, g2_b, t2_b, alpha, hb, N);

    // ---- head (MFMA) ----
    head_mfma_kernel<<<mmBlocks, 256, 0, stream>>>(hb, fused, h_W1, h_b1, h_g, h_be,
                                                   h_W2, h_b2, out, N);
}

// Round 7
// 401.215 us; speedup vs baseline: 1.7605x; 1.0468x over previous
//
#include <hip/hip_runtime.h>
#include <math.h>

// UrbanModelV2: encoder MLPs -> 4x GCNConv (2 graphs) -> gated combine -> LN-MLP head.
// N=100000, CTX=128, TGT=32, H=64, FUS=96, E1=1.6M, E2=0.8M. fp32 in/out.
//
// R16: passp_prep moved to 1024-thread blocks (16 waves). R15 profile showed the
//   kernel tail = 293 passp blocks at 1.1 block/CU -> 1 wave/SIMD, zero latency
//   hiding (Occupancy 32%, VALU 9%). Same PASSP_EDGES=8192 (16-edge bucket runs,
//   full-line scatter) but 8 edges/thread across 16 waves -> 4x TLP in the tail.
//   prep widened to 128 rows/block (16 waves x 8 rows, 16KB tbuf).

#define LN_EPS 1e-5f
#define NRANGES 512
#define RMASK 511
#define LSHIFT 9
#define PASSP_EDGES 8192
#define GSTRIDE 16            // gcur element stride (64B lines)

typedef __attribute__((ext_vector_type(8))) short short8;            // 8 bf16
typedef __attribute__((ext_vector_type(4))) float float4v;           // MFMA acc
typedef __attribute__((ext_vector_type(4))) unsigned short ushort4v; // 4 bf16

__device__ __forceinline__ float gelu_exact(float x) {
    return 0.5f * x * (1.0f + erff(x * 0.70710678118654752440f));
}

// reduce across the 16-lane quad-group (lane masks 1..8 stay within group)
__device__ __forceinline__ float qsum16(float v) {
#pragma unroll
    for (int m = 1; m < 16; m <<= 1)
        v += __shfl_xor(v, m, 64);
    return v;
}

__device__ __forceinline__ int load_edge(const void* ei, int is32, long idx) {
    return is32 ? ((const int*)ei)[idx] : (int)((const long long*)ei)[idx];
}

__device__ __forceinline__ unsigned short f32_to_bf16(float f) {
    unsigned int x = __float_as_uint(f);
    x += 0x7fffu + ((x >> 16) & 1u);   // RNE, finite values
    return (unsigned short)(x >> 16);
}
__device__ __forceinline__ float bf16_to_f32(unsigned short u) {
    return __uint_as_float((unsigned int)u << 16);
}
__device__ __forceinline__ float bflo(unsigned x) { return __uint_as_float(x << 16); }
__device__ __forceinline__ float bfhi(unsigned x) { return __uint_as_float(x & 0xffff0000u); }

// load dst-nodes (transit offset by n) for edges base..base+3; nv = #valid
__device__ __forceinline__ void load_dst4(const void* ei1, int e1, const void* ei2, int e2,
                                          int n, int is32, int base, int nv, int nd[4]) {
    if (is32 && nv == 4) {
        if (base + 3 < e1 && (((e1 + base) & 3) == 0)) {
            int4 v = *(const int4*)((const int*)ei1 + (size_t)e1 + base);
            nd[0] = v.x; nd[1] = v.y; nd[2] = v.z; nd[3] = v.w;
            return;
        }
        if (base >= e1 && (((e2 + base - e1) & 3) == 0)) {
            int4 v = *(const int4*)((const int*)ei2 + (size_t)e2 + (base - e1));
            nd[0] = v.x + n; nd[1] = v.y + n; nd[2] = v.z + n; nd[3] = v.w + n;
            return;
        }
    }
#pragma unroll
    for (int u = 0; u < 4; ++u) {
        int i = base + u;
        if (u >= nv) { nd[u] = -1; continue; }
        if (i < e1) nd[u] = load_edge(ei1, is32, (long)e1 + i);
        else        nd[u] = load_edge(ei2, is32, (long)e2 + (i - e1)) + n;
    }
}

// load src-nodes for edges base..base+3; nv = #valid
__device__ __forceinline__ void load_src4(const void* ei1, int e1, const void* ei2, int e2,
                                          int is32, int base, int nv, int ns[4]) {
    if (is32 && nv == 4) {
        if (base + 3 < e1 && ((base & 3) == 0)) {
            int4 v = *(const int4*)((const int*)ei1 + base);
            ns[0] = v.x; ns[1] = v.y; ns[2] = v.z; ns[3] = v.w;
            return;
        }
        if (base >= e1 && (((base - e1) & 3) == 0)) {
            int4 v = *(const int4*)((const int*)ei2 + (base - e1));
            ns[0] = v.x; ns[1] = v.y; ns[2] = v.z; ns[3] = v.w;
            return;
        }
    }
#pragma unroll
    for (int u = 0; u < 4; ++u) {
        int i = base + u;
        if (u >= nv) { ns[u] = 0; continue; }
        if (i < e1) ns[u] = load_edge(ei1, is32, i);
        else        ns[u] = load_edge(ei2, is32, (long)(i - e1));
    }
}

// ---------------- dtype detection + cursor init ----------------
__global__ __launch_bounds__(256) void detect_kernel(const unsigned char* __restrict__ mask_bytes,
                                                     const int* __restrict__ ei_words,
                                                     int* __restrict__ flags,
                                                     int* __restrict__ gcur, int cap) {
    if (blockIdx.x == 0) {
        __shared__ int f0, f1;
        if (threadIdx.x == 0) { f0 = 0; f1 = 0; }
        __syncthreads();
        int i = threadIdx.x;
        if ((i & 3) != 0 && mask_bytes[i] != 0) f0 = 1;
        if (i < 64 && ei_words[2 * i + 1] != 0) f1 = 1;
        __syncthreads();
        if (threadIdx.x == 0) { flags[0] = f0; flags[1] = f1; }
    } else {
        int r = (blockIdx.x - 1) * 256 + threadIdx.x;
        if (r < NRANGES) gcur[r * GSTRIDE] = r * cap;
    }
}

// ---------------- CSR stage 1 body (1024 thr): partition edges into range buckets ----------------
__device__ __forceinline__ void passp_body(
    const void* ei1, int e1, const void* ei2, int e2,
    int n, const int* flags, int* gcur, int cap, unsigned* ebuf, int sbits, int bid)
{
    __shared__ int hist[NRANGES];
    __shared__ int base[NRANGES];
    const int E = e1 + e2;
    const int is32 = flags[1];
    const int b0 = bid * PASSP_EDGES;
    const int bend = (b0 + PASSP_EDGES < E) ? b0 + PASSP_EDGES : E;
    const int tid = threadIdx.x;

    for (int k = tid; k < NRANGES; k += 1024) hist[k] = 0;
    __syncthreads();

    // pass 1: histogram; the atomic return IS the local rank (kept in regs)
    int nd[8], rk[8];
#pragma unroll
    for (int j = 0; j < 2; ++j) {
        int bi = b0 + j * 4096 + tid * 4;
        int nv = bend - bi; nv = (nv < 0) ? 0 : (nv > 4 ? 4 : nv);
        load_dst4(ei1, e1, ei2, e2, n, is32, bi, nv, &nd[j * 4]);
#pragma unroll
        for (int u = 0; u < 4; ++u)
            if (u < nv) rk[j * 4 + u] = atomicAdd(&hist[nd[j * 4 + u] & RMASK], 1);
    }
    __syncthreads();

    // allocate: one device atomic per nonempty (block,range); gcur strided 64B
    for (int r = tid; r < NRANGES; r += 1024) {
        int c = hist[r];
        base[r] = c ? atomicAdd(&gcur[r * GSTRIDE], c) : 0;
    }
    __syncthreads();

    // pass 2: pure 4B packed scatter, no LDS ops
#pragma unroll
    for (int j = 0; j < 2; ++j) {
        int bi = b0 + j * 4096 + tid * 4;
        int nv = bend - bi; nv = (nv < 0) ? 0 : (nv > 4 ? 4 : nv);
        int sv[4];
        load_src4(ei1, e1, ei2, e2, is32, bi, nv, sv);
#pragma unroll
        for (int u = 0; u < 4; ++u) {
            if (u < nv) {
                int d = nd[j * 4 + u];
                int r = d & RMASK;
                int pos = base[r] + rk[j * 4 + u];
                if (pos < (r + 1) * cap)   // capacity guard (memory safety)
                    ebuf[pos] = (unsigned)sv[u] | ((unsigned)(d >> LSHIFT) << sbits);
            }
        }
    }
}

// ---------------- prep body (1024 thr, 128 rows/block) ----------------
__device__ __forceinline__ void prep_body(
    const float* context, const float* target, const void* mask, const int* flags,
    const float* mask_token, const float* te_W, const float* te_b,
    unsigned short* ctxb, unsigned short* fused, int n, int bid)
{
    __shared__ float tbuf[128][32];
    int w = threadIdx.x >> 6;        // 0..15
    int j = threadIdx.x & 63;
    int r0 = __builtin_amdgcn_readfirstlane(bid * 128 + w * 8);
    if (r0 >= n) return;  // N % 8 == 0; whole 8-row group in or out

    const float4* src = (const float4*)(context + (size_t)r0 * 128);
    ushort4v* dst = (ushort4v*)(ctxb + (size_t)r0 * 128);
#pragma unroll
    for (int p = 0; p < 4; ++p) {
        float4 v = src[p * 64 + j];
        ushort4v o;
        o.x = f32_to_bf16(v.x); o.y = f32_to_bf16(v.y);
        o.z = f32_to_bf16(v.z); o.w = f32_to_bf16(v.w);
        dst[p * 64 + j] = o;
    }

    int tr = j >> 5;
    int tj = j & 31;
#pragma unroll
    for (int rr = 0; rr < 4; ++rr) {
        int r = tr + rr * 2;
        long mi = (long)(r0 + r) * 32 + tj;
        int mraw = flags[0] ? (int)((const unsigned char*)mask)[mi]
                            : ((const int*)mask)[mi];
        float m = mraw ? 1.0f : 0.0f;
        tbuf[w * 8 + r][tj] = target[mi] * (1.0f - m) + mask_token[tj] * m;
    }

#pragma unroll
    for (int rr = 0; rr < 4; ++rr) {
        int r = tr + rr * 2;
        float y3 = te_b[tj];
#pragma unroll
        for (int k = 0; k < 32; ++k)
            y3 = fmaf(tbuf[w * 8 + r][k], te_W[k * 32 + tj], y3);
        fused[(long)(r0 + r) * 96 + 64 + tj] = f32_to_bf16(gelu_exact(y3));
    }
}

// ---------------- fused kernel A: passp | prep (1024 thr) ----------------
__global__ __launch_bounds__(1024) void passp_prep_kernel(
    const void* __restrict__ ei1, int e1, const void* __restrict__ ei2, int e2,
    int n, const int* __restrict__ flags, int* __restrict__ gcur, int cap,
    unsigned* __restrict__ ebuf, int sbits, int ppBlocks,
    const float* __restrict__ context, const float* __restrict__ target,
    const void* __restrict__ mask, const float* __restrict__ mask_token,
    const float* __restrict__ te_W, const float* __restrict__ te_b,
    unsigned short* __restrict__ ctxb, unsigned short* __restrict__ fused)
{
    if ((int)blockIdx.x < ppBlocks)
        passp_body(ei1, e1, ei2, e2, n, flags, gcur, cap, ebuf, sbits, blockIdx.x);
    else
        prep_body(context, target, mask, flags, mask_token, te_W, te_b,
                  ctxb, fused, n, blockIdx.x - ppBlocks);
}

// ---------------- CSR stage 2 body: prefix over 512 range totals (256 thr) ----------------
__device__ __forceinline__ void rscan_body(const int* gcur, int cap,
                                           int* rstart, int* rowptr, int n2) {
    __shared__ int ws[256];
    int t = threadIdx.x;
    int i0 = 2 * t, i1 = 2 * t + 1;
    int a0 = gcur[i0 * GSTRIDE] - i0 * cap;
    int a1 = gcur[i1 * GSTRIDE] - i1 * cap;
    ws[t] = a0 + a1;
    __syncthreads();
    for (int off = 1; off < 256; off <<= 1) {
        int v = (t >= off) ? ws[t - off] : 0;
        __syncthreads();
        if (t >= off) ws[t] += v;
        __syncthreads();
    }
    int ex = t ? ws[t - 1] : 0;
    rstart[i0] = ex;
    rstart[i1] = ex + a0;
    if (t == 255) { rstart[NRANGES] = ws[255]; rowptr[n2] = ws[255]; }
}

// ---------------- MFMA encoder layer 1 body: LN+GELU epilogue ----------------
__device__ __forceinline__ void mfma_ln_body(
    const unsigned short* x, const float* W, const float* bias, const float* g,
    const float* beta, unsigned short* y, int n, int bid, int nblk)
{
    constexpr int K = 128, KS = K / 32, STRIDE = K + 8;
    __shared__ __align__(16) unsigned short wt[64 * STRIDE];
    int n0 = threadIdx.x & 63;
    int kk = threadIdx.x >> 6;
    for (int k = kk; k < K; k += 4)
        wt[n0 * STRIDE + k] = f32_to_bf16(W[k * 64 + n0]);
    __syncthreads();

    int w = threadIdx.x >> 6;
    int lane = threadIdx.x & 63;
    int c = lane & 15;
    int q = lane >> 4;

    short8 bfrag[KS][4];
#pragma unroll
    for (int s = 0; s < KS; ++s)
#pragma unroll
        for (int nt = 0; nt < 4; ++nt)
            bfrag[s][nt] = *(const short8*)&wt[(nt * 16 + c) * STRIDE + s * 32 + q * 8];

    float bs[4], gs[4], be[4];
#pragma unroll
    for (int nt = 0; nt < 4; ++nt) {
        bs[nt] = bias[nt * 16 + c];
        gs[nt] = g[nt * 16 + c];
        be[nt] = beta[nt * 16 + c];
    }

    int T = n >> 4;
    int stride = nblk * 4;
    for (int t = __builtin_amdgcn_readfirstlane(bid * 4 + w); t < T; t += stride) {
        int r0 = t << 4;
        const unsigned short* xa = x + (size_t)(r0 + c) * K + q * 8;
        float4v acc[4] = {{0,0,0,0},{0,0,0,0},{0,0,0,0},{0,0,0,0}};
#pragma unroll
        for (int s = 0; s < KS; ++s) {
            short8 a = *(const short8*)(xa + s * 32);
#pragma unroll
            for (int nt = 0; nt < 4; ++nt)
                acc[nt] = __builtin_amdgcn_mfma_f32_16x16x32_bf16(a, bfrag[s][nt], acc[nt], 0, 0, 0);
        }
#pragma unroll
        for (int reg = 0; reg < 4; ++reg) {
            float v0 = acc[0][reg] + bs[0];
            float v1 = acc[1][reg] + bs[1];
            float v2 = acc[2][reg] + bs[2];
            float v3 = acc[3][reg] + bs[3];
            float mean = qsum16((v0 + v1) + (v2 + v3)) * (1.0f / 64.0f);
            float x0 = v0 - mean, x1 = v1 - mean, x2 = v2 - mean, x3 = v3 - mean;
            float var = qsum16((x0 * x0 + x1 * x1) + (x2 * x2 + x3 * x3)) * (1.0f / 64.0f);
            float rstd = rsqrtf(var + LN_EPS);
            size_t row = (size_t)(r0 + q * 4 + reg) * 64;
            y[row + 0 * 16 + c] = f32_to_bf16(gelu_exact(x0 * rstd * gs[0] + be[0]));
            y[row + 1 * 16 + c] = f32_to_bf16(gelu_exact(x1 * rstd * gs[1] + be[1]));
            y[row + 2 * 16 + c] = f32_to_bf16(gelu_exact(x2 * rstd * gs[2] + be[2]));
            y[row + 3 * 16 + c] = f32_to_bf16(gelu_exact(x3 * rstd * gs[3] + be[3]));
        }
    }
}

// ---------------- fused kernel B: mfma_ln | rscan ----------------
__global__ __launch_bounds__(256) void ln_rscan_kernel(
    const unsigned short* __restrict__ x, const float* __restrict__ W,
    const float* __restrict__ bias, const float* __restrict__ g,
    const float* __restrict__ beta, unsigned short* __restrict__ y, int n, int nblk,
    const int* __restrict__ gcur, int cap, int* __restrict__ rstart,
    int* __restrict__ rowptr, int n2)
{
    if ((int)blockIdx.x == nblk)
        rscan_body(gcur, cap, rstart, rowptr, n2);
    else
        mfma_ln_body(x, W, bias, g, beta, y, n, blockIdx.x, nblk);
}

// ---------------- CSR stage 3 body: per-range CSR build ----------------
// range g owns nodes {d : (d & 511) == g}, local id l = d >> 9.
__device__ __forceinline__ void passq_body(
    const int* rstart, const unsigned* ebuf, int cap, int n2, int sbits,
    int* rowptr, int* rowcnt, float* dinv, int* srcs, int g)
{
    __shared__ int deg[NRANGES];
    __shared__ int cur[NRANGES];
    __shared__ int ws[256];
    const int t = threadIdx.x;
    const int gbase = rstart[g];
    const int total = rstart[g + 1] - gbase;
    const unsigned* eb = ebuf + (size_t)g * cap;
    const unsigned smask = (1u << sbits) - 1u;

    deg[2 * t] = 0; deg[2 * t + 1] = 0;
    __syncthreads();
    for (int i = t; i < total; i += 256)
        atomicAdd(&deg[eb[i] >> sbits], 1);
    __syncthreads();

    int a0 = deg[2 * t], a1 = deg[2 * t + 1];
    ws[t] = a0 + a1;
    __syncthreads();
    for (int off = 1; off < 256; off <<= 1) {
        int v = (t >= off) ? ws[t - off] : 0;
        __syncthreads();
        if (t >= off) ws[t] += v;
        __syncthreads();
    }
    int ex = t ? ws[t - 1] : 0;
    cur[2 * t] = ex;
    cur[2 * t + 1] = ex + a0;
    int node0 = ((2 * t) << LSHIFT) | g;
    int node1 = ((2 * t + 1) << LSHIFT) | g;
    if (node0 < n2) { rowptr[node0] = gbase + ex;      rowcnt[node0] = a0; dinv[node0] = rsqrtf((float)a0 + 1.0f); }
    if (node1 < n2) { rowptr[node1] = gbase + ex + a0; rowcnt[node1] = a1; dinv[node1] = rsqrtf((float)a1 + 1.0f); }
    __syncthreads();

    for (int i = t; i < total; i += 256) {
        unsigned e = eb[i];
        int rk = atomicAdd(&cur[e >> sbits], 1);
        srcs[gbase + rk] = (int)(e & smask);
    }
}

// ---------------- MFMA encoder layer 2 body: GELU epilogue, out stride 96 ----------------
__device__ __forceinline__ void mfma_gelu_body(
    const unsigned short* x, const float* W, const float* bias,
    unsigned short* y, int n, int bid, int nblk)
{
    constexpr int K = 64, KS = K / 32, STRIDE = K + 8;
    __shared__ __align__(16) unsigned short wt[64 * STRIDE];
    int n0 = threadIdx.x & 63;
    int kk = threadIdx.x >> 6;
    for (int k = kk; k < K; k += 4)
        wt[n0 * STRIDE + k] = f32_to_bf16(W[k * 64 + n0]);
    __syncthreads();

    int w = threadIdx.x >> 6;
    int lane = threadIdx.x & 63;
    int c = lane & 15;
    int q = lane >> 4;

    short8 bfrag[KS][4];
#pragma unroll
    for (int s = 0; s < KS; ++s)
#pragma unroll
        for (int nt = 0; nt < 4; ++nt)
            bfrag[s][nt] = *(const short8*)&wt[(nt * 16 + c) * STRIDE + s * 32 + q * 8];

    float bs[4];
#pragma unroll
    for (int nt = 0; nt < 4; ++nt) bs[nt] = bias[nt * 16 + c];

    int T = n >> 4;
    int stride = nblk * 4;
    for (int t = __builtin_amdgcn_readfirstlane(bid * 4 + w); t < T; t += stride) {
        int r0 = t << 4;
        const unsigned short* xa = x + (size_t)(r0 + c) * K + q * 8;
        float4v acc[4] = {{0,0,0,0},{0,0,0,0},{0,0,0,0},{0,0,0,0}};
#pragma unroll
        for (int s = 0; s < KS; ++s) {
            short8 a = *(const short8*)(xa + s * 32);
#pragma unroll
            for (int nt = 0; nt < 4; ++nt)
                acc[nt] = __builtin_amdgcn_mfma_f32_16x16x32_bf16(a, bfrag[s][nt], acc[nt], 0, 0, 0);
        }
#pragma unroll
        for (int nt = 0; nt < 4; ++nt)
#pragma unroll
            for (int reg = 0; reg < 4; ++reg)
                y[(size_t)(r0 + q * 4 + reg) * 96 + nt * 16 + c] =
                    f32_to_bf16(gelu_exact(acc[nt][reg] + bs[nt]));
    }
}

// ---------------- fused kernel C: passq | mfma_gelu ----------------
__global__ __launch_bounds__(256) void passq_gelu_kernel(
    const int* __restrict__ rstart, const unsigned* __restrict__ ebuf, int cap, int n2,
    int sbits, int* __restrict__ rowptr, int* __restrict__ rowcnt,
    float* __restrict__ dinv, int* __restrict__ srcs,
    const unsigned short* __restrict__ x, const float* __restrict__ W,
    const float* __restrict__ bias, unsigned short* __restrict__ y, int n, int nblk)
{
    if ((int)blockIdx.x < NRANGES)
        passq_body(rstart, ebuf, cap, n2, sbits, rowptr, rowcnt, dinv, srcs, blockIdx.x);
    else
        mfma_gelu_body(x, W, bias, y, n, blockIdx.x - NRANGES, nblk);
}

// ---------------- MFMA GCN matmul layer1 (dual-weight, shared A): ----------------
// yg = (x @ Wg) * dinv[row], yt = (x @ Wt) * dinv[n+row]
__global__ __launch_bounds__(256) void mm_l1_dual_kernel(
    const unsigned short* __restrict__ x, const float* __restrict__ Wg,
    const float* __restrict__ Wt, const float* __restrict__ dinv,
    unsigned short* __restrict__ yg, unsigned short* __restrict__ yt, int n)
{
    constexpr int K = 96, KS = K / 32, STRIDE = K + 8;
    __shared__ __align__(16) unsigned short wtg[64 * STRIDE];
    __shared__ __align__(16) unsigned short wtt[64 * STRIDE];
    int n0 = threadIdx.x & 63;
    int kk = threadIdx.x >> 6;
    for (int k = kk; k < K; k += 4) {
        wtg[n0 * STRIDE + k] = f32_to_bf16(Wg[k * 64 + n0]);
        wtt[n0 * STRIDE + k] = f32_to_bf16(Wt[k * 64 + n0]);
    }
    __syncthreads();

    int w = threadIdx.x >> 6;
    int lane = threadIdx.x & 63;
    int c = lane & 15;
    int q = lane >> 4;

    short8 bg[KS][4], bt[KS][4];
#pragma unroll
    for (int s = 0; s < KS; ++s)
#pragma unroll
        for (int nt = 0; nt < 4; ++nt) {
            bg[s][nt] = *(const short8*)&wtg[(nt * 16 + c) * STRIDE + s * 32 + q * 8];
            bt[s][nt] = *(const short8*)&wtt[(nt * 16 + c) * STRIDE + s * 32 + q * 8];
        }

    int T = n >> 4;
    int stride = gridDim.x * 4;
    for (int t = __builtin_amdgcn_readfirstlane(blockIdx.x * 4 + w); t < T; t += stride) {
        int r0 = t << 4;
        const unsigned short* xa = x + (size_t)(r0 + c) * K + q * 8;
        float4v ag[4] = {{0,0,0,0},{0,0,0,0},{0,0,0,0},{0,0,0,0}};
        float4v at[4] = {{0,0,0,0},{0,0,0,0},{0,0,0,0},{0,0,0,0}};
#pragma unroll
        for (int s = 0; s < KS; ++s) {
            short8 a = *(const short8*)(xa + s * 32);
#pragma unroll
            for (int nt = 0; nt < 4; ++nt) {
                ag[nt] = __builtin_amdgcn_mfma_f32_16x16x32_bf16(a, bg[s][nt], ag[nt], 0, 0, 0);
                at[nt] = __builtin_amdgcn_mfma_f32_16x16x32_bf16(a, bt[s][nt], at[nt], 0, 0, 0);
            }
        }
        float sg[4], st[4];
#pragma unroll
        for (int reg = 0; reg < 4; ++reg) {
            sg[reg] = dinv[r0 + q * 4 + reg];
            st[reg] = dinv[n + r0 + q * 4 + reg];
        }
#pragma unroll
        for (int nt = 0; nt < 4; ++nt)
#pragma unroll
            for (int reg = 0; reg < 4; ++reg) {
                size_t row = (size_t)(r0 + q * 4 + reg) * 64 + nt * 16 + c;
                yg[row] = f32_to_bf16(ag[nt][reg] * sg[reg]);
                yt[row] = f32_to_bf16(at[nt][reg] * st[reg]);
            }
    }
}

// ---------------- MFMA GCN matmul body (single), K=64 ----------------
__device__ __forceinline__ void mm64_body(const unsigned short* x, const float* W,
                                          const float* scale, unsigned short* y,
                                          int n, int bid, int nblk) {
    constexpr int K = 64, KS = K / 32, STRIDE = K + 8;
    __shared__ __align__(16) unsigned short wt[64 * STRIDE];
    int n0 = threadIdx.x & 63;
    int kk = threadIdx.x >> 6;
    for (int k = kk; k < K; k += 4)
        wt[n0 * STRIDE + k] = f32_to_bf16(W[k * 64 + n0]);
    __syncthreads();

    int w = threadIdx.x >> 6;
    int lane = threadIdx.x & 63;
    int c = lane & 15;
    int q = lane >> 4;

    short8 bfrag[KS][4];
#pragma unroll
    for (int s = 0; s < KS; ++s)
#pragma unroll
        for (int nt = 0; nt < 4; ++nt)
            bfrag[s][nt] = *(const short8*)&wt[(nt * 16 + c) * STRIDE + s * 32 + q * 8];

    int T = n >> 4;
    int stride = nblk * 4;
    for (int t = __builtin_amdgcn_readfirstlane(bid * 4 + w); t < T; t += stride) {
        int r0 = t << 4;
        const unsigned short* xa = x + (size_t)(r0 + c) * K + q * 8;
        float4v acc[4] = {{0,0,0,0},{0,0,0,0},{0,0,0,0},{0,0,0,0}};
#pragma unroll
        for (int s = 0; s < KS; ++s) {
            short8 a = *(const short8*)(xa + s * 32);
#pragma unroll
            for (int nt = 0; nt < 4; ++nt)
                acc[nt] = __builtin_amdgcn_mfma_f32_16x16x32_bf16(a, bfrag[s][nt], acc[nt], 0, 0, 0);
        }
        float sc[4];
#pragma unroll
        for (int reg = 0; reg < 4; ++reg)
            sc[reg] = scale[r0 + q * 4 + reg];
#pragma unroll
        for (int nt = 0; nt < 4; ++nt)
#pragma unroll
            for (int reg = 0; reg < 4; ++reg)
                y[(size_t)(r0 + q * 4 + reg) * 64 + nt * 16 + c] = f32_to_bf16(acc[nt][reg] * sc[reg]);
    }
}

// ---------------- layer2 matmuls, block-split ----------------
__global__ __launch_bounds__(256) void mm_l2_kernel(
    const unsigned short* __restrict__ xg, const unsigned short* __restrict__ xt,
    const float* __restrict__ Wg, const float* __restrict__ Wt,
    const float* __restrict__ dinv,
    unsigned short* __restrict__ yg, unsigned short* __restrict__ yt, int n, int nblk)
{
    if ((int)blockIdx.x < nblk)
        mm64_body(xg, Wg, dinv, yg, n, blockIdx.x, nblk);
    else
        mm64_body(xt, Wt, dinv + n, yt, n, blockIdx.x - nblk, nblk);
}

// ---------------- 16-lane-group gather: lane l owns features 4l..4l+3 ----------------
__device__ __forceinline__ void gather4(const int* __restrict__ srcs,
                                        const unsigned short* __restrict__ lin,
                                        int beg, int cnt, int l, float acc[4]) {
    for (int base = 0; base < cnt; base += 16) {
        int c2 = cnt - base;
        if (c2 > 16) c2 = 16;
        int sj = (l < c2) ? srcs[beg + base + l] : 0;
        int t = 0;
        for (; t + 4 <= c2; t += 4) {
            uint2 v[4];
#pragma unroll
            for (int u = 0; u < 4; ++u) {
                int s = __shfl(sj, t + u, 16);
                v[u] = *(const uint2*)(lin + (size_t)((unsigned)s * 64u + (unsigned)(l * 4)));
            }
#pragma unroll
            for (int u = 0; u < 4; ++u) {
                acc[0] += bflo(v[u].x); acc[1] += bfhi(v[u].x);
                acc[2] += bflo(v[u].y); acc[3] += bfhi(v[u].y);
            }
        }
        for (; t < c2; ++t) {
            int s = __shfl(sj, t, 16);
            uint2 vv = *(const uint2*)(lin + (size_t)((unsigned)s * 64u + (unsigned)(l * 4)));
            acc[0] += bflo(vv.x); acc[1] += bfhi(vv.x);
            acc[2] += bflo(vv.y); acc[3] += bfhi(vv.y);
        }
    }
}

// layer 1: h1g = gelu(gcn_pre(adj, ling, bg)); h1t = gelu(gcn_pre(tr, lint, bt))
// 4 nodes per wave (16 lanes each).
__global__ __launch_bounds__(256) void gather_l1_kernel(
    const int* __restrict__ rowptr, const int* __restrict__ rowcnt,
    const int* __restrict__ srcs, const float* __restrict__ dinv,
    const unsigned short* __restrict__ ling, const unsigned short* __restrict__ lint,
    const float* __restrict__ bg, const float* __restrict__ bt,
    unsigned short* __restrict__ h1g, unsigned short* __restrict__ h1t, int n)
{
    int w = threadIdx.x >> 6;
    int lane = threadIdx.x & 63;
    int g = lane >> 4;
    int l = lane & 15;
    int node = blockIdx.x * 16 + w * 4 + g;
    if (node >= n) return;

    float4 b4g = ((const float4*)bg)[l];
    float4 b4t = ((const float4*)bt)[l];
    unsigned off = (unsigned)node * 64u + (unsigned)(l * 4);

    {   // adj graph
        float acc[4] = {0, 0, 0, 0};
        gather4(srcs, ling, rowptr[node], rowcnt[node], l, acc);
        uint2 sv = *(const uint2*)(ling + off);
        acc[0] += bflo(sv.x); acc[1] += bfhi(sv.x);
        acc[2] += bflo(sv.y); acc[3] += bfhi(sv.y);
        float dd = dinv[node];
        ushort4v o;
        o.x = f32_to_bf16(gelu_exact(fmaf(dd, acc[0], b4g.x)));
        o.y = f32_to_bf16(gelu_exact(fmaf(dd, acc[1], b4g.y)));
        o.z = f32_to_bf16(gelu_exact(fmaf(dd, acc[2], b4g.z)));
        o.w = f32_to_bf16(gelu_exact(fmaf(dd, acc[3], b4g.w)));
        *(ushort4v*)(h1g + off) = o;
    }
    {   // transit graph
        int tn = n + node;
        float acc[4] = {0, 0, 0, 0};
        gather4(srcs, lint, rowptr[tn], rowcnt[tn], l, acc);
        uint2 sv = *(const uint2*)(lint + off);
        acc[0] += bflo(sv.x); acc[1] += bfhi(sv.x);
        acc[2] += bflo(sv.y); acc[3] += bfhi(sv.y);
        float dd = dinv[tn];
        ushort4v o;
        o.x = f32_to_bf16(gelu_exact(fmaf(dd, acc[0], b4t.x)));
        o.y = f32_to_bf16(gelu_exact(fmaf(dd, acc[1], b4t.y)));
        o.z = f32_to_bf16(gelu_exact(fmaf(dd, acc[2], b4t.z)));
        o.w = f32_to_bf16(gelu_exact(fmaf(dd, acc[3], b4t.w)));
        *(ushort4v*)(h1t + off) = o;
    }
}

// layer 2: hb = bf16( a*gcn_pre(adj, ling, bg) + (1-a)*gcn_pre(tr, lint, bt) )
__global__ __launch_bounds__(256) void gather_l2_kernel(
    const int* __restrict__ rowptr, const int* __restrict__ rowcnt,
    const int* __restrict__ srcs, const float* __restrict__ dinv,
    const unsigned short* __restrict__ ling, const unsigned short* __restrict__ lint,
    const float* __restrict__ bg, const float* __restrict__ bt,
    const float* __restrict__ alpha_ptr, unsigned short* __restrict__ hb, int n)
{
    int w = threadIdx.x >> 6;
    int lane = threadIdx.x & 63;
    int g = lane >> 4;
    int l = lane & 15;
    int node = blockIdx.x * 16 + w * 4 + g;
    if (node >= n) return;

    float4 b4g = ((const float4*)bg)[l];
    float4 b4t = ((const float4*)bt)[l];
    unsigned off = (unsigned)node * 64u + (unsigned)(l * 4);

    float pg[4], pt[4];
    {
        float acc[4] = {0, 0, 0, 0};
        gather4(srcs, ling, rowptr[node], rowcnt[node], l, acc);
        uint2 sv = *(const uint2*)(ling + off);
        acc[0] += bflo(sv.x); acc[1] += bfhi(sv.x);
        acc[2] += bflo(sv.y); acc[3] += bfhi(sv.y);
        float dd = dinv[node];
        pg[0] = fmaf(dd, acc[0], b4g.x); pg[1] = fmaf(dd, acc[1], b4g.y);
        pg[2] = fmaf(dd, acc[2], b4g.z); pg[3] = fmaf(dd, acc[3], b4g.w);
    }
    {
        int tn = n + node;
        float acc[4] = {0, 0, 0, 0};
        gather4(srcs, lint, rowptr[tn], rowcnt[tn], l, acc);
        uint2 sv = *(const uint2*)(lint + off);
        acc[0] += bflo(sv.x); acc[1] += bfhi(sv.x);
        acc[2] += bflo(sv.y); acc[3] += bfhi(sv.y);
        float dd = dinv[tn];
        pt[0] = fmaf(dd, acc[0], b4t.x); pt[1] = fmaf(dd, acc[1], b4t.y);
        pt[2] = fmaf(dd, acc[2], b4t.z); pt[3] = fmaf(dd, acc[3], b4t.w);
    }
    float a = 1.0f / (1.0f + expf(-alpha_ptr[0]));
    float b = 1.0f - a;
    ushort4v o;
    o.x = f32_to_bf16(a * pg[0] + b * pt[0]);
    o.y = f32_to_bf16(a * pg[1] + b * pt[1]);
    o.z = f32_to_bf16(a * pg[2] + b * pt[2]);
    o.w = f32_to_bf16(a * pg[3] + b * pt[3]);
    *(ushort4v*)(hb + off) = o;
}

// ---------------- MFMA head: [hb|fused] @ W1 -> LN -> gelu -> @ W2 + b2 ----------------
__global__ __launch_bounds__(256) void head_mfma_kernel(
    const unsigned short* __restrict__ hb, const unsigned short* __restrict__ fused,
    const float* __restrict__ h_W1, const float* __restrict__ h_b1,
    const float* __restrict__ h_g, const float* __restrict__ h_beta,
    const float* __restrict__ h_W2, const float* __restrict__ h_b2,
    float* __restrict__ out, int n)
{
    constexpr int ST1 = 168;  // 160 + 8
    constexpr int ST2 = 72;   // 64 + 8
    __shared__ __align__(16) unsigned short wt1[64 * ST1];     // 21504 B
    __shared__ __align__(16) unsigned short wt2[32 * ST2];     // 4608 B
    __shared__ __align__(16) unsigned short zl[4][16 * ST2];   // 9216 B

    int n0 = threadIdx.x & 63;
    int kk = threadIdx.x >> 6;
    for (int k = kk; k < 160; k += 4)
        wt1[n0 * ST1 + k] = f32_to_bf16(h_W1[k * 64 + n0]);
    if (n0 < 32)
        for (int k = kk; k < 64; k += 4)
            wt2[n0 * ST2 + k] = f32_to_bf16(h_W2[k * 32 + n0]);
    __syncthreads();

    int w = threadIdx.x >> 6;
    int lane = threadIdx.x & 63;
    int c = lane & 15;
    int q = lane >> 4;

    short8 b1f[5][4];
#pragma unroll
    for (int s = 0; s < 5; ++s)
#pragma unroll
        for (int nt = 0; nt < 4; ++nt)
            b1f[s][nt] = *(const short8*)&wt1[(nt * 16 + c) * ST1 + s * 32 + q * 8];
    short8 b2f[2][2];
#pragma unroll
    for (int s = 0; s < 2; ++s)
#pragma unroll
        for (int nt = 0; nt < 2; ++nt)
            b2f[s][nt] = *(const short8*)&wt2[(nt * 16 + c) * ST2 + s * 32 + q * 8];

    float bs[4], gs[4], be[4];
#pragma unroll
    for (int nt = 0; nt < 4; ++nt) {
        bs[nt] = h_b1[nt * 16 + c];
        gs[nt] = h_g[nt * 16 + c];
        be[nt] = h_beta[nt * 16 + c];
    }
    float b2s[2];
#pragma unroll
    for (int nt = 0; nt < 2; ++nt) b2s[nt] = h_b2[nt * 16 + c];

    unsigned short* zw = zl[w];
    int T = n >> 4;
    int stride = gridDim.x * 4;
    for (int t = __builtin_amdgcn_readfirstlane(blockIdx.x * 4 + w); t < T; t += stride) {
        int r0 = t << 4;
        // stage 1: K=160 (hb: k 0..63, fused: k 64..159)
        const unsigned short* xh = hb + (size_t)(r0 + c) * 64 + q * 8;
        const unsigned short* xf = fused + (size_t)(r0 + c) * 96 + q * 8;
        float4v acc[4] = {{0,0,0,0},{0,0,0,0},{0,0,0,0},{0,0,0,0}};
#pragma unroll
        for (int s = 0; s < 2; ++s) {
            short8 a = *(const short8*)(xh + s * 32);
#pragma unroll
            for (int nt = 0; nt < 4; ++nt)
                acc[nt] = __builtin_amdgcn_mfma_f32_16x16x32_bf16(a, b1f[s][nt], acc[nt], 0, 0, 0);
        }
#pragma unroll
        for (int s = 0; s < 3; ++s) {
            short8 a = *(const short8*)(xf + s * 32);
#pragma unroll
            for (int nt = 0; nt < 4; ++nt)
                acc[nt] = __builtin_amdgcn_mfma_f32_16x16x32_bf16(a, b1f[2 + s][nt], acc[nt], 0, 0, 0);
        }
        // epilogue: +b1, LN per row (q*4+reg), gelu -> zl (wave-private)
#pragma unroll
        for (int reg = 0; reg < 4; ++reg) {
            float v0 = acc[0][reg] + bs[0];
            float v1 = acc[1][reg] + bs[1];
            float v2 = acc[2][reg] + bs[2];
            float v3 = acc[3][reg] + bs[3];
            float mean = qsum16((v0 + v1) + (v2 + v3)) * (1.0f / 64.0f);
            float x0 = v0 - mean, x1 = v1 - mean, x2 = v2 - mean, x3 = v3 - mean;
            float var = qsum16((x0 * x0 + x1 * x1) + (x2 * x2 + x3 * x3)) * (1.0f / 64.0f);
            float rstd = rsqrtf(var + LN_EPS);
            int row = q * 4 + reg;
            zw[row * ST2 + 0 * 16 + c] = f32_to_bf16(gelu_exact(x0 * rstd * gs[0] + be[0]));
            zw[row * ST2 + 1 * 16 + c] = f32_to_bf16(gelu_exact(x1 * rstd * gs[1] + be[1]));
            zw[row * ST2 + 2 * 16 + c] = f32_to_bf16(gelu_exact(x2 * rstd * gs[2] + be[2]));
            zw[row * ST2 + 3 * 16 + c] = f32_to_bf16(gelu_exact(x3 * rstd * gs[3] + be[3]));
        }
        // stage 2: z (16x64) @ W2 (64x32); same-wave LDS write->read, no barrier
        float4v acc2[2] = {{0,0,0,0},{0,0,0,0}};
#pragma unroll
        for (int s = 0; s < 2; ++s) {
            short8 a2 = *(const short8*)&zw[c * ST2 + s * 32 + q * 8];
#pragma unroll
            for (int nt = 0; nt < 2; ++nt)
                acc2[nt] = __builtin_amdgcn_mfma_f32_16x16x32_bf16(a2, b2f[s][nt], acc2[nt], 0, 0, 0);
        }
#pragma unroll
        for (int nt = 0; nt < 2; ++nt)
#pragma unroll
            for (int reg = 0; reg < 4; ++reg)
                out[(size_t)(r0 + q * 4 + reg) * 32 + nt * 16 + c] = acc2[nt][reg] + b2s[nt];
    }
}

extern "C" void kernel_launch(void* const* d_in, const int* in_sizes, int n_in,
                              void* d_out, int out_size, void* d_ws, size_t ws_size,
                              hipStream_t stream) {
    const float* context    = (const float*)d_in[0];
    const float* target     = (const float*)d_in[1];
    const void*  mask       = d_in[2];
    const void*  adj_ei     = d_in[3];
    const void*  tr_ei      = d_in[4];
    const float* mask_token = (const float*)d_in[5];
    const float* ce_W1 = (const float*)d_in[6];
    const float* ce_b1 = (const float*)d_in[7];
    const float* ce_g  = (const float*)d_in[8];
    const float* ce_be = (const float*)d_in[9];
    const float* ce_W2 = (const float*)d_in[10];
    const float* ce_b2 = (const float*)d_in[11];
    const float* te_W  = (const float*)d_in[12];
    const float* te_b  = (const float*)d_in[13];
    const float* g1_W  = (const float*)d_in[14];
    const float* g1_b  = (const float*)d_in[15];
    const float* g2_W  = (const float*)d_in[16];
    const float* g2_b  = (const float*)d_in[17];
    const float* t1_W  = (const float*)d_in[18];
    const float* t1_b  = (const float*)d_in[19];
    const float* t2_W  = (const float*)d_in[20];
    const float* t2_b  = (const float*)d_in[21];
    const float* alpha = (const float*)d_in[22];
    const float* h_W1  = (const float*)d_in[23];
    const float* h_b1  = (const float*)d_in[24];
    const float* h_g   = (const float*)d_in[25];
    const float* h_be  = (const float*)d_in[26];
    const float* h_W2  = (const float*)d_in[27];
    const float* h_b2  = (const float*)d_in[28];

    const int N  = in_sizes[0] / 128;
    const int E1 = in_sizes[3] / 2;
    const int E2 = in_sizes[4] / 2;
    const int E  = E1 + E2;
    const int N2 = 2 * N;

    // src-id bit width for u32 edge packing (src < N)
    int sbits = 1;
    while ((1 << sbits) < N) ++sbits;

    // per-range bucket capacity (range = node & 511 -> uniform load)
    long expct = (E + NRANGES - 1) / NRANGES;
    int cap = (int)((expct * 4 / 3) & ~255L);
    long avail = (long)N * 128;                       // ebuf alias bytes (hacc[0 : N*128])
    int capmax = (int)((avail / ((long)NRANGES * 4)) & ~255L);
    if (cap > capmax) cap = capmax;
    if (cap < 1024) cap = 1024;

    // ---- workspace layout ----
    char* p = (char*)d_ws;
    int*   flags  = (int*)p;                    p += 256;
    unsigned short* ctxb  = (unsigned short*)p; p += (size_t)N * 128 * 2;
    unsigned short* fused = (unsigned short*)p; p += (size_t)N * 96 * 2;
    unsigned short* cb    = (unsigned short*)p; p += (size_t)N * 64 * 2;
    unsigned short* lin   = (unsigned short*)p; p += (size_t)N * 64 * 2;
    unsigned short* h1    = (unsigned short*)p; p += (size_t)N * 64 * 2;
    unsigned short* hb    = (unsigned short*)p; p += (size_t)N * 64 * 2;
    float* hacc   = (float*)p;                  p += (size_t)N * 64 * 4;
    float* dinv   = (float*)p;                  p += (size_t)N2 * 4;
    int*   rowptr = (int*)p;                    p += (size_t)(N2 + 64) * 4;
    int*   rowcnt = (int*)p;                    p += (size_t)(N2 + 64) * 4;
    int*   gcur   = (int*)p;                    p += (size_t)NRANGES * GSTRIDE * 4;
    int*   rstart = (int*)p;                    p += (size_t)(NRANGES + 8) * 4;
    int*   srcs   = (int*)p;                    p += (size_t)E * 4;
    // hacc region (25.6MB) reuse: ebuf (u32, <= N*128 B) then h1t (N*128 B).
    unsigned*       ebuf = (unsigned*)hacc;
    unsigned short* h1t  = (unsigned short*)((char*)hacc + (size_t)N * 128);
    unsigned short* h1g  = h1;
    unsigned short* ling = lin;
    unsigned short* lint = cb;   // cb dead after passq_gelu
    float* out    = (float*)d_out;

    const unsigned prepBlocks   = (unsigned)((N + 127) / 128);
    const unsigned nodeBlocks16 = (unsigned)((N + 15) / 16);
    const unsigned ppBlocks     = (unsigned)((E + PASSP_EDGES - 1) / PASSP_EDGES);
    const unsigned mmBlocks     = 391;

    // [detect | initcur]
    detect_kernel<<<3, 256, 0, stream>>>((const unsigned char*)mask, (const int*)adj_ei,
                                         flags, gcur, cap);
    // [passp | prep] (1024-thread blocks, 16 waves)
    passp_prep_kernel<<<ppBlocks + prepBlocks, 1024, 0, stream>>>(
        adj_ei, E1, tr_ei, E2, N, flags, gcur, cap, ebuf, sbits, (int)ppBlocks,
        context, target, mask, mask_token, te_W, te_b, ctxb, fused);
    // [mfma_ln | rscan]
    ln_rscan_kernel<<<mmBlocks + 1, 256, 0, stream>>>(
        ctxb, ce_W1, ce_b1, ce_g, ce_be, cb, N, (int)mmBlocks,
        gcur, cap, rstart, rowptr, N2);
    // [passq | mfma_gelu]
    passq_gelu_kernel<<<NRANGES + mmBlocks, 256, 0, stream>>>(
        rstart, ebuf, cap, N2, sbits, rowptr, rowcnt, dinv, srcs,
        cb, ce_W2, ce_b2, fused, N, (int)mmBlocks);

    // ---- GCN layer 1: dual matmul (shared A) -> fused gather (both graphs) ----
    mm_l1_dual_kernel<<<mmBlocks, 256, 0, stream>>>(fused, g1_W, t1_W, dinv, ling, lint, N);
    gather_l1_kernel<<<nodeBlocks16, 256, 0, stream>>>(rowptr, rowcnt, srcs, dinv,
                                                       ling, lint, g1_b, t1_b, h1g, h1t, N);
    // ---- GCN layer 2: split matmul -> fused gather + gated combine ----
    mm_l2_kernel<<<2 * mmBlocks, 256, 0, stream>>>(h1g, h1t, g2_W, t2_W, dinv,
                                                   ling, lint, N, (int)mmBlocks);
    gather_l2_kernel<<<nodeBlocks16, 256, 0, stream>>>(rowptr, rowcnt, srcs, dinv,
                                                       ling, lint, g2_b, t2_b, alpha, hb, N);

    // ---- head (MFMA) ----
    head_mfma_kernel<<<mmBlocks, 256, 0, stream>>>(hb, fused, h_W1, h_b1, h_g, h_be,
                                                   h_W2, h_b2, out, N);
}

// Round 8
// 393.803 us; speedup vs baseline: 1.7936x; 1.0188x over previous
//
#include <hip/hip_runtime.h>
#include <math.h>

// UrbanModelV2: encoder MLPs -> 4x GCNConv (2 graphs) -> gated combine -> LN-MLP head.
// N=100000, CTX=128, TGT=32, H=64, FUS=96, E1=1.6M, E2=0.8M. fp32 in/out.
//
// R17: traffic deletion in the top kernel (passp_prep 64us, VALU 11%/HBM 22%,
//   neither pipe saturated -> cut bytes):
//   (a) ctxb eliminated - mfma_ln reads fp32 context directly, converting to
//       bf16 fragments in-register (same RNE numerics). Removes 51.2MB read +
//       25.6MB write from prep and 25.6MB read from ln; ln now reads 51.2 fp32.
//   (b) passp loads src with dst in pass 1 (regs), pass 2 = pure scatter stores.

#define LN_EPS 1e-5f
#define NRANGES 512
#define RMASK 511
#define LSHIFT 9
#define PASSP_EDGES 8192
#define GSTRIDE 16            // gcur element stride (64B lines)

typedef __attribute__((ext_vector_type(8))) short short8;            // 8 bf16
typedef __attribute__((ext_vector_type(4))) float float4v;           // MFMA acc
typedef __attribute__((ext_vector_type(4))) unsigned short ushort4v; // 4 bf16

__device__ __forceinline__ float gelu_exact(float x) {
    return 0.5f * x * (1.0f + erff(x * 0.70710678118654752440f));
}

// reduce across the 16-lane quad-group (lane masks 1..8 stay within group)
__device__ __forceinline__ float qsum16(float v) {
#pragma unroll
    for (int m = 1; m < 16; m <<= 1)
        v += __shfl_xor(v, m, 64);
    return v;
}

__device__ __forceinline__ int load_edge(const void* ei, int is32, long idx) {
    return is32 ? ((const int*)ei)[idx] : (int)((const long long*)ei)[idx];
}

__device__ __forceinline__ unsigned short f32_to_bf16(float f) {
    unsigned int x = __float_as_uint(f);
    x += 0x7fffu + ((x >> 16) & 1u);   // RNE, finite values
    return (unsigned short)(x >> 16);
}
__device__ __forceinline__ float bf16_to_f32(unsigned short u) {
    return __uint_as_float((unsigned int)u << 16);
}
__device__ __forceinline__ float bflo(unsigned x) { return __uint_as_float(x << 16); }
__device__ __forceinline__ float bfhi(unsigned x) { return __uint_as_float(x & 0xffff0000u); }

// load dst-nodes (transit offset by n) for edges base..base+3; nv = #valid
__device__ __forceinline__ void load_dst4(const void* ei1, int e1, const void* ei2, int e2,
                                          int n, int is32, int base, int nv, int nd[4]) {
    if (is32 && nv == 4) {
        if (base + 3 < e1 && (((e1 + base) & 3) == 0)) {
            int4 v = *(const int4*)((const int*)ei1 + (size_t)e1 + base);
            nd[0] = v.x; nd[1] = v.y; nd[2] = v.z; nd[3] = v.w;
            return;
        }
        if (base >= e1 && (((e2 + base - e1) & 3) == 0)) {
            int4 v = *(const int4*)((const int*)ei2 + (size_t)e2 + (base - e1));
            nd[0] = v.x + n; nd[1] = v.y + n; nd[2] = v.z + n; nd[3] = v.w + n;
            return;
        }
    }
#pragma unroll
    for (int u = 0; u < 4; ++u) {
        int i = base + u;
        if (u >= nv) { nd[u] = -1; continue; }
        if (i < e1) nd[u] = load_edge(ei1, is32, (long)e1 + i);
        else        nd[u] = load_edge(ei2, is32, (long)e2 + (i - e1)) + n;
    }
}

// load src-nodes for edges base..base+3; nv = #valid
__device__ __forceinline__ void load_src4(const void* ei1, int e1, const void* ei2, int e2,
                                          int is32, int base, int nv, int ns[4]) {
    if (is32 && nv == 4) {
        if (base + 3 < e1 && ((base & 3) == 0)) {
            int4 v = *(const int4*)((const int*)ei1 + base);
            ns[0] = v.x; ns[1] = v.y; ns[2] = v.z; ns[3] = v.w;
            return;
        }
        if (base >= e1 && (((base - e1) & 3) == 0)) {
            int4 v = *(const int4*)((const int*)ei2 + (base - e1));
            ns[0] = v.x; ns[1] = v.y; ns[2] = v.z; ns[3] = v.w;
            return;
        }
    }
#pragma unroll
    for (int u = 0; u < 4; ++u) {
        int i = base + u;
        if (u >= nv) { ns[u] = 0; continue; }
        if (i < e1) ns[u] = load_edge(ei1, is32, i);
        else        ns[u] = load_edge(ei2, is32, (long)(i - e1));
    }
}

// ---------------- dtype detection + cursor init ----------------
__global__ __launch_bounds__(256) void detect_kernel(const unsigned char* __restrict__ mask_bytes,
                                                     const int* __restrict__ ei_words,
                                                     int* __restrict__ flags,
                                                     int* __restrict__ gcur, int cap) {
    if (blockIdx.x == 0) {
        __shared__ int f0, f1;
        if (threadIdx.x == 0) { f0 = 0; f1 = 0; }
        __syncthreads();
        int i = threadIdx.x;
        if ((i & 3) != 0 && mask_bytes[i] != 0) f0 = 1;
        if (i < 64 && ei_words[2 * i + 1] != 0) f1 = 1;
        __syncthreads();
        if (threadIdx.x == 0) { flags[0] = f0; flags[1] = f1; }
    } else {
        int r = (blockIdx.x - 1) * 256 + threadIdx.x;
        if (r < NRANGES) gcur[r * GSTRIDE] = r * cap;
    }
}

// ---------------- CSR stage 1 body (1024 thr): partition edges into range buckets ----------------
__device__ __forceinline__ void passp_body(
    const void* ei1, int e1, const void* ei2, int e2,
    int n, const int* flags, int* gcur, int cap, unsigned* ebuf, int sbits, int bid)
{
    __shared__ int hist[NRANGES];
    __shared__ int base[NRANGES];
    const int E = e1 + e2;
    const int is32 = flags[1];
    const int b0 = bid * PASSP_EDGES;
    const int bend = (b0 + PASSP_EDGES < E) ? b0 + PASSP_EDGES : E;
    const int tid = threadIdx.x;

    for (int k = tid; k < NRANGES; k += 1024) hist[k] = 0;
    __syncthreads();

    // pass 1: load dst AND src; histogram (the atomic return IS the local rank)
    int nd[8], rk[8], sv[8];
#pragma unroll
    for (int j = 0; j < 2; ++j) {
        int bi = b0 + j * 4096 + tid * 4;
        int nv = bend - bi; nv = (nv < 0) ? 0 : (nv > 4 ? 4 : nv);
        load_dst4(ei1, e1, ei2, e2, n, is32, bi, nv, &nd[j * 4]);
        load_src4(ei1, e1, ei2, e2, is32, bi, nv, &sv[j * 4]);
#pragma unroll
        for (int u = 0; u < 4; ++u)
            if (u < nv) rk[j * 4 + u] = atomicAdd(&hist[nd[j * 4 + u] & RMASK], 1);
    }
    __syncthreads();

    // allocate: one device atomic per nonempty (block,range); gcur strided 64B
    for (int r = tid; r < NRANGES; r += 1024) {
        int c = hist[r];
        base[r] = c ? atomicAdd(&gcur[r * GSTRIDE], c) : 0;
    }
    __syncthreads();

    // pass 2: pure 4B packed scatter (no reloads, no LDS ops)
#pragma unroll
    for (int j = 0; j < 2; ++j) {
        int bi = b0 + j * 4096 + tid * 4;
        int nv = bend - bi; nv = (nv < 0) ? 0 : (nv > 4 ? 4 : nv);
#pragma unroll
        for (int u = 0; u < 4; ++u) {
            if (u < nv) {
                int d = nd[j * 4 + u];
                int r = d & RMASK;
                int pos = base[r] + rk[j * 4 + u];
                if (pos < (r + 1) * cap)   // capacity guard (memory safety)
                    ebuf[pos] = (unsigned)sv[j * 4 + u] | ((unsigned)(d >> LSHIFT) << sbits);
            }
        }
    }
}

// ---------------- prep body (1024 thr, 128 rows/block): masked-target encoder ----------------
__device__ __forceinline__ void prep_body(
    const float* target, const void* mask, const int* flags,
    const float* mask_token, const float* te_W, const float* te_b,
    unsigned short* fused, int n, int bid)
{
    __shared__ float tbuf[128][32];
    int w = threadIdx.x >> 6;        // 0..15
    int j = threadIdx.x & 63;
    int r0 = __builtin_amdgcn_readfirstlane(bid * 128 + w * 8);
    if (r0 >= n) return;  // N % 8 == 0; whole 8-row group in or out

    int tr = j >> 5;
    int tj = j & 31;
#pragma unroll
    for (int rr = 0; rr < 4; ++rr) {
        int r = tr + rr * 2;
        long mi = (long)(r0 + r) * 32 + tj;
        int mraw = flags[0] ? (int)((const unsigned char*)mask)[mi]
                            : ((const int*)mask)[mi];
        float m = mraw ? 1.0f : 0.0f;
        tbuf[w * 8 + r][tj] = target[mi] * (1.0f - m) + mask_token[tj] * m;
    }

#pragma unroll
    for (int rr = 0; rr < 4; ++rr) {
        int r = tr + rr * 2;
        float y3 = te_b[tj];
#pragma unroll
        for (int k = 0; k < 32; ++k)
            y3 = fmaf(tbuf[w * 8 + r][k], te_W[k * 32 + tj], y3);
        fused[(long)(r0 + r) * 96 + 64 + tj] = f32_to_bf16(gelu_exact(y3));
    }
}

// ---------------- fused kernel A: passp | prep (1024 thr) ----------------
__global__ __launch_bounds__(1024) void passp_prep_kernel(
    const void* __restrict__ ei1, int e1, const void* __restrict__ ei2, int e2,
    int n, const int* __restrict__ flags, int* __restrict__ gcur, int cap,
    unsigned* __restrict__ ebuf, int sbits, int ppBlocks,
    const float* __restrict__ target,
    const void* __restrict__ mask, const float* __restrict__ mask_token,
    const float* __restrict__ te_W, const float* __restrict__ te_b,
    unsigned short* __restrict__ fused)
{
    if ((int)blockIdx.x < ppBlocks)
        passp_body(ei1, e1, ei2, e2, n, flags, gcur, cap, ebuf, sbits, blockIdx.x);
    else
        prep_body(target, mask, flags, mask_token, te_W, te_b,
                  fused, n, blockIdx.x - ppBlocks);
}

// ---------------- CSR stage 2 body: prefix over 512 range totals (256 thr) ----------------
__device__ __forceinline__ void rscan_body(const int* gcur, int cap,
                                           int* rstart, int* rowptr, int n2) {
    __shared__ int ws[256];
    int t = threadIdx.x;
    int i0 = 2 * t, i1 = 2 * t + 1;
    int a0 = gcur[i0 * GSTRIDE] - i0 * cap;
    int a1 = gcur[i1 * GSTRIDE] - i1 * cap;
    ws[t] = a0 + a1;
    __syncthreads();
    for (int off = 1; off < 256; off <<= 1) {
        int v = (t >= off) ? ws[t - off] : 0;
        __syncthreads();
        if (t >= off) ws[t] += v;
        __syncthreads();
    }
    int ex = t ? ws[t - 1] : 0;
    rstart[i0] = ex;
    rstart[i1] = ex + a0;
    if (t == 255) { rstart[NRANGES] = ws[255]; rowptr[n2] = ws[255]; }
}

// ---------------- MFMA encoder layer 1 body: fp32 input, LN+GELU epilogue ----------------
__device__ __forceinline__ void mfma_ln_body(
    const float* x, const float* W, const float* bias, const float* g,
    const float* beta, unsigned short* y, int n, int bid, int nblk)
{
    constexpr int K = 128, KS = K / 32, STRIDE = K + 8;
    __shared__ __align__(16) unsigned short wt[64 * STRIDE];
    int n0 = threadIdx.x & 63;
    int kk = threadIdx.x >> 6;
    for (int k = kk; k < K; k += 4)
        wt[n0 * STRIDE + k] = f32_to_bf16(W[k * 64 + n0]);
    __syncthreads();

    int w = threadIdx.x >> 6;
    int lane = threadIdx.x & 63;
    int c = lane & 15;
    int q = lane >> 4;

    short8 bfrag[KS][4];
#pragma unroll
    for (int s = 0; s < KS; ++s)
#pragma unroll
        for (int nt = 0; nt < 4; ++nt)
            bfrag[s][nt] = *(const short8*)&wt[(nt * 16 + c) * STRIDE + s * 32 + q * 8];

    float bs[4], gs[4], be[4];
#pragma unroll
    for (int nt = 0; nt < 4; ++nt) {
        bs[nt] = bias[nt * 16 + c];
        gs[nt] = g[nt * 16 + c];
        be[nt] = beta[nt * 16 + c];
    }

    int T = n >> 4;
    int stride = nblk * 4;
    for (int t = __builtin_amdgcn_readfirstlane(bid * 4 + w); t < T; t += stride) {
        int r0 = t << 4;
        const float* xa = x + (size_t)(r0 + c) * K + q * 8;
        float4v acc[4] = {{0,0,0,0},{0,0,0,0},{0,0,0,0},{0,0,0,0}};
#pragma unroll
        for (int s = 0; s < KS; ++s) {
            float4 f0 = *(const float4*)(xa + s * 32);
            float4 f1 = *(const float4*)(xa + s * 32 + 4);
            short8 a;
            a[0] = (short)f32_to_bf16(f0.x); a[1] = (short)f32_to_bf16(f0.y);
            a[2] = (short)f32_to_bf16(f0.z); a[3] = (short)f32_to_bf16(f0.w);
            a[4] = (short)f32_to_bf16(f1.x); a[5] = (short)f32_to_bf16(f1.y);
            a[6] = (short)f32_to_bf16(f1.z); a[7] = (short)f32_to_bf16(f1.w);
#pragma unroll
            for (int nt = 0; nt < 4; ++nt)
                acc[nt] = __builtin_amdgcn_mfma_f32_16x16x32_bf16(a, bfrag[s][nt], acc[nt], 0, 0, 0);
        }
#pragma unroll
        for (int reg = 0; reg < 4; ++reg) {
            float v0 = acc[0][reg] + bs[0];
            float v1 = acc[1][reg] + bs[1];
            float v2 = acc[2][reg] + bs[2];
            float v3 = acc[3][reg] + bs[3];
            float mean = qsum16((v0 + v1) + (v2 + v3)) * (1.0f / 64.0f);
            float x0 = v0 - mean, x1 = v1 - mean, x2 = v2 - mean, x3 = v3 - mean;
            float var = qsum16((x0 * x0 + x1 * x1) + (x2 * x2 + x3 * x3)) * (1.0f / 64.0f);
            float rstd = rsqrtf(var + LN_EPS);
            size_t row = (size_t)(r0 + q * 4 + reg) * 64;
            y[row + 0 * 16 + c] = f32_to_bf16(gelu_exact(x0 * rstd * gs[0] + be[0]));
            y[row + 1 * 16 + c] = f32_to_bf16(gelu_exact(x1 * rstd * gs[1] + be[1]));
            y[row + 2 * 16 + c] = f32_to_bf16(gelu_exact(x2 * rstd * gs[2] + be[2]));
            y[row + 3 * 16 + c] = f32_to_bf16(gelu_exact(x3 * rstd * gs[3] + be[3]));
        }
    }
}

// ---------------- fused kernel B: mfma_ln | rscan ----------------
__global__ __launch_bounds__(256) void ln_rscan_kernel(
    const float* __restrict__ x, const float* __restrict__ W,
    const float* __restrict__ bias, const float* __restrict__ g,
    const float* __restrict__ beta, unsigned short* __restrict__ y, int n, int nblk,
    const int* __restrict__ gcur, int cap, int* __restrict__ rstart,
    int* __restrict__ rowptr, int n2)
{
    if ((int)blockIdx.x == nblk)
        rscan_body(gcur, cap, rstart, rowptr, n2);
    else
        mfma_ln_body(x, W, bias, g, beta, y, n, blockIdx.x, nblk);
}

// ---------------- CSR stage 3 body: per-range CSR build ----------------
// range g owns nodes {d : (d & 511) == g}, local id l = d >> 9.
__device__ __forceinline__ void passq_body(
    const int* rstart, const unsigned* ebuf, int cap, int n2, int sbits,
    int* rowptr, int* rowcnt, float* dinv, int* srcs, int g)
{
    __shared__ int deg[NRANGES];
    __shared__ int cur[NRANGES];
    __shared__ int ws[256];
    const int t = threadIdx.x;
    const int gbase = rstart[g];
    const int total = rstart[g + 1] - gbase;
    const unsigned* eb = ebuf + (size_t)g * cap;
    const unsigned smask = (1u << sbits) - 1u;

    deg[2 * t] = 0; deg[2 * t + 1] = 0;
    __syncthreads();
    for (int i = t; i < total; i += 256)
        atomicAdd(&deg[eb[i] >> sbits], 1);
    __syncthreads();

    int a0 = deg[2 * t], a1 = deg[2 * t + 1];
    ws[t] = a0 + a1;
    __syncthreads();
    for (int off = 1; off < 256; off <<= 1) {
        int v = (t >= off) ? ws[t - off] : 0;
        __syncthreads();
        if (t >= off) ws[t] += v;
        __syncthreads();
    }
    int ex = t ? ws[t - 1] : 0;
    cur[2 * t] = ex;
    cur[2 * t + 1] = ex + a0;
    int node0 = ((2 * t) << LSHIFT) | g;
    int node1 = ((2 * t + 1) << LSHIFT) | g;
    if (node0 < n2) { rowptr[node0] = gbase + ex;      rowcnt[node0] = a0; dinv[node0] = rsqrtf((float)a0 + 1.0f); }
    if (node1 < n2) { rowptr[node1] = gbase + ex + a0; rowcnt[node1] = a1; dinv[node1] = rsqrtf((float)a1 + 1.0f); }
    __syncthreads();

    for (int i = t; i < total; i += 256) {
        unsigned e = eb[i];
        int rk = atomicAdd(&cur[e >> sbits], 1);
        srcs[gbase + rk] = (int)(e & smask);
    }
}

// ---------------- MFMA encoder layer 2 body: GELU epilogue, out stride 96 ----------------
__device__ __forceinline__ void mfma_gelu_body(
    const unsigned short* x, const float* W, const float* bias,
    unsigned short* y, int n, int bid, int nblk)
{
    constexpr int K = 64, KS = K / 32, STRIDE = K + 8;
    __shared__ __align__(16) unsigned short wt[64 * STRIDE];
    int n0 = threadIdx.x & 63;
    int kk = threadIdx.x >> 6;
    for (int k = kk; k < K; k += 4)
        wt[n0 * STRIDE + k] = f32_to_bf16(W[k * 64 + n0]);
    __syncthreads();

    int w = threadIdx.x >> 6;
    int lane = threadIdx.x & 63;
    int c = lane & 15;
    int q = lane >> 4;

    short8 bfrag[KS][4];
#pragma unroll
    for (int s = 0; s < KS; ++s)
#pragma unroll
        for (int nt = 0; nt < 4; ++nt)
            bfrag[s][nt] = *(const short8*)&wt[(nt * 16 + c) * STRIDE + s * 32 + q * 8];

    float bs[4];
#pragma unroll
    for (int nt = 0; nt < 4; ++nt) bs[nt] = bias[nt * 16 + c];

    int T = n >> 4;
    int stride = nblk * 4;
    for (int t = __builtin_amdgcn_readfirstlane(bid * 4 + w); t < T; t += stride) {
        int r0 = t << 4;
        const unsigned short* xa = x + (size_t)(r0 + c) * K + q * 8;
        float4v acc[4] = {{0,0,0,0},{0,0,0,0},{0,0,0,0},{0,0,0,0}};
#pragma unroll
        for (int s = 0; s < KS; ++s) {
            short8 a = *(const short8*)(xa + s * 32);
#pragma unroll
            for (int nt = 0; nt < 4; ++nt)
                acc[nt] = __builtin_amdgcn_mfma_f32_16x16x32_bf16(a, bfrag[s][nt], acc[nt], 0, 0, 0);
        }
#pragma unroll
        for (int nt = 0; nt < 4; ++nt)
#pragma unroll
            for (int reg = 0; reg < 4; ++reg)
                y[(size_t)(r0 + q * 4 + reg) * 96 + nt * 16 + c] =
                    f32_to_bf16(gelu_exact(acc[nt][reg] + bs[nt]));
    }
}

// ---------------- fused kernel C: passq | mfma_gelu ----------------
__global__ __launch_bounds__(256) void passq_gelu_kernel(
    const int* __restrict__ rstart, const unsigned* __restrict__ ebuf, int cap, int n2,
    int sbits, int* __restrict__ rowptr, int* __restrict__ rowcnt,
    float* __restrict__ dinv, int* __restrict__ srcs,
    const unsigned short* __restrict__ x, const float* __restrict__ W,
    const float* __restrict__ bias, unsigned short* __restrict__ y, int n, int nblk)
{
    if ((int)blockIdx.x < NRANGES)
        passq_body(rstart, ebuf, cap, n2, sbits, rowptr, rowcnt, dinv, srcs, blockIdx.x);
    else
        mfma_gelu_body(x, W, bias, y, n, blockIdx.x - NRANGES, nblk);
}

// ---------------- MFMA GCN matmul layer1 (dual-weight, shared A): ----------------
// yg = (x @ Wg) * dinv[row], yt = (x @ Wt) * dinv[n+row]
__global__ __launch_bounds__(256) void mm_l1_dual_kernel(
    const unsigned short* __restrict__ x, const float* __restrict__ Wg,
    const float* __restrict__ Wt, const float* __restrict__ dinv,
    unsigned short* __restrict__ yg, unsigned short* __restrict__ yt, int n)
{
    constexpr int K = 96, KS = K / 32, STRIDE = K + 8;
    __shared__ __align__(16) unsigned short wtg[64 * STRIDE];
    __shared__ __align__(16) unsigned short wtt[64 * STRIDE];
    int n0 = threadIdx.x & 63;
    int kk = threadIdx.x >> 6;
    for (int k = kk; k < K; k += 4) {
        wtg[n0 * STRIDE + k] = f32_to_bf16(Wg[k * 64 + n0]);
        wtt[n0 * STRIDE + k] = f32_to_bf16(Wt[k * 64 + n0]);
    }
    __syncthreads();

    int w = threadIdx.x >> 6;
    int lane = threadIdx.x & 63;
    int c = lane & 15;
    int q = lane >> 4;

    short8 bg[KS][4], bt[KS][4];
#pragma unroll
    for (int s = 0; s < KS; ++s)
#pragma unroll
        for (int nt = 0; nt < 4; ++nt) {
            bg[s][nt] = *(const short8*)&wtg[(nt * 16 + c) * STRIDE + s * 32 + q * 8];
            bt[s][nt] = *(const short8*)&wtt[(nt * 16 + c) * STRIDE + s * 32 + q * 8];
        }

    int T = n >> 4;
    int stride = gridDim.x * 4;
    for (int t = __builtin_amdgcn_readfirstlane(blockIdx.x * 4 + w); t < T; t += stride) {
        int r0 = t << 4;
        const unsigned short* xa = x + (size_t)(r0 + c) * K + q * 8;
        float4v ag[4] = {{0,0,0,0},{0,0,0,0},{0,0,0,0},{0,0,0,0}};
        float4v at[4] = {{0,0,0,0},{0,0,0,0},{0,0,0,0},{0,0,0,0}};
#pragma unroll
        for (int s = 0; s < KS; ++s) {
            short8 a = *(const short8*)(xa + s * 32);
#pragma unroll
            for (int nt = 0; nt < 4; ++nt) {
                ag[nt] = __builtin_amdgcn_mfma_f32_16x16x32_bf16(a, bg[s][nt], ag[nt], 0, 0, 0);
                at[nt] = __builtin_amdgcn_mfma_f32_16x16x32_bf16(a, bt[s][nt], at[nt], 0, 0, 0);
            }
        }
        float sg[4], st[4];
#pragma unroll
        for (int reg = 0; reg < 4; ++reg) {
            sg[reg] = dinv[r0 + q * 4 + reg];
            st[reg] = dinv[n + r0 + q * 4 + reg];
        }
#pragma unroll
        for (int nt = 0; nt < 4; ++nt)
#pragma unroll
            for (int reg = 0; reg < 4; ++reg) {
                size_t row = (size_t)(r0 + q * 4 + reg) * 64 + nt * 16 + c;
                yg[row] = f32_to_bf16(ag[nt][reg] * sg[reg]);
                yt[row] = f32_to_bf16(at[nt][reg] * st[reg]);
            }
    }
}

// ---------------- MFMA GCN matmul body (single), K=64 ----------------
__device__ __forceinline__ void mm64_body(const unsigned short* x, const float* W,
                                          const float* scale, unsigned short* y,
                                          int n, int bid, int nblk) {
    constexpr int K = 64, KS = K / 32, STRIDE = K + 8;
    __shared__ __align__(16) unsigned short wt[64 * STRIDE];
    int n0 = threadIdx.x & 63;
    int kk = threadIdx.x >> 6;
    for (int k = kk; k < K; k += 4)
        wt[n0 * STRIDE + k] = f32_to_bf16(W[k * 64 + n0]);
    __syncthreads();

    int w = threadIdx.x >> 6;
    int lane = threadIdx.x & 63;
    int c = lane & 15;
    int q = lane >> 4;

    short8 bfrag[KS][4];
#pragma unroll
    for (int s = 0; s < KS; ++s)
#pragma unroll
        for (int nt = 0; nt < 4; ++nt)
            bfrag[s][nt] = *(const short8*)&wt[(nt * 16 + c) * STRIDE + s * 32 + q * 8];

    int T = n >> 4;
    int stride = nblk * 4;
    for (int t = __builtin_amdgcn_readfirstlane(bid * 4 + w); t < T; t += stride) {
        int r0 = t << 4;
        const unsigned short* xa = x + (size_t)(r0 + c) * K + q * 8;
        float4v acc[4] = {{0,0,0,0},{0,0,0,0},{0,0,0,0},{0,0,0,0}};
#pragma unroll
        for (int s = 0; s < KS; ++s) {
            short8 a = *(const short8*)(xa + s * 32);
#pragma unroll
            for (int nt = 0; nt < 4; ++nt)
                acc[nt] = __builtin_amdgcn_mfma_f32_16x16x32_bf16(a, bfrag[s][nt], acc[nt], 0, 0, 0);
        }
        float sc[4];
#pragma unroll
        for (int reg = 0; reg < 4; ++reg)
            sc[reg] = scale[r0 + q * 4 + reg];
#pragma unroll
        for (int nt = 0; nt < 4; ++nt)
#pragma unroll
            for (int reg = 0; reg < 4; ++reg)
                y[(size_t)(r0 + q * 4 + reg) * 64 + nt * 16 + c] = f32_to_bf16(acc[nt][reg] * sc[reg]);
    }
}

// ---------------- layer2 matmuls, block-split ----------------
__global__ __launch_bounds__(256) void mm_l2_kernel(
    const unsigned short* __restrict__ xg, const unsigned short* __restrict__ xt,
    const float* __restrict__ Wg, const float* __restrict__ Wt,
    const float* __restrict__ dinv,
    unsigned short* __restrict__ yg, unsigned short* __restrict__ yt, int n, int nblk)
{
    if ((int)blockIdx.x < nblk)
        mm64_body(xg, Wg, dinv, yg, n, blockIdx.x, nblk);
    else
        mm64_body(xt, Wt, dinv + n, yt, n, blockIdx.x - nblk, nblk);
}

// ---------------- 16-lane-group gather: lane l owns features 4l..4l+3 ----------------
__device__ __forceinline__ void gather4(const int* __restrict__ srcs,
                                        const unsigned short* __restrict__ lin,
                                        int beg, int cnt, int l, float acc[4]) {
    for (int base = 0; base < cnt; base += 16) {
        int c2 = cnt - base;
        if (c2 > 16) c2 = 16;
        int sj = (l < c2) ? srcs[beg + base + l] : 0;
        int t = 0;
        for (; t + 4 <= c2; t += 4) {
            uint2 v[4];
#pragma unroll
            for (int u = 0; u < 4; ++u) {
                int s = __shfl(sj, t + u, 16);
                v[u] = *(const uint2*)(lin + (size_t)((unsigned)s * 64u + (unsigned)(l * 4)));
            }
#pragma unroll
            for (int u = 0; u < 4; ++u) {
                acc[0] += bflo(v[u].x); acc[1] += bfhi(v[u].x);
                acc[2] += bflo(v[u].y); acc[3] += bfhi(v[u].y);
            }
        }
        for (; t < c2; ++t) {
            int s = __shfl(sj, t, 16);
            uint2 vv = *(const uint2*)(lin + (size_t)((unsigned)s * 64u + (unsigned)(l * 4)));
            acc[0] += bflo(vv.x); acc[1] += bfhi(vv.x);
            acc[2] += bflo(vv.y); acc[3] += bfhi(vv.y);
        }
    }
}

// layer 1: h1g = gelu(gcn_pre(adj, ling, bg)); h1t = gelu(gcn_pre(tr, lint, bt))
// 4 nodes per wave (16 lanes each).
__global__ __launch_bounds__(256) void gather_l1_kernel(
    const int* __restrict__ rowptr, const int* __restrict__ rowcnt,
    const int* __restrict__ srcs, const float* __restrict__ dinv,
    const unsigned short* __restrict__ ling, const unsigned short* __restrict__ lint,
    const float* __restrict__ bg, const float* __restrict__ bt,
    unsigned short* __restrict__ h1g, unsigned short* __restrict__ h1t, int n)
{
    int w = threadIdx.x >> 6;
    int lane = threadIdx.x & 63;
    int g = lane >> 4;
    int l = lane & 15;
    int node = blockIdx.x * 16 + w * 4 + g;
    if (node >= n) return;

    float4 b4g = ((const float4*)bg)[l];
    float4 b4t = ((const float4*)bt)[l];
    unsigned off = (unsigned)node * 64u + (unsigned)(l * 4);

    {   // adj graph
        float acc[4] = {0, 0, 0, 0};
        gather4(srcs, ling, rowptr[node], rowcnt[node], l, acc);
        uint2 sv = *(const uint2*)(ling + off);
        acc[0] += bflo(sv.x); acc[1] += bfhi(sv.x);
        acc[2] += bflo(sv.y); acc[3] += bfhi(sv.y);
        float dd = dinv[node];
        ushort4v o;
        o.x = f32_to_bf16(gelu_exact(fmaf(dd, acc[0], b4g.x)));
        o.y = f32_to_bf16(gelu_exact(fmaf(dd, acc[1], b4g.y)));
        o.z = f32_to_bf16(gelu_exact(fmaf(dd, acc[2], b4g.z)));
        o.w = f32_to_bf16(gelu_exact(fmaf(dd, acc[3], b4g.w)));
        *(ushort4v*)(h1g + off) = o;
    }
    {   // transit graph
        int tn = n + node;
        float acc[4] = {0, 0, 0, 0};
        gather4(srcs, lint, rowptr[tn], rowcnt[tn], l, acc);
        uint2 sv = *(const uint2*)(lint + off);
        acc[0] += bflo(sv.x); acc[1] += bfhi(sv.x);
        acc[2] += bflo(sv.y); acc[3] += bfhi(sv.y);
        float dd = dinv[tn];
        ushort4v o;
        o.x = f32_to_bf16(gelu_exact(fmaf(dd, acc[0], b4t.x)));
        o.y = f32_to_bf16(gelu_exact(fmaf(dd, acc[1], b4t.y)));
        o.z = f32_to_bf16(gelu_exact(fmaf(dd, acc[2], b4t.z)));
        o.w = f32_to_bf16(gelu_exact(fmaf(dd, acc[3], b4t.w)));
        *(ushort4v*)(h1t + off) = o;
    }
}

// layer 2: hb = bf16( a*gcn_pre(adj, ling, bg) + (1-a)*gcn_pre(tr, lint, bt) )
__global__ __launch_bounds__(256) void gather_l2_kernel(
    const int* __restrict__ rowptr, const int* __restrict__ rowcnt,
    const int* __restrict__ srcs, const float* __restrict__ dinv,
    const unsigned short* __restrict__ ling, const unsigned short* __restrict__ lint,
    const float* __restrict__ bg, const float* __restrict__ bt,
    const float* __restrict__ alpha_ptr, unsigned short* __restrict__ hb, int n)
{
    int w = threadIdx.x >> 6;
    int lane = threadIdx.x & 63;
    int g = lane >> 4;
    int l = lane & 15;
    int node = blockIdx.x * 16 + w * 4 + g;
    if (node >= n) return;

    float4 b4g = ((const float4*)bg)[l];
    float4 b4t = ((const float4*)bt)[l];
    unsigned off = (unsigned)node * 64u + (unsigned)(l * 4);

    float pg[4], pt[4];
    {
        float acc[4] = {0, 0, 0, 0};
        gather4(srcs, ling, rowptr[node], rowcnt[node], l, acc);
        uint2 sv = *(const uint2*)(ling + off);
        acc[0] += bflo(sv.x); acc[1] += bfhi(sv.x);
        acc[2] += bflo(sv.y); acc[3] += bfhi(sv.y);
        float dd = dinv[node];
        pg[0] = fmaf(dd, acc[0], b4g.x); pg[1] = fmaf(dd, acc[1], b4g.y);
        pg[2] = fmaf(dd, acc[2], b4g.z); pg[3] = fmaf(dd, acc[3], b4g.w);
    }
    {
        int tn = n + node;
        float acc[4] = {0, 0, 0, 0};
        gather4(srcs, lint, rowptr[tn], rowcnt[tn], l, acc);
        uint2 sv = *(const uint2*)(lint + off);
        acc[0] += bflo(sv.x); acc[1] += bfhi(sv.x);
        acc[2] += bflo(sv.y); acc[3] += bfhi(sv.y);
        float dd = dinv[tn];
        pt[0] = fmaf(dd, acc[0], b4t.x); pt[1] = fmaf(dd, acc[1], b4t.y);
        pt[2] = fmaf(dd, acc[2], b4t.z); pt[3] = fmaf(dd, acc[3], b4t.w);
    }
    float a = 1.0f / (1.0f + expf(-alpha_ptr[0]));
    float b = 1.0f - a;
    ushort4v o;
    o.x = f32_to_bf16(a * pg[0] + b * pt[0]);
    o.y = f32_to_bf16(a * pg[1] + b * pt[1]);
    o.z = f32_to_bf16(a * pg[2] + b * pt[2]);
    o.w = f32_to_bf16(a * pg[3] + b * pt[3]);
    *(ushort4v*)(hb + off) = o;
}

// ---------------- MFMA head: [hb|fused] @ W1 -> LN -> gelu -> @ W2 + b2 ----------------
__global__ __launch_bounds__(256) void head_mfma_kernel(
    const unsigned short* __restrict__ hb, const unsigned short* __restrict__ fused,
    const float* __restrict__ h_W1, const float* __restrict__ h_b1,
    const float* __restrict__ h_g, const float* __restrict__ h_beta,
    const float* __restrict__ h_W2, const float* __restrict__ h_b2,
    float* __restrict__ out, int n)
{
    constexpr int ST1 = 168;  // 160 + 8
    constexpr int ST2 = 72;   // 64 + 8
    __shared__ __align__(16) unsigned short wt1[64 * ST1];     // 21504 B
    __shared__ __align__(16) unsigned short wt2[32 * ST2];     // 4608 B
    __shared__ __align__(16) unsigned short zl[4][16 * ST2];   // 9216 B

    int n0 = threadIdx.x & 63;
    int kk = threadIdx.x >> 6;
    for (int k = kk; k < 160; k += 4)
        wt1[n0 * ST1 + k] = f32_to_bf16(h_W1[k * 64 + n0]);
    if (n0 < 32)
        for (int k = kk; k < 64; k += 4)
            wt2[n0 * ST2 + k] = f32_to_bf16(h_W2[k * 32 + n0]);
    __syncthreads();

    int w = threadIdx.x >> 6;
    int lane = threadIdx.x & 63;
    int c = lane & 15;
    int q = lane >> 4;

    short8 b1f[5][4];
#pragma unroll
    for (int s = 0; s < 5; ++s)
#pragma unroll
        for (int nt = 0; nt < 4; ++nt)
            b1f[s][nt] = *(const short8*)&wt1[(nt * 16 + c) * ST1 + s * 32 + q * 8];
    short8 b2f[2][2];
#pragma unroll
    for (int s = 0; s < 2; ++s)
#pragma unroll
        for (int nt = 0; nt < 2; ++nt)
            b2f[s][nt] = *(const short8*)&wt2[(nt * 16 + c) * ST2 + s * 32 + q * 8];

    float bs[4], gs[4], be[4];
#pragma unroll
    for (int nt = 0; nt < 4; ++nt) {
        bs[nt] = h_b1[nt * 16 + c];
        gs[nt] = h_g[nt * 16 + c];
        be[nt] = h_beta[nt * 16 + c];
    }
    float b2s[2];
#pragma unroll
    for (int nt = 0; nt < 2; ++nt) b2s[nt] = h_b2[nt * 16 + c];

    unsigned short* zw = zl[w];
    int T = n >> 4;
    int stride = gridDim.x * 4;
    for (int t = __builtin_amdgcn_readfirstlane(blockIdx.x * 4 + w); t < T; t += stride) {
        int r0 = t << 4;
        // stage 1: K=160 (hb: k 0..63, fused: k 64..159)
        const unsigned short* xh = hb + (size_t)(r0 + c) * 64 + q * 8;
        const unsigned short* xf = fused + (size_t)(r0 + c) * 96 + q * 8;
        float4v acc[4] = {{0,0,0,0},{0,0,0,0},{0,0,0,0},{0,0,0,0}};
#pragma unroll
        for (int s = 0; s < 2; ++s) {
            short8 a = *(const short8*)(xh + s * 32);
#pragma unroll
            for (int nt = 0; nt < 4; ++nt)
                acc[nt] = __builtin_amdgcn_mfma_f32_16x16x32_bf16(a, b1f[s][nt], acc[nt], 0, 0, 0);
        }
#pragma unroll
        for (int s = 0; s < 3; ++s) {
            short8 a = *(const short8*)(xf + s * 32);
#pragma unroll
            for (int nt = 0; nt < 4; ++nt)
                acc[nt] = __builtin_amdgcn_mfma_f32_16x16x32_bf16(a, b1f[2 + s][nt], acc[nt], 0, 0, 0);
        }
        // epilogue: +b1, LN per row (q*4+reg), gelu -> zl (wave-private)
#pragma unroll
        for (int reg = 0; reg < 4; ++reg) {
            float v0 = acc[0][reg] + bs[0];
            float v1 = acc[1][reg] + bs[1];
            float v2 = acc[2][reg] + bs[2];
            float v3 = acc[3][reg] + bs[3];
            float mean = qsum16((v0 + v1) + (v2 + v3)) * (1.0f / 64.0f);
            float x0 = v0 - mean, x1 = v1 - mean, x2 = v2 - mean, x3 = v3 - mean;
            float var = qsum16((x0 * x0 + x1 * x1) + (x2 * x2 + x3 * x3)) * (1.0f / 64.0f);
            float rstd = rsqrtf(var + LN_EPS);
            int row = q * 4 + reg;
            zw[row * ST2 + 0 * 16 + c] = f32_to_bf16(gelu_exact(x0 * rstd * gs[0] + be[0]));
            zw[row * ST2 + 1 * 16 + c] = f32_to_bf16(gelu_exact(x1 * rstd * gs[1] + be[1]));
            zw[row * ST2 + 2 * 16 + c] = f32_to_bf16(gelu_exact(x2 * rstd * gs[2] + be[2]));
            zw[row * ST2 + 3 * 16 + c] = f32_to_bf16(gelu_exact(x3 * rstd * gs[3] + be[3]));
        }
        // stage 2: z (16x64) @ W2 (64x32); same-wave LDS write->read, no barrier
        float4v acc2[2] = {{0,0,0,0},{0,0,0,0}};
#pragma unroll
        for (int s = 0; s < 2; ++s) {
            short8 a2 = *(const short8*)&zw[c * ST2 + s * 32 + q * 8];
#pragma unroll
            for (int nt = 0; nt < 2; ++nt)
                acc2[nt] = __builtin_amdgcn_mfma_f32_16x16x32_bf16(a2, b2f[s][nt], acc2[nt], 0, 0, 0);
        }
#pragma unroll
        for (int nt = 0; nt < 2; ++nt)
#pragma unroll
            for (int reg = 0; reg < 4; ++reg)
                out[(size_t)(r0 + q * 4 + reg) * 32 + nt * 16 + c] = acc2[nt][reg] + b2s[nt];
    }
}

extern "C" void kernel_launch(void* const* d_in, const int* in_sizes, int n_in,
                              void* d_out, int out_size, void* d_ws, size_t ws_size,
                              hipStream_t stream) {
    const float* context    = (const float*)d_in[0];
    const float* target     = (const float*)d_in[1];
    const void*  mask       = d_in[2];
    const void*  adj_ei     = d_in[3];
    const void*  tr_ei      = d_in[4];
    const float* mask_token = (const float*)d_in[5];
    const float* ce_W1 = (const float*)d_in[6];
    const float* ce_b1 = (const float*)d_in[7];
    const float* ce_g  = (const float*)d_in[8];
    const float* ce_be = (const float*)d_in[9];
    const float* ce_W2 = (const float*)d_in[10];
    const float* ce_b2 = (const float*)d_in[11];
    const float* te_W  = (const float*)d_in[12];
    const float* te_b  = (const float*)d_in[13];
    const float* g1_W  = (const float*)d_in[14];
    const float* g1_b  = (const float*)d_in[15];
    const float* g2_W  = (const float*)d_in[16];
    const float* g2_b  = (const float*)d_in[17];
    const float* t1_W  = (const float*)d_in[18];
    const float* t1_b  = (const float*)d_in[19];
    const float* t2_W  = (const float*)d_in[20];
    const float* t2_b  = (const float*)d_in[21];
    const float* alpha = (const float*)d_in[22];
    const float* h_W1  = (const float*)d_in[23];
    const float* h_b1  = (const float*)d_in[24];
    const float* h_g   = (const float*)d_in[25];
    const float* h_be  = (const float*)d_in[26];
    const float* h_W2  = (const float*)d_in[27];
    const float* h_b2  = (const float*)d_in[28];

    const int N  = in_sizes[0] / 128;
    const int E1 = in_sizes[3] / 2;
    const int E2 = in_sizes[4] / 2;
    const int E  = E1 + E2;
    const int N2 = 2 * N;

    // src-id bit width for u32 edge packing (src < N)
    int sbits = 1;
    while ((1 << sbits) < N) ++sbits;

    // per-range bucket capacity (range = node & 511 -> uniform load)
    long expct = (E + NRANGES - 1) / NRANGES;
    int cap = (int)((expct * 4 / 3) & ~255L);
    long avail = (long)N * 128;                       // ebuf alias bytes (hacc[0 : N*128])
    int capmax = (int)((avail / ((long)NRANGES * 4)) & ~255L);
    if (cap > capmax) cap = capmax;
    if (cap < 1024) cap = 1024;

    // ---- workspace layout ----
    char* p = (char*)d_ws;
    int*   flags  = (int*)p;                    p += 256;
    unsigned short* fused = (unsigned short*)p; p += (size_t)N * 96 * 2;
    unsigned short* cb    = (unsigned short*)p; p += (size_t)N * 64 * 2;
    unsigned short* lin   = (unsigned short*)p; p += (size_t)N * 64 * 2;
    unsigned short* h1    = (unsigned short*)p; p += (size_t)N * 64 * 2;
    unsigned short* hb    = (unsigned short*)p; p += (size_t)N * 64 * 2;
    float* hacc   = (float*)p;                  p += (size_t)N * 64 * 4;
    float* dinv   = (float*)p;                  p += (size_t)N2 * 4;
    int*   rowptr = (int*)p;                    p += (size_t)(N2 + 64) * 4;
    int*   rowcnt = (int*)p;                    p += (size_t)(N2 + 64) * 4;
    int*   gcur   = (int*)p;                    p += (size_t)NRANGES * GSTRIDE * 4;
    int*   rstart = (int*)p;                    p += (size_t)(NRANGES + 8) * 4;
    int*   srcs   = (int*)p;                    p += (size_t)E * 4;
    // hacc region (25.6MB) reuse: ebuf (u32, <= N*128 B) then h1t (N*128 B).
    unsigned*       ebuf = (unsigned*)hacc;
    unsigned short* h1t  = (unsigned short*)((char*)hacc + (size_t)N * 128);
    unsigned short* h1g  = h1;
    unsigned short* ling = lin;
    unsigned short* lint = cb;   // cb dead after passq_gelu
    float* out    = (float*)d_out;

    const unsigned prepBlocks   = (unsigned)((N + 127) / 128);
    const unsigned nodeBlocks16 = (unsigned)((N + 15) / 16);
    const unsigned ppBlocks     = (unsigned)((E + PASSP_EDGES - 1) / PASSP_EDGES);
    const unsigned mmBlocks     = 391;

    // [detect | initcur]
    detect_kernel<<<3, 256, 0, stream>>>((const unsigned char*)mask, (const int*)adj_ei,
                                         flags, gcur, cap);
    // [passp | prep] (1024-thread blocks, 16 waves)
    passp_prep_kernel<<<ppBlocks + prepBlocks, 1024, 0, stream>>>(
        adj_ei, E1, tr_ei, E2, N, flags, gcur, cap, ebuf, sbits, (int)ppBlocks,
        target, mask, mask_token, te_W, te_b, fused);
    // [mfma_ln | rscan]  (ln reads fp32 context directly)
    ln_rscan_kernel<<<mmBlocks + 1, 256, 0, stream>>>(
        context, ce_W1, ce_b1, ce_g, ce_be, cb, N, (int)mmBlocks,
        gcur, cap, rstart, rowptr, N2);
    // [passq | mfma_gelu]
    passq_gelu_kernel<<<NRANGES + mmBlocks, 256, 0, stream>>>(
        rstart, ebuf, cap, N2, sbits, rowptr, rowcnt, dinv, srcs,
        cb, ce_W2, ce_b2, fused, N, (int)mmBlocks);

    // ---- GCN layer 1: dual matmul (shared A) -> fused gather (both graphs) ----
    mm_l1_dual_kernel<<<mmBlocks, 256, 0, stream>>>(fused, g1_W, t1_W, dinv, ling, lint, N);
    gather_l1_kernel<<<nodeBlocks16, 256, 0, stream>>>(rowptr, rowcnt, srcs, dinv,
                                                       ling, lint, g1_b, t1_b, h1g, h1t, N);
    // ---- GCN layer 2: split matmul -> fused gather + gated combine ----
    mm_l2_kernel<<<2 * mmBlocks, 256, 0, stream>>>(h1g, h1t, g2_W, t2_W, dinv,
                                                   ling, lint, N, (int)mmBlocks);
    gather_l2_kernel<<<nodeBlocks16, 256, 0, stream>>>(rowptr, rowcnt, srcs, dinv,
                                                       ling, lint, g2_b, t2_b, alpha, hb, N);

    // ---- head (MFMA) ----
    head_mfma_kernel<<<mmBlocks, 256, 0, stream>>>(hb, fused, h_W1, h_b1, h_g, h_be,
                                                   h_W2, h_b2, out, N);
}